// Round 13
// baseline (211.515 us; speedup 1.0000x reference)
//
#include <hip/hip_runtime.h>

#define B_ 16
#define L_ 300
#define E_ 256
#define H_ 8
#define HD_ 32
#define FF_ 1024
#define SCALE_ 0.17677669529663687f
#define EPS_ 1e-5f

typedef __attribute__((ext_vector_type(8))) short bf16x8;
typedef __attribute__((ext_vector_type(4))) float f32x4;

__device__ __forceinline__ ushort f2b(float f) {
    unsigned u = __float_as_uint(f);
    u += 0x7fff + ((u >> 16) & 1);
    return (ushort)(u >> 16);
}
// packed f32x2 -> bf16x2 via HW cvt (RNE), 1 VALU op
__device__ __forceinline__ unsigned pk2(float a, float b) {
    unsigned r;
    asm("v_cvt_pk_bf16_f32 %0, %1, %2" : "=v"(r) : "v"(a), "v"(b));
    return r;
}

// ---------------- mgemm device body (pipelined, depth-2 register prefetch) ----------------
// AMODE: 0 = f32 A (+ADD2 if n0<a2lim); 2 = bf16 A row-major; 3 = srcs layout (BM=128).
// CL: 1 = bf16 BHLD 3-way dest (qscale on gn<256); 2 = bf16 vvT [b*8+nh][h][d][w];
//     3 = bf16 row-major.
template<int BM, int BN, int AMODE, bool ADD2, bool RELU, int CL>
__device__ __forceinline__ void mgemm_body(char* smraw, int bx, int by,
    const void* Ap, const float* A2p, const float* Wp, const float* biasp,
    void* C0v, void* C1_, void* C2_, int M, int N, int K, int Lh, float qscale, int a2lim)
{
    constexpr int TM = BM / 2, TN = BN / 2;
    constexpr int FM = TM / 16, FN = TN / 16;
    constexpr int LDT = 40;
    constexpr int NAR = (AMODE == 2) ? (BM / 64) : (BM / 32);
    constexpr int NWR = BN / 32;
    ushort* sA = (ushort*)smraw;
    ushort* sW = (ushort*)(smraw + BM * LDT * 2);
    const int t = threadIdx.x;
    const int lane = t & 63, wv = t >> 6;
    const int lo = lane & 15, kg = lane >> 4;
    const int wm = wv >> 1, wn = wv & 1;
    const int m0 = bx * BM, n0 = by * BN;

    struct RS {
        float4 ra[(AMODE == 0) ? NAR : 1];
        uint4  ra16[(AMODE == 2) ? NAR : 1];
        float  ra3[(AMODE == 3) ? 16 : 1];
        float4 rw[NWR];
    };
    RS s0, s1;

    auto LOAD = [&](int k0, RS& S) {
        if constexpr (AMODE == 0) {
            const float* A = (const float*)Ap;
#pragma unroll
            for (int i = 0; i < NAR; ++i) {
                int e = t + 256 * i;
                int m = e >> 3, kc = (e & 7) << 2;
                float4 va = *(const float4*)(A + (size_t)(m0 + m) * K + k0 + kc);
                if constexpr (ADD2) {
                    if (n0 < a2lim) {
                        float4 v2 = *(const float4*)(A2p + (size_t)(m0 + m) * K + k0 + kc);
                        va.x += v2.x; va.y += v2.y; va.z += v2.z; va.w += v2.w;
                    }
                }
                S.ra[i] = va;
            }
        } else if constexpr (AMODE == 2) {
            const ushort* A = (const ushort*)Ap;
#pragma unroll
            for (int i = 0; i < NAR; ++i) {
                int e = t + 256 * i;
                int m = e >> 2, c = (e & 3) << 3;
                S.ra16[i] = *(const uint4*)(A + (size_t)(m0 + m) * K + k0 + c);
            }
        } else {
            const float* A = (const float*)Ap;
            const int bb = m0 >> 12, p0 = m0 & 4095;
#pragma unroll
            for (int i = 0; i < 2; ++i) {
                int e = t + 256 * i;
                int m = e & 127, kslot = e >> 7;
                const float* base = A + ((size_t)(bb * 256 + k0 + kslot * 8)) * 4096 + p0 + m;
#pragma unroll
                for (int j = 0; j < 8; ++j) S.ra3[i * 8 + j] = base[(size_t)j * 4096];
            }
        }
#pragma unroll
        for (int i = 0; i < NWR; ++i) {
            int e = t + 256 * i;
            int n = e >> 3, kc = (e & 7) << 2;
            S.rw[i] = *(const float4*)(Wp + (size_t)(n0 + n) * K + k0 + kc);
        }
    };
    auto STORE = [&](RS& S) {
        if constexpr (AMODE == 0) {
#pragma unroll
            for (int i = 0; i < NAR; ++i) {
                int e = t + 256 * i;
                int m = e >> 3, kc = (e & 7) << 2;
                uint2 pk; pk.x = pk2(S.ra[i].x, S.ra[i].y); pk.y = pk2(S.ra[i].z, S.ra[i].w);
                *(uint2*)&sA[m * LDT + kc] = pk;
            }
        } else if constexpr (AMODE == 2) {
#pragma unroll
            for (int i = 0; i < NAR; ++i) {
                int e = t + 256 * i;
                int m = e >> 2, c = (e & 3) << 3;
                *(uint4*)&sA[m * LDT + c] = S.ra16[i];
            }
        } else {
#pragma unroll
            for (int i = 0; i < 2; ++i) {
                int e = t + 256 * i;
                int m = e & 127, kslot = e >> 7;
                uint4 pk;
                pk.x = pk2(S.ra3[i * 8 + 0], S.ra3[i * 8 + 1]);
                pk.y = pk2(S.ra3[i * 8 + 2], S.ra3[i * 8 + 3]);
                pk.z = pk2(S.ra3[i * 8 + 4], S.ra3[i * 8 + 5]);
                pk.w = pk2(S.ra3[i * 8 + 6], S.ra3[i * 8 + 7]);
                *(uint4*)&sA[m * LDT + kslot * 8] = pk;
            }
        }
#pragma unroll
        for (int i = 0; i < NWR; ++i) {
            int e = t + 256 * i;
            int n = e >> 3, kc = (e & 7) << 2;
            uint2 pk; pk.x = pk2(S.rw[i].x, S.rw[i].y); pk.y = pk2(S.rw[i].z, S.rw[i].w);
            *(uint2*)&sW[n * LDT + kc] = pk;
        }
    };

    f32x4 acc[FM][FN];
#pragma unroll
    for (int i = 0; i < FM; ++i)
#pragma unroll
        for (int j = 0; j < FN; ++j) acc[i][j] = (f32x4){0.f, 0.f, 0.f, 0.f};

    auto MFMAstep = [&]() {
        bf16x8 af[FM], bfr[FN];
#pragma unroll
        for (int mi = 0; mi < FM; ++mi)
            af[mi] = *(const bf16x8*)&sA[(wm * TM + mi * 16 + lo) * LDT + kg * 8];
#pragma unroll
        for (int ni = 0; ni < FN; ++ni)
            bfr[ni] = *(const bf16x8*)&sW[(wn * TN + ni * 16 + lo) * LDT + kg * 8];
#pragma unroll
        for (int mi = 0; mi < FM; ++mi)
#pragma unroll
            for (int ni = 0; ni < FN; ++ni)
                acc[mi][ni] = __builtin_amdgcn_mfma_f32_16x16x32_bf16(af[mi], bfr[ni], acc[mi][ni], 0, 0, 0);
    };

    LOAD(0, s0); LOAD(32, s1);
    for (int k0 = 0; k0 < K; k0 += 64) {
        STORE(s0);
        __syncthreads();
        if (k0 + 64 < K) LOAD(k0 + 64, s0);
        MFMAstep();
        __syncthreads();
        STORE(s1);
        __syncthreads();
        if (k0 + 96 < K) LOAD(k0 + 96, s1);
        MFMAstep();
        __syncthreads();
    }

    if constexpr (CL == 2) {
#pragma unroll
        for (int mi = 0; mi < FM; ++mi) {
            const int gmb = m0 + wm * TM + mi * 16 + kg * 4;
            const int b = gmb >> 12, p = gmb & 4095;
            const int h = p >> 6, w = p & 63;
#pragma unroll
            for (int ni = 0; ni < FN; ++ni) {
                const int gn = n0 + wn * TN + ni * 16 + lo;
                const int nh = gn >> 5, dd = gn & 31;
                const float bs = biasp[gn];
                uint2 pk;
                pk.x = pk2(acc[mi][ni][0] + bs, acc[mi][ni][1] + bs);
                pk.y = pk2(acc[mi][ni][2] + bs, acc[mi][ni][3] + bs);
                *(uint2*)((ushort*)C0v + ((size_t)(b * 8 + nh)) * 131072 + h * 2048 + dd * 64 + w) = pk;
            }
        }
    } else {
#pragma unroll
        for (int mi = 0; mi < FM; ++mi) {
#pragma unroll
            for (int r = 0; r < 4; ++r) {
                const int gm = m0 + wm * TM + mi * 16 + kg * 4 + r;
#pragma unroll
                for (int ni = 0; ni < FN; ++ni) {
                    const int gn = n0 + wn * TN + ni * 16 + lo;
                    float v = acc[mi][ni][r] + biasp[gn];
                    if constexpr (RELU) v = fmaxf(v, 0.f);
                    if constexpr (CL == 1) {
                        if (gn < 256) v *= qscale;
                        int head = (gn & 255) >> 5, d = gn & 31;
                        ushort* dst = (gn < 256) ? (ushort*)C0v
                                     : (gn < 512 ? (ushort*)C1_ : (ushort*)C2_);
                        int b = gm / Lh, l = gm - b * Lh;
                        dst[(((size_t)b * H_ + head) * Lh + l) * HD_ + d] = f2b(v);
                    } else {
                        ushort* C0 = (ushort*)C0v;
                        C0[(size_t)gm * N + gn] = f2b(v);
                    }
                }
            }
        }
    }
}

// ---------------- src means device body ----------------
__device__ __forceinline__ void means_body(char* smraw, int bc,
    const float* __restrict__ srcs, float* __restrict__ rowm, float* __restrict__ colm)
{
    float* tile = (float*)smraw;   // 64 x 65 f32
    const int b = bc >> 8, c = bc & 255;
    const float* sp = srcs + (size_t)bc * 4096;
    for (int e = threadIdx.x; e < 4096; e += 256) tile[(e >> 6) * 65 + (e & 63)] = sp[e];
    __syncthreads();
    const int t = threadIdx.x;
    if (t < 64) {
        float s = 0.f;
        for (int y = 0; y < 64; ++y) s += tile[y * 65 + t];
        rowm[((size_t)b * 64 + t) * 256 + c] = s * (1.f / 64.f);
    } else if (t < 128) {
        int y = t - 64;
        float s = 0.f;
        for (int x = 0; x < 64; ++x) s += tile[y * 65 + x];
        colm[((size_t)b * 64 + y) * 256 + c] = s * (1.f / 64.f);
    }
}

// ---------------- Phase 1: vv GEMM + qkv proj + means, one launch ----------------
// blocks [0,1024): vv (XCD-swizzled); [1024,2824): qkv; [2824,6920): means.
__global__ __launch_bounds__(256) void phase1(
    const float* __restrict__ srcs, const float* __restrict__ vw, const float* __restrict__ vb,
    ushort* __restrict__ vvb,
    const float* __restrict__ tgt, const float* __restrict__ qpos,
    const float* __restrict__ sa_w, const float* __restrict__ sa_b,
    ushort* __restrict__ q16, ushort* __restrict__ k16, ushort* __restrict__ v16,
    float* __restrict__ rowm, float* __restrict__ colm)
{
    __shared__ __align__(16) char sm[20480];
    const int bid = blockIdx.x;
    if (bid < 1024) {
        int xcd = bid & 7, s = bid >> 3;
        int by = s & 1, bx = (s >> 1) * 8 + xcd;
        mgemm_body<128,128,3,false,false,2>(sm, bx, by, srcs, nullptr, vw, vb,
            vvb, nullptr, nullptr, 65536, 256, 256, 0, 1.f, 0);
    } else if (bid < 2824) {
        int b2 = bid - 1024;
        mgemm_body<64,32,0,true,false,1>(sm, b2 % 75, b2 / 75, tgt, qpos, sa_w, sa_b,
            q16, k16, v16, 4800, 768, 256, 300, SCALE_, 512);
    } else {
        means_body(sm, bid - 2824, srcs, rowm, colm);
    }
}

// ---------------- Standalone mgemm (FFN1) ----------------
template<int BM, int BN, int AMODE, bool ADD2, bool RELU, int CL>
__global__ __launch_bounds__(256) void mgemm(
    const void* __restrict__ A_, const float* __restrict__ A2_,
    const float* __restrict__ W_, const float* __restrict__ bias_,
    void* __restrict__ C0_, void* __restrict__ C1_, void* __restrict__ C2_,
    int M, int N, int K, int Lh, float qscale, int a2lim)
{
    __shared__ __align__(16) char sm[(BM + BN) * 40 * 2];
    mgemm_body<BM,BN,AMODE,ADD2,RELU,CL>(sm, blockIdx.x, blockIdx.y,
        A_, A2_, W_, bias_, C0_, C1_, C2_, M, N, K, Lh, qscale, a2lim);
}

// ---------------- Merged CA map projections: z = {qrow, qcol, krow, kcol} ----------------
__global__ __launch_bounds__(256) void mgemm_maps(
    const float* __restrict__ A0, const float* __restrict__ A1,
    const float* __restrict__ A2x, const float* __restrict__ A3,
    const float* __restrict__ P0, const float* __restrict__ P1,
    const float* __restrict__ P2, const float* __restrict__ P3,
    const float* __restrict__ W0, const float* __restrict__ W1,
    const float* __restrict__ W2, const float* __restrict__ W3,
    const float* __restrict__ B0, const float* __restrict__ B1,
    const float* __restrict__ B2, const float* __restrict__ B3,
    ushort* __restrict__ C0, ushort* __restrict__ C1,
    ushort* __restrict__ C2, ushort* __restrict__ C3)
{
    constexpr int LDT = 40;
    __shared__ ushort sA[64 * LDT];
    __shared__ ushort sW[32 * LDT];
    const int z = blockIdx.z;
    const int M = (z < 2) ? 4800 : 1024;
    const int m0 = blockIdx.x * 64;
    if (m0 >= M) return;
    const int Lh = (z < 2) ? 300 : 64;
    const float qs = (z < 2) ? SCALE_ : 1.f;
    const float* Ap = (z == 0) ? A0 : (z == 1) ? A1 : (z == 2) ? A2x : A3;
    const float* Pp = (z == 0) ? P0 : (z == 1) ? P1 : (z == 2) ? P2 : P3;
    const float* Wp = (z == 0) ? W0 : (z == 1) ? W1 : (z == 2) ? W2 : W3;
    const float* Bp = (z == 0) ? B0 : (z == 1) ? B1 : (z == 2) ? B2 : B3;
    ushort* Cp = (z == 0) ? C0 : (z == 1) ? C1 : (z == 2) ? C2 : C3;
    const int t = threadIdx.x, lane = t & 63, wv = t >> 6;
    const int lo = lane & 15, kg = lane >> 4;
    const int wm = wv >> 1, wn = wv & 1;
    const int n0 = blockIdx.y * 32;

    float4 ra0[2], ra1[2], rw0, rw1;
    auto LOAD = [&](int k0, float4 (&ra)[2], float4& rw) {
#pragma unroll
        for (int i = 0; i < 2; ++i) {
            int e = t + 256 * i;
            int m = e >> 3, kc = (e & 7) << 2;
            float4 va = *(const float4*)(Ap + (size_t)(m0 + m) * 256 + k0 + kc);
            float4 v2 = *(const float4*)(Pp + (size_t)(m0 + m) * 256 + k0 + kc);
            va.x += v2.x; va.y += v2.y; va.z += v2.z; va.w += v2.w;
            ra[i] = va;
        }
        int n = t >> 3, kc = (t & 7) << 2;
        rw = *(const float4*)(Wp + (size_t)(n0 + n) * 256 + k0 + kc);
    };
    auto STORE = [&](float4 (&ra)[2], float4& rw) {
#pragma unroll
        for (int i = 0; i < 2; ++i) {
            int e = t + 256 * i;
            int m = e >> 3, kc = (e & 7) << 2;
            uint2 pk; pk.x = pk2(ra[i].x, ra[i].y); pk.y = pk2(ra[i].z, ra[i].w);
            *(uint2*)&sA[m * LDT + kc] = pk;
        }
        int n = t >> 3, kc = (t & 7) << 2;
        uint2 pk; pk.x = pk2(rw.x, rw.y); pk.y = pk2(rw.z, rw.w);
        *(uint2*)&sW[n * LDT + kc] = pk;
    };

    f32x4 acc[2];
    acc[0] = (f32x4){0.f, 0.f, 0.f, 0.f};
    acc[1] = (f32x4){0.f, 0.f, 0.f, 0.f};
    auto MFMAstep = [&]() {
        bf16x8 bfr = *(const bf16x8*)&sW[(wn * 16 + lo) * LDT + kg * 8];
#pragma unroll
        for (int mi = 0; mi < 2; ++mi) {
            bf16x8 af = *(const bf16x8*)&sA[(wm * 32 + mi * 16 + lo) * LDT + kg * 8];
            acc[mi] = __builtin_amdgcn_mfma_f32_16x16x32_bf16(af, bfr, acc[mi], 0, 0, 0);
        }
    };

    LOAD(0, ra0, rw0); LOAD(32, ra1, rw1);
    for (int k0 = 0; k0 < 256; k0 += 64) {
        STORE(ra0, rw0);
        __syncthreads();
        if (k0 + 64 < 256) LOAD(k0 + 64, ra0, rw0);
        MFMAstep();
        __syncthreads();
        STORE(ra1, rw1);
        __syncthreads();
        if (k0 + 96 < 256) LOAD(k0 + 96, ra1, rw1);
        MFMAstep();
        __syncthreads();
    }

#pragma unroll
    for (int mi = 0; mi < 2; ++mi) {
#pragma unroll
        for (int r = 0; r < 4; ++r) {
            const int gm = m0 + wm * 32 + mi * 16 + kg * 4 + r;
            const int gn = n0 + wn * 16 + lo;
            float v = (acc[mi][r] + Bp[gn]) * qs;
            int head = gn >> 5, d = gn & 31;
            int b = gm / Lh, l = gm - b * Lh;
            Cp[(((size_t)b * H_ + head) * Lh + l) * HD_ + d] = f2b(v);
        }
    }
}

// ---------------- GEMM + residual + LayerNorm fused (BM=16, BN=256=N, bf16 A) ----------------
template<int KK>
__global__ __launch_bounds__(256) void mgemm_ln(
    const ushort* __restrict__ A, const float* __restrict__ W,
    const float* __restrict__ bias, const float* __restrict__ res,
    const float* __restrict__ gw, const float* __restrict__ gb, float* __restrict__ O)
{
    constexpr int LDT = 40;
    __shared__ ushort sA[16 * LDT];
    __shared__ ushort sW[256 * LDT];
    __shared__ float red[4][16][2];
    const int t = threadIdx.x, lane = t & 63, wv = t >> 6;
    const int lo = lane & 15, kg = lane >> 4;
    const int m0 = blockIdx.x * 16;
    const bool aact = (t < 128);

    uint2 a0, a1;
    float4 w0[8], w1[8];
    auto LOADA = [&](int k0, uint2& aa) {
        if (aact) aa = *(const uint2*)(A + (size_t)(m0 + (t >> 3)) * KK + k0 + ((t & 7) << 2));
    };
    auto LOADW = [&](int k0, float4 (&ww)[8]) {
#pragma unroll
        for (int i = 0; i < 8; ++i) {
            int e = t + 256 * i;
            int n = e >> 3, kc = (e & 7) << 2;
            ww[i] = *(const float4*)(W + (size_t)n * KK + k0 + kc);
        }
    };
    auto STOREA = [&](uint2& aa) {
        if (aact) *(uint2*)&sA[(t >> 3) * LDT + ((t & 7) << 2)] = aa;
    };
    auto STOREW = [&](float4 (&ww)[8]) {
#pragma unroll
        for (int i = 0; i < 8; ++i) {
            int e = t + 256 * i;
            int n = e >> 3, kc = (e & 7) << 2;
            uint2 pk; pk.x = pk2(ww[i].x, ww[i].y); pk.y = pk2(ww[i].z, ww[i].w);
            *(uint2*)&sW[n * LDT + kc] = pk;
        }
    };

    f32x4 acc[4];
#pragma unroll
    for (int i = 0; i < 4; ++i) acc[i] = (f32x4){0.f, 0.f, 0.f, 0.f};

    auto MFMAstep = [&]() {
        bf16x8 af = *(const bf16x8*)&sA[lo * LDT + kg * 8];
#pragma unroll
        for (int ni = 0; ni < 4; ++ni) {
            bf16x8 bfr = *(const bf16x8*)&sW[(wv * 64 + ni * 16 + lo) * LDT + kg * 8];
            acc[ni] = __builtin_amdgcn_mfma_f32_16x16x32_bf16(af, bfr, acc[ni], 0, 0, 0);
        }
    };

    LOADA(0, a0); LOADW(0, w0);
    LOADA(32, a1); LOADW(32, w1);
    for (int k0 = 0; k0 < KK; k0 += 64) {
        STOREA(a0); STOREW(w0);
        __syncthreads();
        if (k0 + 64 < KK) { LOADA(k0 + 64, a0); LOADW(k0 + 64, w0); }
        MFMAstep();
        __syncthreads();
        STOREA(a1); STOREW(w1);
        __syncthreads();
        if (k0 + 96 < KK) { LOADA(k0 + 96, a1); LOADW(k0 + 96, w1); }
        MFMAstep();
        __syncthreads();
    }

    const int gmb = m0 + kg * 4;
    float vvv[4][4];
    float ps[4] = {0.f, 0.f, 0.f, 0.f}, qs[4] = {0.f, 0.f, 0.f, 0.f};
#pragma unroll
    for (int ni = 0; ni < 4; ++ni) {
        const int gn = wv * 64 + ni * 16 + lo;
        const float bs = bias[gn];
#pragma unroll
        for (int r = 0; r < 4; ++r) {
            float x = acc[ni][r] + bs + res[(size_t)(gmb + r) * 256 + gn];
            vvv[ni][r] = x;
            ps[r] += x;
            qs[r] += x * x;
        }
    }
#pragma unroll
    for (int off = 1; off < 16; off <<= 1) {
#pragma unroll
        for (int r = 0; r < 4; ++r) {
            ps[r] += __shfl_xor(ps[r], off);
            qs[r] += __shfl_xor(qs[r], off);
        }
    }
    if (lo == 0) {
#pragma unroll
        for (int r = 0; r < 4; ++r) {
            red[wv][kg * 4 + r][0] = ps[r];
            red[wv][kg * 4 + r][1] = qs[r];
        }
    }
    __syncthreads();
    float mean[4], rs[4];
#pragma unroll
    for (int r = 0; r < 4; ++r) {
        const int row = kg * 4 + r;
        float s = red[0][row][0] + red[1][row][0] + red[2][row][0] + red[3][row][0];
        float q = red[0][row][1] + red[1][row][1] + red[2][row][1] + red[3][row][1];
        mean[r] = s * (1.f / 256.f);
        float var = q * (1.f / 256.f) - mean[r] * mean[r];
        rs[r] = rsqrtf(var + EPS_);
    }
#pragma unroll
    for (int ni = 0; ni < 4; ++ni) {
        const int gn = wv * 64 + ni * 16 + lo;
        const float g = gw[gn], b2 = gb[gn];
#pragma unroll
        for (int r = 0; r < 4; ++r)
            O[(size_t)(gmb + r) * 256 + gn] = (vvv[ni][r] - mean[r]) * rs[r] * g + b2;
    }
}

// ---------------- Fused SA attention; LDS-aliased; XCD-grouped ----------------
__global__ __launch_bounds__(256) void sa_fused(const ushort* __restrict__ q,
    const ushort* __restrict__ k, const ushort* __restrict__ v, ushort* __restrict__ ctx)
{
    __shared__ __align__(16) char sm[62976];
    ushort* Vt = (ushort*)sm;             // [d][key] 32 x 328
    ushort* Kt = (ushort*)(sm + 20992);   // [key][d] 304 x 40
    ushort* Pt = (ushort*)(sm + 20992);   // [wv][l][key] 4 x 16 x 328 (aliases Kt)
    const int t = threadIdx.x, lane = t & 63, wv = t >> 6;
    const int lo = lane & 15, kg = lane >> 4;
    const int linear = blockIdx.x + 5 * blockIdx.y;
    const int xcd = linear & 7, slot = linear >> 3;
    const int l0 = (slot % 5) * 64;
    const int bh = xcd + 8 * (slot / 5);
    const ushort* qp = q + (size_t)bh * 9600;
    const ushort* kp = k + (size_t)bh * 9600;
    const ushort* vp = v + (size_t)bh * 9600;

    for (int e = t; e < 1216; e += 256) {
        int row = e >> 2, dq = (e & 3) << 3;
        uint4 kv = (row < 300) ? *(const uint4*)(kp + row * 32 + dq)
                               : make_uint4(0, 0, 0, 0);
        *(uint4*)&Kt[row * 40 + dq] = kv;
    }
    for (int e = t; e < 1200; e += 256) {
        int row = e >> 2, dq = (e & 3) << 3;
        uint4 vv4 = *(const uint4*)(vp + row * 32 + dq);
        const ushort* sv = (const ushort*)&vv4;
#pragma unroll
        for (int j = 0; j < 8; ++j) Vt[(dq + j) * 328 + row] = sv[j];
    }
    for (int e = t; e < 32 * 28; e += 256) {
        int d = e / 28, kk = 300 + e % 28;
        Vt[d * 328 + kk] = 0;
    }
    const int ql = l0 + wv * 16 + lo;
    bf16x8 qf = {0, 0, 0, 0, 0, 0, 0, 0};
    if (ql < 300) qf = *(const bf16x8*)(qp + ql * 32 + kg * 8);
    __syncthreads();

    f32x4 s[19];
#pragma unroll
    for (int f = 0; f < 19; ++f) {
        bf16x8 af = *(const bf16x8*)&Kt[(f * 16 + lo) * 40 + kg * 8];
        f32x4 z = {0.f, 0.f, 0.f, 0.f};
        s[f] = __builtin_amdgcn_mfma_f32_16x16x32_bf16(af, qf, z, 0, 0, 0);
    }
    if (kg == 3) { s[18][0] = -3.4e38f; s[18][1] = -3.4e38f; s[18][2] = -3.4e38f; s[18][3] = -3.4e38f; }

    float mx = -3.4e38f;
#pragma unroll
    for (int f = 0; f < 19; ++f)
#pragma unroll
        for (int r = 0; r < 4; ++r) mx = fmaxf(mx, s[f][r]);
    mx = fmaxf(mx, __shfl_xor(mx, 16));
    mx = fmaxf(mx, __shfl_xor(mx, 32));
    float sum = 0.f;
#pragma unroll
    for (int f = 0; f < 19; ++f)
#pragma unroll
        for (int r = 0; r < 4; ++r) { s[f][r] = __expf(s[f][r] - mx); sum += s[f][r]; }
    sum += __shfl_xor(sum, 16);
    sum += __shfl_xor(sum, 32);
    const float inv = 1.f / sum;

    __syncthreads();   // all waves done reading Kt; Pt may overwrite

    ushort* Ptw = Pt + wv * (16 * 328);
#pragma unroll
    for (int f = 0; f < 19; ++f) {
        *(unsigned*)&Ptw[lo * 328 + f * 16 + kg * 4]     = pk2(s[f][0] * inv, s[f][1] * inv);
        *(unsigned*)&Ptw[lo * 328 + f * 16 + kg * 4 + 2] = pk2(s[f][2] * inv, s[f][3] * inv);
    }
    {
        uint2 z2 = make_uint2(0, 0);
        *(uint2*)&Ptw[(lane & 15) * 328 + 304 + ((lane >> 4) << 2)] = z2;
    }

    f32x4 o0 = {0.f, 0.f, 0.f, 0.f}, o1 = {0.f, 0.f, 0.f, 0.f};
#pragma unroll
    for (int f = 0; f < 10; ++f) {
        bf16x8 pa = *(const bf16x8*)&Ptw[lo * 328 + f * 32 + kg * 8];
        bf16x8 b0 = *(const bf16x8*)&Vt[lo * 328 + f * 32 + kg * 8];
        bf16x8 b1 = *(const bf16x8*)&Vt[(16 + lo) * 328 + f * 32 + kg * 8];
        o0 = __builtin_amdgcn_mfma_f32_16x16x32_bf16(pa, b0, o0, 0, 0, 0);
        o1 = __builtin_amdgcn_mfma_f32_16x16x32_bf16(pa, b1, o1, 0, 0, 0);
    }

    const int lb = l0 + wv * 16 + kg * 4;
    const int b = bh >> 3, h = bh & 7;
#pragma unroll
    for (int r = 0; r < 4; ++r) {
        int l = lb + r;
        if (l < 300) {
            ushort* op = ctx + ((size_t)b * 300 + l) * 256 + h * 32;
            op[lo] = f2b(o0[r]);
            op[lo + 16] = f2b(o1[r]);
        }
    }
}

// ---------------- Fused CA; LDS-aliased; XCD-grouped (depth-1 vv prefetch) ----------------
__global__ __launch_bounds__(256) void ca_fused(const ushort* __restrict__ qr,
    const ushort* __restrict__ qc, const ushort* __restrict__ kr, const ushort* __restrict__ kc,
    const ushort* __restrict__ vv, ushort* __restrict__ out)
{
    __shared__ __align__(16) char sm[45056];
    ushort* s_ar = (ushort*)sm;             // [l][w] 64 x 72 bf16
    float*  s_ac = (float*)(sm + 9216);     // [h][l] 64 x 68 f32
    ushort* Kr   = (ushort*)(sm + 26624);   // 64 x 40
    ushort* Kc   = (ushort*)(sm + 31744);   // 64 x 40
    ushort* vvT  = (ushort*)(sm + 26624);   // [buf][h'][d][w] 2 x 2 x 32 x 72

    const int t = threadIdx.x, lane = t & 63, wv = t >> 6;
    const int lo = lane & 15, kg = lane >> 4;
    const int linear = blockIdx.x + 5 * (blockIdx.y + 8 * blockIdx.z);
    const int xcd = linear & 7, slot = linear >> 3;
    const int l0 = (slot % 5) * 64;
    const int bh = xcd + 8 * (slot / 5);
    const int nh = bh & 7, b = bh >> 3;

    {
        const ushort* krp = kr + (size_t)bh * 2048;
        const ushort* kcp = kc + (size_t)bh * 2048;
        int row = t >> 2, dq = (t & 3) << 3;
        *(uint4*)&Kr[row * 40 + dq] = *(const uint4*)(krp + row * 32 + dq);
        *(uint4*)&Kc[row * 40 + dq] = *(const uint4*)(kcp + row * 32 + dq);
    }
    const int ql = l0 + wv * 16 + lo;
    bf16x8 qrf = {0,0,0,0,0,0,0,0}, qcf = {0,0,0,0,0,0,0,0};
    if (ql < 300) {
        qrf = *(const bf16x8*)(qr + (size_t)bh * 9600 + ql * 32 + kg * 8);
        qcf = *(const bf16x8*)(qc + (size_t)bh * 9600 + ql * 32 + kg * 8);
    }
    const ushort* vvp = vv + (size_t)bh * 131072;
    __syncthreads();   // Kr/Kc staged

#pragma unroll
    for (int m = 0; m < 2; ++m) {
        const ushort* Kp = m ? Kc : Kr;
        const bf16x8 qf = m ? qcf : qrf;
        f32x4 s[4];
#pragma unroll
        for (int f = 0; f < 4; ++f) {
            bf16x8 af = *(const bf16x8*)&Kp[(f * 16 + lo) * 40 + kg * 8];
            f32x4 z = {0.f, 0.f, 0.f, 0.f};
            s[f] = __builtin_amdgcn_mfma_f32_16x16x32_bf16(af, qf, z, 0, 0, 0);
        }
        float mx = -3.4e38f;
#pragma unroll
        for (int f = 0; f < 4; ++f)
#pragma unroll
            for (int r = 0; r < 4; ++r) mx = fmaxf(mx, s[f][r]);
        mx = fmaxf(mx, __shfl_xor(mx, 16));
        mx = fmaxf(mx, __shfl_xor(mx, 32));
        float sum = 0.f;
#pragma unroll
        for (int f = 0; f < 4; ++f)
#pragma unroll
            for (int r = 0; r < 4; ++r) { s[f][r] = __expf(s[f][r] - mx); sum += s[f][r]; }
        sum += __shfl_xor(sum, 16);
        sum += __shfl_xor(sum, 32);
        const float inv = 1.f / sum;
        if (m == 0) {
#pragma unroll
            for (int f = 0; f < 4; ++f) {
                *(unsigned*)&s_ar[(wv * 16 + lo) * 72 + f * 16 + kg * 4]     = pk2(s[f][0] * inv, s[f][1] * inv);
                *(unsigned*)&s_ar[(wv * 16 + lo) * 72 + f * 16 + kg * 4 + 2] = pk2(s[f][2] * inv, s[f][3] * inv);
            }
        } else {
#pragma unroll
            for (int f = 0; f < 4; ++f)
#pragma unroll
                for (int r = 0; r < 4; ++r)
                    s_ac[(f * 16 + kg * 4 + r) * 68 + wv * 16 + lo] = s[f][r] * inv;
        }
    }

    __syncthreads();   // done reading Kr/Kc; vvT may overwrite

#pragma unroll
    for (int i = 0; i < 2; ++i) {
        int c = t + 256 * i;
        int h1 = c >> 8, d = (c >> 3) & 31, w8 = (c & 7) << 3;
        uint4 v4 = *(const uint4*)(vvp + h1 * 2048 + d * 64 + w8);
        *(uint4*)&vvT[(h1 * 32 + d) * 72 + w8] = v4;
    }
    __syncthreads();

    const bf16x8 af0 = *(const bf16x8*)&s_ar[(wv * 16 + lo) * 72 + kg * 8];
    const bf16x8 af1 = *(const bf16x8*)&s_ar[(wv * 16 + lo) * 72 + 32 + kg * 8];

    f32x4 acc0 = {0.f, 0.f, 0.f, 0.f};
    f32x4 acc1 = {0.f, 0.f, 0.f, 0.f};

    for (int it = 0; it < 32; ++it) {
        const int cur = it & 1;
        uint4 pre[2];
        if (it < 31) {
            const ushort* nxt = vvp + (size_t)(2 * (it + 1)) * 2048;
#pragma unroll
            for (int i = 0; i < 2; ++i) {
                int c = t + 256 * i;
                int h1 = c >> 8, d = (c >> 3) & 31, w8 = (c & 7) << 3;
                pre[i] = *(const uint4*)(nxt + h1 * 2048 + d * 64 + w8);
            }
        }
#pragma unroll
        for (int hh = 0; hh < 2; ++hh) {
            const int h = 2 * it + hh;
            const ushort* vt = &vvT[(cur * 2 + hh) * 32 * 72];
            bf16x8 b00 = *(const bf16x8*)&vt[lo * 72 + kg * 8];
            bf16x8 b01 = *(const bf16x8*)&vt[lo * 72 + 32 + kg * 8];
            bf16x8 b10 = *(const bf16x8*)&vt[(16 + lo) * 72 + kg * 8];
            bf16x8 b11 = *(const bf16x8*)&vt[(16 + lo) * 72 + 32 + kg * 8];
            f32x4 z = {0.f, 0.f, 0.f, 0.f};
            f32x4 t0 = __builtin_amdgcn_mfma_f32_16x16x32_bf16(af0, b00, z, 0, 0, 0);
            t0 = __builtin_amdgcn_mfma_f32_16x16x32_bf16(af1, b01, t0, 0, 0, 0);
            f32x4 t1 = __builtin_amdgcn_mfma_f32_16x16x32_bf16(af0, b10, z, 0, 0, 0);
            t1 = __builtin_amdgcn_mfma_f32_16x16x32_bf16(af1, b11, t1, 0, 0, 0);
            const float* sp = &s_ac[h * 68 + wv * 16 + kg * 4];
#pragma unroll
            for (int r = 0; r < 4; ++r) {
                float sc = sp[r];
                acc0[r] += sc * t0[r];
                acc1[r] += sc * t1[r];
            }
        }
        if (it < 31) {
#pragma unroll
            for (int i = 0; i < 2; ++i) {
                int c = t + 256 * i;
                int h1 = c >> 8, d = (c >> 3) & 31, w8 = (c & 7) << 3;
                *(uint4*)&vvT[((cur ^ 1) * 2 + h1) * 32 * 72 + d * 72 + w8] = pre[i];
            }
        }
        __syncthreads();
    }

    const int lbase = l0 + wv * 16 + kg * 4;
#pragma unroll
    for (int r = 0; r < 4; ++r) {
        if (lbase + r < 300) {
            ushort* op = out + ((size_t)b * 300 + lbase + r) * 256 + nh * 32;
            op[lo] = f2b(acc0[r]);
            op[16 + lo] = f2b(acc1[r]);
        }
    }
}

extern "C" void kernel_launch(void* const* d_in, const int* in_sizes, int n_in,
                              void* d_out, int out_size, void* d_ws, size_t ws_size,
                              hipStream_t stream)
{
    (void)in_sizes; (void)n_in; (void)out_size; (void)ws_size;
    const float* tgt   = (const float*)d_in[0];
    const float* qpos  = (const float*)d_in[1];
    const float* qpx   = (const float*)d_in[2];
    const float* qpy   = (const float*)d_in[3];
    const float* srcs  = (const float*)d_in[4];
    const float* prow  = (const float*)d_in[6];
    const float* pcol  = (const float*)d_in[7];
    const float* sa_w  = (const float*)d_in[8];
    const float* sa_b  = (const float*)d_in[9];
    const float* sa_ow = (const float*)d_in[10];
    const float* sa_ob = (const float*)d_in[11];
    const float* ca_w  = (const float*)d_in[12];
    const float* ca_b  = (const float*)d_in[13];
    const float* ca_ow = (const float*)d_in[14];
    const float* ca_ob = (const float*)d_in[15];
    const float* n1w   = (const float*)d_in[16];
    const float* n1b   = (const float*)d_in[17];
    const float* n2w   = (const float*)d_in[18];
    const float* n2b   = (const float*)d_in[19];
    const float* l1w   = (const float*)d_in[20];
    const float* l1b   = (const float*)d_in[21];
    const float* l2w   = (const float*)d_in[22];
    const float* l2b   = (const float*)d_in[23];
    const float* nfw   = (const float*)d_in[24];
    const float* nfb   = (const float*)d_in[25];
    float* out = (float*)d_out;
    float* ws  = (float*)d_ws;

    float* tgt2  = ws + 1228800;
    float* tgt3  = ws + 2457600;
    float* rowm  = ws + 3686400;       // (B,64,E) f32
    float* colm  = ws + 3948544;
    ushort* u    = (ushort*)(ws + 4210688);
    ushort* q16    = u;                // (B,H,L,HD)
    ushort* k16    = u + 1228800;
    ushort* v16    = u + 2457600;
    ushort* ctx16  = u + 3686400;      // (B,L,E)
    ushort* qrow16 = u + 4915200;
    ushort* qcol16 = u + 6144000;
    ushort* krow16 = u + 7372800;      // (B,H,64,HD)
    ushort* kcol16 = u + 7634944;
    ushort* ffm16  = u + 7897088;      // (B,L,FF)
    ushort* vvb    = u + 12812288;     // vvT: (B*H)[h][d][w] bf16

    // ---- Phase 1: vv GEMM + qkv proj + means (independent; one launch) ----
    phase1<<<6920,256,0,stream>>>(
        srcs, ca_w + 4*65536, ca_b + 1024, vvb,
        tgt, qpos, sa_w, sa_b, q16, k16, v16,
        rowm, colm);

    // ---- Self-attention ----
    sa_fused<<<dim3(5,128),256,0,stream>>>(q16, k16, v16, ctx16);
    mgemm_ln<256><<<300,256,0,stream>>>(ctx16, sa_ow, sa_ob, tgt, n2w, n2b, tgt2);

    // ---- Cross-attention maps ----
    mgemm_maps<<<dim3(75,8,4),256,0,stream>>>(
        tgt2, tgt2, rowm, colm,
        qpx, qpy, prow, pcol,
        ca_w, ca_w + 65536, ca_w + 2*65536, ca_w + 3*65536,
        ca_b, ca_b + 256, ca_b + 512, ca_b + 768,
        qrow16, qcol16, krow16, kcol16);

    // ---- CA fused core + out proj + LN ----
    ca_fused<<<dim3(5,8,16),256,0,stream>>>(qrow16, qcol16, krow16, kcol16, vvb, ctx16);
    mgemm_ln<256><<<300,256,0,stream>>>(ctx16, ca_ow, ca_ob, tgt2, n1w, n1b, tgt3);

    // ---- FFN ----
    mgemm<64,128,0,false,true,3><<<dim3(75,8),256,0,stream>>>(
        tgt3, nullptr, l1w, l1b, ffm16, nullptr, nullptr, 4800, 1024, 256, 0, 1.f, 0);
    mgemm_ln<1024><<<300,256,0,stream>>>(ffm16, l2w, l2b, tgt3, nfw, nfb, out);
}

// Round 14
// 192.124 us; speedup vs baseline: 1.1009x; 1.1009x over previous
//
#include <hip/hip_runtime.h>

#define B_ 16
#define L_ 300
#define E_ 256
#define H_ 8
#define HD_ 32
#define FF_ 1024
#define SCALE_ 0.17677669529663687f
#define EPS_ 1e-5f

typedef __attribute__((ext_vector_type(8))) short bf16x8;
typedef __attribute__((ext_vector_type(4))) float f32x4;

__device__ __forceinline__ ushort f2b(float f) {
    unsigned u = __float_as_uint(f);
    u += 0x7fff + ((u >> 16) & 1);
    return (ushort)(u >> 16);
}
// packed f32x2 -> bf16x2 via HW cvt (RNE), 1 VALU op
__device__ __forceinline__ unsigned pk2(float a, float b) {
    unsigned r;
    asm("v_cvt_pk_bf16_f32 %0, %1, %2" : "=v"(r) : "v"(a), "v"(b));
    return r;
}

// ---------------- Pipelined bf16 MFMA GEMM, depth-2 register prefetch ----------------
// AMODE: 0 = f32 A (+ADD2 if n0<a2lim); 2 = bf16 A row-major; 3 = srcs layout (BM=128).
// CL: 1 = bf16 BHLD 3-way dest (qscale on gn<256); 2 = bf16 vvT [b*8+nh][h][d][w];
//     3 = bf16 row-major.
template<int BM, int BN, int AMODE, bool ADD2, bool RELU, int CL, bool DUAL, bool SWZ>
__global__ __launch_bounds__(256) void mgemm(
    const void* __restrict__ A_, const float* __restrict__ A2_,
    const float* __restrict__ W_, const float* __restrict__ bias_,
    void* __restrict__ C0_, void* __restrict__ C1_,
    void* __restrict__ C2_, int M, int N, int K, int Lh, float qscale, int a2lim,
    const void* __restrict__ Ab_, const float* __restrict__ A2b_,
    const float* __restrict__ Wb_, const float* __restrict__ biasb_, void* __restrict__ C0b_)
{
    constexpr int TM = BM / 2, TN = BN / 2;
    constexpr int FM = TM / 16, FN = TN / 16;
    constexpr int LDT = 40;
    constexpr int NAR = (AMODE == 2) ? (BM / 64) : (BM / 32);
    constexpr int NWR = BN / 32;
    __shared__ ushort sA[BM * LDT];
    __shared__ ushort sW[BN * LDT];
    const int t = threadIdx.x;
    const int lane = t & 63, wv = t >> 6;
    const int lo = lane & 15, kg = lane >> 4;
    const int wm = wv >> 1, wn = wv & 1;
    int bx = blockIdx.x, by = blockIdx.y;
    if constexpr (SWZ) {
        int linear = blockIdx.x + gridDim.x * blockIdx.y;
        int xcd = linear & 7, s = linear >> 3;
        by = s & 1; bx = (s >> 1) * 8 + xcd;
    }
    const int m0 = bx * BM, n0 = by * BN;

    const void* Ap = A_; const float* A2p = A2_; const float* Wp = W_;
    const float* biasp = bias_; void* C0v = C0_;
    if constexpr (DUAL) {
        if (blockIdx.z) { Ap = Ab_; A2p = A2b_; Wp = Wb_; biasp = biasb_; C0v = C0b_; }
    }

    struct RS {
        float4 ra[(AMODE == 0) ? NAR : 1];
        uint4  ra16[(AMODE == 2) ? NAR : 1];
        float  ra3[(AMODE == 3) ? 16 : 1];
        float4 rw[NWR];
    };
    RS s0, s1;

    auto LOAD = [&](int k0, RS& S) {
        if constexpr (AMODE == 0) {
            const float* A = (const float*)Ap;
#pragma unroll
            for (int i = 0; i < NAR; ++i) {
                int e = t + 256 * i;
                int m = e >> 3, kc = (e & 7) << 2;
                float4 va = *(const float4*)(A + (size_t)(m0 + m) * K + k0 + kc);
                if constexpr (ADD2) {
                    if (n0 < a2lim) {
                        float4 v2 = *(const float4*)(A2p + (size_t)(m0 + m) * K + k0 + kc);
                        va.x += v2.x; va.y += v2.y; va.z += v2.z; va.w += v2.w;
                    }
                }
                S.ra[i] = va;
            }
        } else if constexpr (AMODE == 2) {
            const ushort* A = (const ushort*)Ap;
#pragma unroll
            for (int i = 0; i < NAR; ++i) {
                int e = t + 256 * i;
                int m = e >> 2, c = (e & 3) << 3;
                S.ra16[i] = *(const uint4*)(A + (size_t)(m0 + m) * K + k0 + c);
            }
        } else {
            const float* A = (const float*)Ap;
            const int bb = m0 >> 12, p0 = m0 & 4095;
#pragma unroll
            for (int i = 0; i < 2; ++i) {
                int e = t + 256 * i;
                int m = e & 127, kslot = e >> 7;
                const float* base = A + ((size_t)(bb * 256 + k0 + kslot * 8)) * 4096 + p0 + m;
#pragma unroll
                for (int j = 0; j < 8; ++j) S.ra3[i * 8 + j] = base[(size_t)j * 4096];
            }
        }
#pragma unroll
        for (int i = 0; i < NWR; ++i) {
            int e = t + 256 * i;
            int n = e >> 3, kc = (e & 7) << 2;
            S.rw[i] = *(const float4*)(Wp + (size_t)(n0 + n) * K + k0 + kc);
        }
    };
    auto STORE = [&](RS& S) {
        if constexpr (AMODE == 0) {
#pragma unroll
            for (int i = 0; i < NAR; ++i) {
                int e = t + 256 * i;
                int m = e >> 3, kc = (e & 7) << 2;
                uint2 pk; pk.x = pk2(S.ra[i].x, S.ra[i].y); pk.y = pk2(S.ra[i].z, S.ra[i].w);
                *(uint2*)&sA[m * LDT + kc] = pk;
            }
        } else if constexpr (AMODE == 2) {
#pragma unroll
            for (int i = 0; i < NAR; ++i) {
                int e = t + 256 * i;
                int m = e >> 2, c = (e & 3) << 3;
                *(uint4*)&sA[m * LDT + c] = S.ra16[i];
            }
        } else {
#pragma unroll
            for (int i = 0; i < 2; ++i) {
                int e = t + 256 * i;
                int m = e & 127, kslot = e >> 7;
                uint4 pk;
                pk.x = pk2(S.ra3[i * 8 + 0], S.ra3[i * 8 + 1]);
                pk.y = pk2(S.ra3[i * 8 + 2], S.ra3[i * 8 + 3]);
                pk.z = pk2(S.ra3[i * 8 + 4], S.ra3[i * 8 + 5]);
                pk.w = pk2(S.ra3[i * 8 + 6], S.ra3[i * 8 + 7]);
                *(uint4*)&sA[m * LDT + kslot * 8] = pk;
            }
        }
#pragma unroll
        for (int i = 0; i < NWR; ++i) {
            int e = t + 256 * i;
            int n = e >> 3, kc = (e & 7) << 2;
            uint2 pk; pk.x = pk2(S.rw[i].x, S.rw[i].y); pk.y = pk2(S.rw[i].z, S.rw[i].w);
            *(uint2*)&sW[n * LDT + kc] = pk;
        }
    };

    f32x4 acc[FM][FN];
#pragma unroll
    for (int i = 0; i < FM; ++i)
#pragma unroll
        for (int j = 0; j < FN; ++j) acc[i][j] = (f32x4){0.f, 0.f, 0.f, 0.f};

    auto MFMAstep = [&]() {
        bf16x8 af[FM], bfr[FN];
#pragma unroll
        for (int mi = 0; mi < FM; ++mi)
            af[mi] = *(const bf16x8*)&sA[(wm * TM + mi * 16 + lo) * LDT + kg * 8];
#pragma unroll
        for (int ni = 0; ni < FN; ++ni)
            bfr[ni] = *(const bf16x8*)&sW[(wn * TN + ni * 16 + lo) * LDT + kg * 8];
#pragma unroll
        for (int mi = 0; mi < FM; ++mi)
#pragma unroll
            for (int ni = 0; ni < FN; ++ni)
                acc[mi][ni] = __builtin_amdgcn_mfma_f32_16x16x32_bf16(af[mi], bfr[ni], acc[mi][ni], 0, 0, 0);
    };

    LOAD(0, s0); LOAD(32, s1);
    for (int k0 = 0; k0 < K; k0 += 64) {
        STORE(s0);
        __syncthreads();
        if (k0 + 64 < K) LOAD(k0 + 64, s0);
        MFMAstep();
        __syncthreads();
        STORE(s1);
        __syncthreads();
        if (k0 + 96 < K) LOAD(k0 + 96, s1);
        MFMAstep();
        __syncthreads();
    }

    if constexpr (CL == 2) {
#pragma unroll
        for (int mi = 0; mi < FM; ++mi) {
            const int gmb = m0 + wm * TM + mi * 16 + kg * 4;
            const int b = gmb >> 12, p = gmb & 4095;
            const int h = p >> 6, w = p & 63;
#pragma unroll
            for (int ni = 0; ni < FN; ++ni) {
                const int gn = n0 + wn * TN + ni * 16 + lo;
                const int nh = gn >> 5, dd = gn & 31;
                const float bs = biasp[gn];
                uint2 pk;
                pk.x = pk2(acc[mi][ni][0] + bs, acc[mi][ni][1] + bs);
                pk.y = pk2(acc[mi][ni][2] + bs, acc[mi][ni][3] + bs);
                *(uint2*)((ushort*)C0v + ((size_t)(b * 8 + nh)) * 131072 + h * 2048 + dd * 64 + w) = pk;
            }
        }
    } else {
#pragma unroll
        for (int mi = 0; mi < FM; ++mi) {
#pragma unroll
            for (int r = 0; r < 4; ++r) {
                const int gm = m0 + wm * TM + mi * 16 + kg * 4 + r;
#pragma unroll
                for (int ni = 0; ni < FN; ++ni) {
                    const int gn = n0 + wn * TN + ni * 16 + lo;
                    float v = acc[mi][ni][r] + biasp[gn];
                    if constexpr (RELU) v = fmaxf(v, 0.f);
                    if constexpr (CL == 1) {
                        if (gn < 256) v *= qscale;
                        int head = (gn & 255) >> 5, d = gn & 31;
                        ushort* dst = (gn < 256) ? (ushort*)C0v
                                     : (gn < 512 ? (ushort*)C1_ : (ushort*)C2_);
                        int b = gm / Lh, l = gm - b * Lh;
                        dst[(((size_t)b * H_ + head) * Lh + l) * HD_ + d] = f2b(v);
                    } else {
                        ushort* C0 = (ushort*)C0v;
                        C0[(size_t)gm * N + gn] = f2b(v);
                    }
                }
            }
        }
    }
}

// ---------------- Merged CA map projections: z = {qrow, qcol, krow, kcol} ----------------
__global__ __launch_bounds__(256) void mgemm_maps(
    const float* __restrict__ A0, const float* __restrict__ A1,
    const float* __restrict__ A2x, const float* __restrict__ A3,
    const float* __restrict__ P0, const float* __restrict__ P1,
    const float* __restrict__ P2, const float* __restrict__ P3,
    const float* __restrict__ W0, const float* __restrict__ W1,
    const float* __restrict__ W2, const float* __restrict__ W3,
    const float* __restrict__ B0, const float* __restrict__ B1,
    const float* __restrict__ B2, const float* __restrict__ B3,
    ushort* __restrict__ C0, ushort* __restrict__ C1,
    ushort* __restrict__ C2, ushort* __restrict__ C3)
{
    constexpr int LDT = 40;
    __shared__ ushort sA[64 * LDT];
    __shared__ ushort sW[32 * LDT];
    const int z = blockIdx.z;
    const int M = (z < 2) ? 4800 : 1024;
    const int m0 = blockIdx.x * 64;
    if (m0 >= M) return;
    const int Lh = (z < 2) ? 300 : 64;
    const float qs = (z < 2) ? SCALE_ : 1.f;
    const float* Ap = (z == 0) ? A0 : (z == 1) ? A1 : (z == 2) ? A2x : A3;
    const float* Pp = (z == 0) ? P0 : (z == 1) ? P1 : (z == 2) ? P2 : P3;
    const float* Wp = (z == 0) ? W0 : (z == 1) ? W1 : (z == 2) ? W2 : W3;
    const float* Bp = (z == 0) ? B0 : (z == 1) ? B1 : (z == 2) ? B2 : B3;
    ushort* Cp = (z == 0) ? C0 : (z == 1) ? C1 : (z == 2) ? C2 : C3;
    const int t = threadIdx.x, lane = t & 63, wv = t >> 6;
    const int lo = lane & 15, kg = lane >> 4;
    const int wm = wv >> 1, wn = wv & 1;
    const int n0 = blockIdx.y * 32;

    float4 ra0[2], ra1[2], rw0, rw1;
    auto LOAD = [&](int k0, float4 (&ra)[2], float4& rw) {
#pragma unroll
        for (int i = 0; i < 2; ++i) {
            int e = t + 256 * i;
            int m = e >> 3, kc = (e & 7) << 2;
            float4 va = *(const float4*)(Ap + (size_t)(m0 + m) * 256 + k0 + kc);
            float4 v2 = *(const float4*)(Pp + (size_t)(m0 + m) * 256 + k0 + kc);
            va.x += v2.x; va.y += v2.y; va.z += v2.z; va.w += v2.w;
            ra[i] = va;
        }
        int n = t >> 3, kc = (t & 7) << 2;
        rw = *(const float4*)(Wp + (size_t)(n0 + n) * 256 + k0 + kc);
    };
    auto STORE = [&](float4 (&ra)[2], float4& rw) {
#pragma unroll
        for (int i = 0; i < 2; ++i) {
            int e = t + 256 * i;
            int m = e >> 3, kc = (e & 7) << 2;
            uint2 pk; pk.x = pk2(ra[i].x, ra[i].y); pk.y = pk2(ra[i].z, ra[i].w);
            *(uint2*)&sA[m * LDT + kc] = pk;
        }
        int n = t >> 3, kc = (t & 7) << 2;
        uint2 pk; pk.x = pk2(rw.x, rw.y); pk.y = pk2(rw.z, rw.w);
        *(uint2*)&sW[n * LDT + kc] = pk;
    };

    f32x4 acc[2];
    acc[0] = (f32x4){0.f, 0.f, 0.f, 0.f};
    acc[1] = (f32x4){0.f, 0.f, 0.f, 0.f};
    auto MFMAstep = [&]() {
        bf16x8 bfr = *(const bf16x8*)&sW[(wn * 16 + lo) * LDT + kg * 8];
#pragma unroll
        for (int mi = 0; mi < 2; ++mi) {
            bf16x8 af = *(const bf16x8*)&sA[(wm * 32 + mi * 16 + lo) * LDT + kg * 8];
            acc[mi] = __builtin_amdgcn_mfma_f32_16x16x32_bf16(af, bfr, acc[mi], 0, 0, 0);
        }
    };

    LOAD(0, ra0, rw0); LOAD(32, ra1, rw1);
    for (int k0 = 0; k0 < 256; k0 += 64) {
        STORE(ra0, rw0);
        __syncthreads();
        if (k0 + 64 < 256) LOAD(k0 + 64, ra0, rw0);
        MFMAstep();
        __syncthreads();
        STORE(ra1, rw1);
        __syncthreads();
        if (k0 + 96 < 256) LOAD(k0 + 96, ra1, rw1);
        MFMAstep();
        __syncthreads();
    }

#pragma unroll
    for (int mi = 0; mi < 2; ++mi) {
#pragma unroll
        for (int r = 0; r < 4; ++r) {
            const int gm = m0 + wm * 32 + mi * 16 + kg * 4 + r;
            const int gn = n0 + wn * 16 + lo;
            float v = (acc[mi][r] + Bp[gn]) * qs;
            int head = gn >> 5, d = gn & 31;
            int b = gm / Lh, l = gm - b * Lh;
            Cp[(((size_t)b * H_ + head) * Lh + l) * HD_ + d] = f2b(v);
        }
    }
}

// ---------------- GEMM + residual + LayerNorm fused (BM=16, BN=256=N, bf16 A) ----------------
template<int KK>
__global__ __launch_bounds__(256) void mgemm_ln(
    const ushort* __restrict__ A, const float* __restrict__ W,
    const float* __restrict__ bias, const float* __restrict__ res,
    const float* __restrict__ gw, const float* __restrict__ gb, float* __restrict__ O)
{
    constexpr int LDT = 40;
    __shared__ ushort sA[16 * LDT];
    __shared__ ushort sW[256 * LDT];
    __shared__ float red[4][16][2];
    const int t = threadIdx.x, lane = t & 63, wv = t >> 6;
    const int lo = lane & 15, kg = lane >> 4;
    const int m0 = blockIdx.x * 16;
    const bool aact = (t < 128);

    uint2 a0, a1;
    float4 w0[8], w1[8];
    auto LOADA = [&](int k0, uint2& aa) {
        if (aact) aa = *(const uint2*)(A + (size_t)(m0 + (t >> 3)) * KK + k0 + ((t & 7) << 2));
    };
    auto LOADW = [&](int k0, float4 (&ww)[8]) {
#pragma unroll
        for (int i = 0; i < 8; ++i) {
            int e = t + 256 * i;
            int n = e >> 3, kc = (e & 7) << 2;
            ww[i] = *(const float4*)(W + (size_t)n * KK + k0 + kc);
        }
    };
    auto STOREA = [&](uint2& aa) {
        if (aact) *(uint2*)&sA[(t >> 3) * LDT + ((t & 7) << 2)] = aa;
    };
    auto STOREW = [&](float4 (&ww)[8]) {
#pragma unroll
        for (int i = 0; i < 8; ++i) {
            int e = t + 256 * i;
            int n = e >> 3, kc = (e & 7) << 2;
            uint2 pk; pk.x = pk2(ww[i].x, ww[i].y); pk.y = pk2(ww[i].z, ww[i].w);
            *(uint2*)&sW[n * LDT + kc] = pk;
        }
    };

    f32x4 acc[4];
#pragma unroll
    for (int i = 0; i < 4; ++i) acc[i] = (f32x4){0.f, 0.f, 0.f, 0.f};

    auto MFMAstep = [&]() {
        bf16x8 af = *(const bf16x8*)&sA[lo * LDT + kg * 8];
#pragma unroll
        for (int ni = 0; ni < 4; ++ni) {
            bf16x8 bfr = *(const bf16x8*)&sW[(wv * 64 + ni * 16 + lo) * LDT + kg * 8];
            acc[ni] = __builtin_amdgcn_mfma_f32_16x16x32_bf16(af, bfr, acc[ni], 0, 0, 0);
        }
    };

    LOADA(0, a0); LOADW(0, w0);
    LOADA(32, a1); LOADW(32, w1);
    for (int k0 = 0; k0 < KK; k0 += 64) {
        STOREA(a0); STOREW(w0);
        __syncthreads();
        if (k0 + 64 < KK) { LOADA(k0 + 64, a0); LOADW(k0 + 64, w0); }
        MFMAstep();
        __syncthreads();
        STOREA(a1); STOREW(w1);
        __syncthreads();
        if (k0 + 96 < KK) { LOADA(k0 + 96, a1); LOADW(k0 + 96, w1); }
        MFMAstep();
        __syncthreads();
    }

    const int gmb = m0 + kg * 4;
    float vvv[4][4];
    float ps[4] = {0.f, 0.f, 0.f, 0.f}, qs[4] = {0.f, 0.f, 0.f, 0.f};
#pragma unroll
    for (int ni = 0; ni < 4; ++ni) {
        const int gn = wv * 64 + ni * 16 + lo;
        const float bs = bias[gn];
#pragma unroll
        for (int r = 0; r < 4; ++r) {
            float x = acc[ni][r] + bs + res[(size_t)(gmb + r) * 256 + gn];
            vvv[ni][r] = x;
            ps[r] += x;
            qs[r] += x * x;
        }
    }
#pragma unroll
    for (int off = 1; off < 16; off <<= 1) {
#pragma unroll
        for (int r = 0; r < 4; ++r) {
            ps[r] += __shfl_xor(ps[r], off);
            qs[r] += __shfl_xor(qs[r], off);
        }
    }
    if (lo == 0) {
#pragma unroll
        for (int r = 0; r < 4; ++r) {
            red[wv][kg * 4 + r][0] = ps[r];
            red[wv][kg * 4 + r][1] = qs[r];
        }
    }
    __syncthreads();
    float mean[4], rs[4];
#pragma unroll
    for (int r = 0; r < 4; ++r) {
        const int row = kg * 4 + r;
        float s = red[0][row][0] + red[1][row][0] + red[2][row][0] + red[3][row][0];
        float q = red[0][row][1] + red[1][row][1] + red[2][row][1] + red[3][row][1];
        mean[r] = s * (1.f / 256.f);
        float var = q * (1.f / 256.f) - mean[r] * mean[r];
        rs[r] = rsqrtf(var + EPS_);
    }
#pragma unroll
    for (int ni = 0; ni < 4; ++ni) {
        const int gn = wv * 64 + ni * 16 + lo;
        const float g = gw[gn], b2 = gb[gn];
#pragma unroll
        for (int r = 0; r < 4; ++r)
            O[(size_t)(gmb + r) * 256 + gn] = (vvv[ni][r] - mean[r]) * rs[r] * g + b2;
    }
}

// ---------------- Fused SA attention; LDS-aliased; XCD-grouped ----------------
__global__ __launch_bounds__(256) void sa_fused(const ushort* __restrict__ q,
    const ushort* __restrict__ k, const ushort* __restrict__ v, ushort* __restrict__ ctx)
{
    __shared__ __align__(16) char sm[62976];
    ushort* Vt = (ushort*)sm;             // [d][key] 32 x 328
    ushort* Kt = (ushort*)(sm + 20992);   // [key][d] 304 x 40
    ushort* Pt = (ushort*)(sm + 20992);   // [wv][l][key] 4 x 16 x 328 (aliases Kt)
    const int t = threadIdx.x, lane = t & 63, wv = t >> 6;
    const int lo = lane & 15, kg = lane >> 4;
    const int linear = blockIdx.x + 5 * blockIdx.y;
    const int xcd = linear & 7, slot = linear >> 3;
    const int l0 = (slot % 5) * 64;
    const int bh = xcd + 8 * (slot / 5);
    const ushort* qp = q + (size_t)bh * 9600;
    const ushort* kp = k + (size_t)bh * 9600;
    const ushort* vp = v + (size_t)bh * 9600;

    for (int e = t; e < 1216; e += 256) {
        int row = e >> 2, dq = (e & 3) << 3;
        uint4 kv = (row < 300) ? *(const uint4*)(kp + row * 32 + dq)
                               : make_uint4(0, 0, 0, 0);
        *(uint4*)&Kt[row * 40 + dq] = kv;
    }
    for (int e = t; e < 1200; e += 256) {
        int row = e >> 2, dq = (e & 3) << 3;
        uint4 vv4 = *(const uint4*)(vp + row * 32 + dq);
        const ushort* sv = (const ushort*)&vv4;
#pragma unroll
        for (int j = 0; j < 8; ++j) Vt[(dq + j) * 328 + row] = sv[j];
    }
    for (int e = t; e < 32 * 28; e += 256) {
        int d = e / 28, kk = 300 + e % 28;
        Vt[d * 328 + kk] = 0;
    }
    const int ql = l0 + wv * 16 + lo;
    bf16x8 qf = {0, 0, 0, 0, 0, 0, 0, 0};
    if (ql < 300) qf = *(const bf16x8*)(qp + ql * 32 + kg * 8);
    __syncthreads();

    f32x4 s[19];
#pragma unroll
    for (int f = 0; f < 19; ++f) {
        bf16x8 af = *(const bf16x8*)&Kt[(f * 16 + lo) * 40 + kg * 8];
        f32x4 z = {0.f, 0.f, 0.f, 0.f};
        s[f] = __builtin_amdgcn_mfma_f32_16x16x32_bf16(af, qf, z, 0, 0, 0);
    }
    if (kg == 3) { s[18][0] = -3.4e38f; s[18][1] = -3.4e38f; s[18][2] = -3.4e38f; s[18][3] = -3.4e38f; }

    float mx = -3.4e38f;
#pragma unroll
    for (int f = 0; f < 19; ++f)
#pragma unroll
        for (int r = 0; r < 4; ++r) mx = fmaxf(mx, s[f][r]);
    mx = fmaxf(mx, __shfl_xor(mx, 16));
    mx = fmaxf(mx, __shfl_xor(mx, 32));
    float sum = 0.f;
#pragma unroll
    for (int f = 0; f < 19; ++f)
#pragma unroll
        for (int r = 0; r < 4; ++r) { s[f][r] = __expf(s[f][r] - mx); sum += s[f][r]; }
    sum += __shfl_xor(sum, 16);
    sum += __shfl_xor(sum, 32);
    const float inv = 1.f / sum;

    __syncthreads();   // all waves done reading Kt; Pt may overwrite

    ushort* Ptw = Pt + wv * (16 * 328);
#pragma unroll
    for (int f = 0; f < 19; ++f) {
        *(unsigned*)&Ptw[lo * 328 + f * 16 + kg * 4]     = pk2(s[f][0] * inv, s[f][1] * inv);
        *(unsigned*)&Ptw[lo * 328 + f * 16 + kg * 4 + 2] = pk2(s[f][2] * inv, s[f][3] * inv);
    }
    {
        uint2 z2 = make_uint2(0, 0);
        *(uint2*)&Ptw[(lane & 15) * 328 + 304 + ((lane >> 4) << 2)] = z2;
    }

    f32x4 o0 = {0.f, 0.f, 0.f, 0.f}, o1 = {0.f, 0.f, 0.f, 0.f};
#pragma unroll
    for (int f = 0; f < 10; ++f) {
        bf16x8 pa = *(const bf16x8*)&Ptw[lo * 328 + f * 32 + kg * 8];
        bf16x8 b0 = *(const bf16x8*)&Vt[lo * 328 + f * 32 + kg * 8];
        bf16x8 b1 = *(const bf16x8*)&Vt[(16 + lo) * 328 + f * 32 + kg * 8];
        o0 = __builtin_amdgcn_mfma_f32_16x16x32_bf16(pa, b0, o0, 0, 0, 0);
        o1 = __builtin_amdgcn_mfma_f32_16x16x32_bf16(pa, b1, o1, 0, 0, 0);
    }

    const int lb = l0 + wv * 16 + kg * 4;
    const int b = bh >> 3, h = bh & 7;
#pragma unroll
    for (int r = 0; r < 4; ++r) {
        int l = lb + r;
        if (l < 300) {
            ushort* op = ctx + ((size_t)b * 300 + l) * 256 + h * 32;
            op[lo] = f2b(o0[r]);
            op[lo + 16] = f2b(o1[r]);
        }
    }
}

// ---------------- Fused CA; LDS-aliased; XCD-grouped (depth-1 vv prefetch) ----------------
__global__ __launch_bounds__(256) void ca_fused(const ushort* __restrict__ qr,
    const ushort* __restrict__ qc, const ushort* __restrict__ kr, const ushort* __restrict__ kc,
    const ushort* __restrict__ vv, ushort* __restrict__ out)
{
    __shared__ __align__(16) char sm[45056];
    ushort* s_ar = (ushort*)sm;             // [l][w] 64 x 72 bf16
    float*  s_ac = (float*)(sm + 9216);     // [h][l] 64 x 68 f32
    ushort* Kr   = (ushort*)(sm + 26624);   // 64 x 40
    ushort* Kc   = (ushort*)(sm + 31744);   // 64 x 40
    ushort* vvT  = (ushort*)(sm + 26624);   // [buf][h'][d][w] 2 x 2 x 32 x 72

    const int t = threadIdx.x, lane = t & 63, wv = t >> 6;
    const int lo = lane & 15, kg = lane >> 4;
    const int linear = blockIdx.x + 5 * (blockIdx.y + 8 * blockIdx.z);
    const int xcd = linear & 7, slot = linear >> 3;
    const int l0 = (slot % 5) * 64;
    const int bh = xcd + 8 * (slot / 5);
    const int nh = bh & 7, b = bh >> 3;

    {
        const ushort* krp = kr + (size_t)bh * 2048;
        const ushort* kcp = kc + (size_t)bh * 2048;
        int row = t >> 2, dq = (t & 3) << 3;
        *(uint4*)&Kr[row * 40 + dq] = *(const uint4*)(krp + row * 32 + dq);
        *(uint4*)&Kc[row * 40 + dq] = *(const uint4*)(kcp + row * 32 + dq);
    }
    const int ql = l0 + wv * 16 + lo;
    bf16x8 qrf = {0,0,0,0,0,0,0,0}, qcf = {0,0,0,0,0,0,0,0};
    if (ql < 300) {
        qrf = *(const bf16x8*)(qr + (size_t)bh * 9600 + ql * 32 + kg * 8);
        qcf = *(const bf16x8*)(qc + (size_t)bh * 9600 + ql * 32 + kg * 8);
    }
    const ushort* vvp = vv + (size_t)bh * 131072;
    __syncthreads();   // Kr/Kc staged

#pragma unroll
    for (int m = 0; m < 2; ++m) {
        const ushort* Kp = m ? Kc : Kr;
        const bf16x8 qf = m ? qcf : qrf;
        f32x4 s[4];
#pragma unroll
        for (int f = 0; f < 4; ++f) {
            bf16x8 af = *(const bf16x8*)&Kp[(f * 16 + lo) * 40 + kg * 8];
            f32x4 z = {0.f, 0.f, 0.f, 0.f};
            s[f] = __builtin_amdgcn_mfma_f32_16x16x32_bf16(af, qf, z, 0, 0, 0);
        }
        float mx = -3.4e38f;
#pragma unroll
        for (int f = 0; f < 4; ++f)
#pragma unroll
            for (int r = 0; r < 4; ++r) mx = fmaxf(mx, s[f][r]);
        mx = fmaxf(mx, __shfl_xor(mx, 16));
        mx = fmaxf(mx, __shfl_xor(mx, 32));
        float sum = 0.f;
#pragma unroll
        for (int f = 0; f < 4; ++f)
#pragma unroll
            for (int r = 0; r < 4; ++r) { s[f][r] = __expf(s[f][r] - mx); sum += s[f][r]; }
        sum += __shfl_xor(sum, 16);
        sum += __shfl_xor(sum, 32);
        const float inv = 1.f / sum;
        if (m == 0) {
#pragma unroll
            for (int f = 0; f < 4; ++f) {
                *(unsigned*)&s_ar[(wv * 16 + lo) * 72 + f * 16 + kg * 4]     = pk2(s[f][0] * inv, s[f][1] * inv);
                *(unsigned*)&s_ar[(wv * 16 + lo) * 72 + f * 16 + kg * 4 + 2] = pk2(s[f][2] * inv, s[f][3] * inv);
            }
        } else {
#pragma unroll
            for (int f = 0; f < 4; ++f)
#pragma unroll
                for (int r = 0; r < 4; ++r)
                    s_ac[(f * 16 + kg * 4 + r) * 68 + wv * 16 + lo] = s[f][r] * inv;
        }
    }

    __syncthreads();   // done reading Kr/Kc; vvT may overwrite

#pragma unroll
    for (int i = 0; i < 2; ++i) {
        int c = t + 256 * i;
        int h1 = c >> 8, d = (c >> 3) & 31, w8 = (c & 7) << 3;
        uint4 v4 = *(const uint4*)(vvp + h1 * 2048 + d * 64 + w8);
        *(uint4*)&vvT[(h1 * 32 + d) * 72 + w8] = v4;
    }
    __syncthreads();

    const bf16x8 af0 = *(const bf16x8*)&s_ar[(wv * 16 + lo) * 72 + kg * 8];
    const bf16x8 af1 = *(const bf16x8*)&s_ar[(wv * 16 + lo) * 72 + 32 + kg * 8];

    f32x4 acc0 = {0.f, 0.f, 0.f, 0.f};
    f32x4 acc1 = {0.f, 0.f, 0.f, 0.f};

    for (int it = 0; it < 32; ++it) {
        const int cur = it & 1;
        uint4 pre[2];
        if (it < 31) {
            const ushort* nxt = vvp + (size_t)(2 * (it + 1)) * 2048;
#pragma unroll
            for (int i = 0; i < 2; ++i) {
                int c = t + 256 * i;
                int h1 = c >> 8, d = (c >> 3) & 31, w8 = (c & 7) << 3;
                pre[i] = *(const uint4*)(nxt + h1 * 2048 + d * 64 + w8);
            }
        }
#pragma unroll
        for (int hh = 0; hh < 2; ++hh) {
            const int h = 2 * it + hh;
            const ushort* vt = &vvT[(cur * 2 + hh) * 32 * 72];
            bf16x8 b00 = *(const bf16x8*)&vt[lo * 72 + kg * 8];
            bf16x8 b01 = *(const bf16x8*)&vt[lo * 72 + 32 + kg * 8];
            bf16x8 b10 = *(const bf16x8*)&vt[(16 + lo) * 72 + kg * 8];
            bf16x8 b11 = *(const bf16x8*)&vt[(16 + lo) * 72 + 32 + kg * 8];
            f32x4 z = {0.f, 0.f, 0.f, 0.f};
            f32x4 t0 = __builtin_amdgcn_mfma_f32_16x16x32_bf16(af0, b00, z, 0, 0, 0);
            t0 = __builtin_amdgcn_mfma_f32_16x16x32_bf16(af1, b01, t0, 0, 0, 0);
            f32x4 t1 = __builtin_amdgcn_mfma_f32_16x16x32_bf16(af0, b10, z, 0, 0, 0);
            t1 = __builtin_amdgcn_mfma_f32_16x16x32_bf16(af1, b11, t1, 0, 0, 0);
            const float* sp = &s_ac[h * 68 + wv * 16 + kg * 4];
#pragma unroll
            for (int r = 0; r < 4; ++r) {
                float sc = sp[r];
                acc0[r] += sc * t0[r];
                acc1[r] += sc * t1[r];
            }
        }
        if (it < 31) {
#pragma unroll
            for (int i = 0; i < 2; ++i) {
                int c = t + 256 * i;
                int h1 = c >> 8, d = (c >> 3) & 31, w8 = (c & 7) << 3;
                *(uint4*)&vvT[((cur ^ 1) * 2 + h1) * 32 * 72 + d * 72 + w8] = pre[i];
            }
        }
        __syncthreads();
    }

    const int lbase = l0 + wv * 16 + kg * 4;
#pragma unroll
    for (int r = 0; r < 4; ++r) {
        if (lbase + r < 300) {
            ushort* op = out + ((size_t)b * 300 + lbase + r) * 256 + nh * 32;
            op[lo] = f2b(acc0[r]);
            op[16 + lo] = f2b(acc1[r]);
        }
    }
}

// ---------------- src means ----------------
__global__ __launch_bounds__(256) void means_kernel(const float* __restrict__ srcs,
    float* __restrict__ rowm, float* __restrict__ colm)
{
    const int bc = blockIdx.x;
    const int b = bc >> 8, c = bc & 255;
    const float* sp = srcs + (size_t)bc * 4096;
    __shared__ float tile[64][65];
    for (int e = threadIdx.x; e < 4096; e += 256) tile[e >> 6][e & 63] = sp[e];
    __syncthreads();
    const int t = threadIdx.x;
    if (t < 64) {
        float s = 0.f;
        for (int y = 0; y < 64; ++y) s += tile[y][t];
        rowm[((size_t)b * 64 + t) * 256 + c] = s * (1.f / 64.f);
    } else if (t < 128) {
        int y = t - 64;
        float s = 0.f;
        for (int x = 0; x < 64; ++x) s += tile[y][x];
        colm[((size_t)b * 64 + y) * 256 + c] = s * (1.f / 64.f);
    }
}

extern "C" void kernel_launch(void* const* d_in, const int* in_sizes, int n_in,
                              void* d_out, int out_size, void* d_ws, size_t ws_size,
                              hipStream_t stream)
{
    (void)in_sizes; (void)n_in; (void)out_size; (void)ws_size;
    const float* tgt   = (const float*)d_in[0];
    const float* qpos  = (const float*)d_in[1];
    const float* qpx   = (const float*)d_in[2];
    const float* qpy   = (const float*)d_in[3];
    const float* srcs  = (const float*)d_in[4];
    const float* prow  = (const float*)d_in[6];
    const float* pcol  = (const float*)d_in[7];
    const float* sa_w  = (const float*)d_in[8];
    const float* sa_b  = (const float*)d_in[9];
    const float* sa_ow = (const float*)d_in[10];
    const float* sa_ob = (const float*)d_in[11];
    const float* ca_w  = (const float*)d_in[12];
    const float* ca_b  = (const float*)d_in[13];
    const float* ca_ow = (const float*)d_in[14];
    const float* ca_ob = (const float*)d_in[15];
    const float* n1w   = (const float*)d_in[16];
    const float* n1b   = (const float*)d_in[17];
    const float* n2w   = (const float*)d_in[18];
    const float* n2b   = (const float*)d_in[19];
    const float* l1w   = (const float*)d_in[20];
    const float* l1b   = (const float*)d_in[21];
    const float* l2w   = (const float*)d_in[22];
    const float* l2b   = (const float*)d_in[23];
    const float* nfw   = (const float*)d_in[24];
    const float* nfb   = (const float*)d_in[25];
    float* out = (float*)d_out;
    float* ws  = (float*)d_ws;

    float* tgt2  = ws + 1228800;
    float* tgt3  = ws + 2457600;
    float* rowm  = ws + 3686400;       // (B,64,E) f32
    float* colm  = ws + 3948544;
    ushort* u    = (ushort*)(ws + 4210688);
    ushort* q16    = u;                // (B,H,L,HD)
    ushort* k16    = u + 1228800;
    ushort* v16    = u + 2457600;
    ushort* ctx16  = u + 3686400;      // (B,L,E)
    ushort* qrow16 = u + 4915200;
    ushort* qcol16 = u + 6144000;
    ushort* krow16 = u + 7372800;      // (B,H,64,HD)
    ushort* kcol16 = u + 7634944;
    ushort* ffm16  = u + 7897088;      // (B,L,FF)
    ushort* vvb    = u + 12812288;     // vvT: (B*H)[h][d][w] bf16

    // ---- Self-attention ----
    mgemm<64,32,0,true,false,1,false,false><<<dim3(75,24),256,0,stream>>>(
        tgt, qpos, sa_w, sa_b, q16, k16, v16, 4800, 768, 256, 300, SCALE_, 512,
        nullptr, nullptr, nullptr, nullptr, nullptr);
    sa_fused<<<dim3(5,128),256,0,stream>>>(q16, k16, v16, ctx16);
    mgemm_ln<256><<<300,256,0,stream>>>(ctx16, sa_ow, sa_ob, tgt, n2w, n2b, tgt2);

    // ---- Cross-attention prep ----
    means_kernel<<<4096,256,0,stream>>>(srcs, rowm, colm);
    mgemm_maps<<<dim3(75,8,4),256,0,stream>>>(
        tgt2, tgt2, rowm, colm,
        qpx, qpy, prow, pcol,
        ca_w, ca_w + 65536, ca_w + 2*65536, ca_w + 3*65536,
        ca_b, ca_b + 256, ca_b + 512, ca_b + 768,
        qrow16, qcol16, krow16, kcol16);
    mgemm<128,128,3,false,false,2,false,true><<<dim3(512,2),256,0,stream>>>(
        srcs, nullptr, ca_w + 4*65536, ca_b + 1024, vvb, nullptr, nullptr,
        65536, 256, 256, 0, 1.f, 0,
        nullptr, nullptr, nullptr, nullptr, nullptr);

    // ---- CA fused core + out proj + LN ----
    ca_fused<<<dim3(5,8,16),256,0,stream>>>(qrow16, qcol16, krow16, kcol16, vvb, ctx16);
    mgemm_ln<256><<<300,256,0,stream>>>(ctx16, ca_ow, ca_ob, tgt2, n1w, n1b, tgt3);

    // ---- FFN ----
    mgemm<64,128,0,false,true,3,false,false><<<dim3(75,8),256,0,stream>>>(
        tgt3, nullptr, l1w, l1b, ffm16, nullptr, nullptr, 4800, 1024, 256, 0, 1.f, 0,
        nullptr, nullptr, nullptr, nullptr, nullptr);
    mgemm_ln<1024><<<300,256,0,stream>>>(ffm16, l2w, l2b, tgt3, nfw, nfb, out);
}

// Round 15
// 190.717 us; speedup vs baseline: 1.1091x; 1.0074x over previous
//
#include <hip/hip_runtime.h>

#define B_ 16
#define L_ 300
#define E_ 256
#define H_ 8
#define HD_ 32
#define FF_ 1024
#define SCALE_ 0.17677669529663687f
#define EPS_ 1e-5f

typedef __attribute__((ext_vector_type(8))) short bf16x8;
typedef __attribute__((ext_vector_type(4))) float f32x4;

__device__ __forceinline__ ushort f2b(float f) {
    unsigned u = __float_as_uint(f);
    u += 0x7fff + ((u >> 16) & 1);
    return (ushort)(u >> 16);
}
// packed f32x2 -> bf16x2 via HW cvt (RNE), 1 VALU op
__device__ __forceinline__ unsigned pk2(float a, float b) {
    unsigned r;
    asm("v_cvt_pk_bf16_f32 %0, %1, %2" : "=v"(r) : "v"(a), "v"(b));
    return r;
}

// ---------------- Weight pre-conversion: all W matrices f32 -> bf16 pool ----------------
// segments (float4 units): sa_w 49152 | sa_ow 16384 | ca_w 81920 | ca_ow 16384 |
//                          l1w 65536 | l2w 65536   => total 294912 float4 (grid 1152)
__global__ __launch_bounds__(256) void convert_w(
    const float* __restrict__ w0, const float* __restrict__ w1,
    const float* __restrict__ w2, const float* __restrict__ w3,
    const float* __restrict__ w4, const float* __restrict__ w5,
    ushort* __restrict__ dst)
{
    int i4 = blockIdx.x * 256 + threadIdx.x;
    const float* src; int base4;
    if (i4 < 49152)       { src = w0; base4 = 0; }
    else if (i4 < 65536)  { src = w1; base4 = 49152; }
    else if (i4 < 147456) { src = w2; base4 = 65536; }
    else if (i4 < 163840) { src = w3; base4 = 147456; }
    else if (i4 < 229376) { src = w4; base4 = 163840; }
    else                  { src = w5; base4 = 229376; }
    float4 v = *(const float4*)(src + (size_t)(i4 - base4) * 4);
    uint2 pk; pk.x = pk2(v.x, v.y); pk.y = pk2(v.z, v.w);
    *(uint2*)(dst + (size_t)i4 * 4) = pk;
}

// ---------------- Pipelined bf16 MFMA GEMM, depth-2 register prefetch; bf16 W ----------------
// AMODE: 0 = f32 A (+ADD2 if n0<a2lim); 2 = bf16 A row-major; 3 = srcs layout (BM=128).
// CL: 1 = bf16 BHLD 3-way dest (qscale on gn<256); 2 = bf16 vvT [b*8+nh][h][d][w];
//     3 = bf16 row-major.
template<int BM, int BN, int AMODE, bool ADD2, bool RELU, int CL, bool DUAL, bool SWZ>
__global__ __launch_bounds__(256) void mgemm(
    const void* __restrict__ A_, const float* __restrict__ A2_,
    const ushort* __restrict__ W_, const float* __restrict__ bias_,
    void* __restrict__ C0_, void* __restrict__ C1_,
    void* __restrict__ C2_, int M, int N, int K, int Lh, float qscale, int a2lim,
    const void* __restrict__ Ab_, const float* __restrict__ A2b_,
    const ushort* __restrict__ Wb_, const float* __restrict__ biasb_, void* __restrict__ C0b_)
{
    constexpr int TM = BM / 2, TN = BN / 2;
    constexpr int FM = TM / 16, FN = TN / 16;
    constexpr int LDT = 40;
    constexpr int NAR = (AMODE == 2) ? (BM / 64) : (BM / 32);
    constexpr int NWR = BN / 32;
    __shared__ ushort sA[BM * LDT];
    __shared__ ushort sW[BN * LDT];
    const int t = threadIdx.x;
    const int lane = t & 63, wv = t >> 6;
    const int lo = lane & 15, kg = lane >> 4;
    const int wm = wv >> 1, wn = wv & 1;
    int bx = blockIdx.x, by = blockIdx.y;
    if constexpr (SWZ) {
        int linear = blockIdx.x + gridDim.x * blockIdx.y;
        int xcd = linear & 7, s = linear >> 3;
        by = s & 1; bx = (s >> 1) * 8 + xcd;
    }
    const int m0 = bx * BM, n0 = by * BN;

    const void* Ap = A_; const float* A2p = A2_; const ushort* Wp = W_;
    const float* biasp = bias_; void* C0v = C0_;
    if constexpr (DUAL) {
        if (blockIdx.z) { Ap = Ab_; A2p = A2b_; Wp = Wb_; biasp = biasb_; C0v = C0b_; }
    }

    struct RS {
        float4 ra[(AMODE == 0) ? NAR : 1];
        uint4  ra16[(AMODE == 2) ? NAR : 1];
        float  ra3[(AMODE == 3) ? 16 : 1];
        uint2  rw[NWR];
    };
    RS s0, s1;

    auto LOAD = [&](int k0, RS& S) {
        if constexpr (AMODE == 0) {
            const float* A = (const float*)Ap;
#pragma unroll
            for (int i = 0; i < NAR; ++i) {
                int e = t + 256 * i;
                int m = e >> 3, kc = (e & 7) << 2;
                float4 va = *(const float4*)(A + (size_t)(m0 + m) * K + k0 + kc);
                if constexpr (ADD2) {
                    if (n0 < a2lim) {
                        float4 v2 = *(const float4*)(A2p + (size_t)(m0 + m) * K + k0 + kc);
                        va.x += v2.x; va.y += v2.y; va.z += v2.z; va.w += v2.w;
                    }
                }
                S.ra[i] = va;
            }
        } else if constexpr (AMODE == 2) {
            const ushort* A = (const ushort*)Ap;
#pragma unroll
            for (int i = 0; i < NAR; ++i) {
                int e = t + 256 * i;
                int m = e >> 2, c = (e & 3) << 3;
                S.ra16[i] = *(const uint4*)(A + (size_t)(m0 + m) * K + k0 + c);
            }
        } else {
            const float* A = (const float*)Ap;
            const int bb = m0 >> 12, p0 = m0 & 4095;
#pragma unroll
            for (int i = 0; i < 2; ++i) {
                int e = t + 256 * i;
                int m = e & 127, kslot = e >> 7;
                const float* base = A + ((size_t)(bb * 256 + k0 + kslot * 8)) * 4096 + p0 + m;
#pragma unroll
                for (int j = 0; j < 8; ++j) S.ra3[i * 8 + j] = base[(size_t)j * 4096];
            }
        }
#pragma unroll
        for (int i = 0; i < NWR; ++i) {
            int e = t + 256 * i;
            int n = e >> 3, kc = (e & 7) << 2;
            S.rw[i] = *(const uint2*)(Wp + (size_t)(n0 + n) * K + k0 + kc);
        }
    };
    auto STORE = [&](RS& S) {
        if constexpr (AMODE == 0) {
#pragma unroll
            for (int i = 0; i < NAR; ++i) {
                int e = t + 256 * i;
                int m = e >> 3, kc = (e & 7) << 2;
                uint2 pk; pk.x = pk2(S.ra[i].x, S.ra[i].y); pk.y = pk2(S.ra[i].z, S.ra[i].w);
                *(uint2*)&sA[m * LDT + kc] = pk;
            }
        } else if constexpr (AMODE == 2) {
#pragma unroll
            for (int i = 0; i < NAR; ++i) {
                int e = t + 256 * i;
                int m = e >> 2, c = (e & 3) << 3;
                *(uint4*)&sA[m * LDT + c] = S.ra16[i];
            }
        } else {
#pragma unroll
            for (int i = 0; i < 2; ++i) {
                int e = t + 256 * i;
                int m = e & 127, kslot = e >> 7;
                uint4 pk;
                pk.x = pk2(S.ra3[i * 8 + 0], S.ra3[i * 8 + 1]);
                pk.y = pk2(S.ra3[i * 8 + 2], S.ra3[i * 8 + 3]);
                pk.z = pk2(S.ra3[i * 8 + 4], S.ra3[i * 8 + 5]);
                pk.w = pk2(S.ra3[i * 8 + 6], S.ra3[i * 8 + 7]);
                *(uint4*)&sA[m * LDT + kslot * 8] = pk;
            }
        }
#pragma unroll
        for (int i = 0; i < NWR; ++i) {
            int e = t + 256 * i;
            int n = e >> 3, kc = (e & 7) << 2;
            *(uint2*)&sW[n * LDT + kc] = S.rw[i];
        }
    };

    f32x4 acc[FM][FN];
#pragma unroll
    for (int i = 0; i < FM; ++i)
#pragma unroll
        for (int j = 0; j < FN; ++j) acc[i][j] = (f32x4){0.f, 0.f, 0.f, 0.f};

    auto MFMAstep = [&]() {
        bf16x8 af[FM], bfr[FN];
#pragma unroll
        for (int mi = 0; mi < FM; ++mi)
            af[mi] = *(const bf16x8*)&sA[(wm * TM + mi * 16 + lo) * LDT + kg * 8];
#pragma unroll
        for (int ni = 0; ni < FN; ++ni)
            bfr[ni] = *(const bf16x8*)&sW[(wn * TN + ni * 16 + lo) * LDT + kg * 8];
#pragma unroll
        for (int mi = 0; mi < FM; ++mi)
#pragma unroll
            for (int ni = 0; ni < FN; ++ni)
                acc[mi][ni] = __builtin_amdgcn_mfma_f32_16x16x32_bf16(af[mi], bfr[ni], acc[mi][ni], 0, 0, 0);
    };

    LOAD(0, s0); LOAD(32, s1);
    for (int k0 = 0; k0 < K; k0 += 64) {
        STORE(s0);
        __syncthreads();
        if (k0 + 64 < K) LOAD(k0 + 64, s0);
        MFMAstep();
        __syncthreads();
        STORE(s1);
        __syncthreads();
        if (k0 + 96 < K) LOAD(k0 + 96, s1);
        MFMAstep();
        __syncthreads();
    }

    if constexpr (CL == 2) {
#pragma unroll
        for (int mi = 0; mi < FM; ++mi) {
            const int gmb = m0 + wm * TM + mi * 16 + kg * 4;
            const int b = gmb >> 12, p = gmb & 4095;
            const int h = p >> 6, w = p & 63;
#pragma unroll
            for (int ni = 0; ni < FN; ++ni) {
                const int gn = n0 + wn * TN + ni * 16 + lo;
                const int nh = gn >> 5, dd = gn & 31;
                const float bs = biasp[gn];
                uint2 pk;
                pk.x = pk2(acc[mi][ni][0] + bs, acc[mi][ni][1] + bs);
                pk.y = pk2(acc[mi][ni][2] + bs, acc[mi][ni][3] + bs);
                *(uint2*)((ushort*)C0v + ((size_t)(b * 8 + nh)) * 131072 + h * 2048 + dd * 64 + w) = pk;
            }
        }
    } else {
#pragma unroll
        for (int mi = 0; mi < FM; ++mi) {
#pragma unroll
            for (int r = 0; r < 4; ++r) {
                const int gm = m0 + wm * TM + mi * 16 + kg * 4 + r;
#pragma unroll
                for (int ni = 0; ni < FN; ++ni) {
                    const int gn = n0 + wn * TN + ni * 16 + lo;
                    float v = acc[mi][ni][r] + biasp[gn];
                    if constexpr (RELU) v = fmaxf(v, 0.f);
                    if constexpr (CL == 1) {
                        if (gn < 256) v *= qscale;
                        int head = (gn & 255) >> 5, d = gn & 31;
                        ushort* dst = (gn < 256) ? (ushort*)C0v
                                     : (gn < 512 ? (ushort*)C1_ : (ushort*)C2_);
                        int b = gm / Lh, l = gm - b * Lh;
                        dst[(((size_t)b * H_ + head) * Lh + l) * HD_ + d] = f2b(v);
                    } else {
                        ushort* C0 = (ushort*)C0v;
                        C0[(size_t)gm * N + gn] = f2b(v);
                    }
                }
            }
        }
    }
}

// ---------------- Merged CA map projections: z = {qrow, qcol, krow, kcol}; bf16 W ----------------
__global__ __launch_bounds__(256) void mgemm_maps(
    const float* __restrict__ A0, const float* __restrict__ A1,
    const float* __restrict__ A2x, const float* __restrict__ A3,
    const float* __restrict__ P0, const float* __restrict__ P1,
    const float* __restrict__ P2, const float* __restrict__ P3,
    const ushort* __restrict__ W0, const ushort* __restrict__ W1,
    const ushort* __restrict__ W2, const ushort* __restrict__ W3,
    const float* __restrict__ B0, const float* __restrict__ B1,
    const float* __restrict__ B2, const float* __restrict__ B3,
    ushort* __restrict__ C0, ushort* __restrict__ C1,
    ushort* __restrict__ C2, ushort* __restrict__ C3)
{
    constexpr int LDT = 40;
    __shared__ ushort sA[64 * LDT];
    __shared__ ushort sW[32 * LDT];
    const int z = blockIdx.z;
    const int M = (z < 2) ? 4800 : 1024;
    const int m0 = blockIdx.x * 64;
    if (m0 >= M) return;
    const int Lh = (z < 2) ? 300 : 64;
    const float qs = (z < 2) ? SCALE_ : 1.f;
    const float* Ap = (z == 0) ? A0 : (z == 1) ? A1 : (z == 2) ? A2x : A3;
    const float* Pp = (z == 0) ? P0 : (z == 1) ? P1 : (z == 2) ? P2 : P3;
    const ushort* Wp = (z == 0) ? W0 : (z == 1) ? W1 : (z == 2) ? W2 : W3;
    const float* Bp = (z == 0) ? B0 : (z == 1) ? B1 : (z == 2) ? B2 : B3;
    ushort* Cp = (z == 0) ? C0 : (z == 1) ? C1 : (z == 2) ? C2 : C3;
    const int t = threadIdx.x, lane = t & 63, wv = t >> 6;
    const int lo = lane & 15, kg = lane >> 4;
    const int wm = wv >> 1, wn = wv & 1;
    const int n0 = blockIdx.y * 32;

    float4 ra0[2], ra1[2];
    uint2 rw0, rw1;
    auto LOAD = [&](int k0, float4 (&ra)[2], uint2& rw) {
#pragma unroll
        for (int i = 0; i < 2; ++i) {
            int e = t + 256 * i;
            int m = e >> 3, kc = (e & 7) << 2;
            float4 va = *(const float4*)(Ap + (size_t)(m0 + m) * 256 + k0 + kc);
            float4 v2 = *(const float4*)(Pp + (size_t)(m0 + m) * 256 + k0 + kc);
            va.x += v2.x; va.y += v2.y; va.z += v2.z; va.w += v2.w;
            ra[i] = va;
        }
        int n = t >> 3, kc = (t & 7) << 2;
        rw = *(const uint2*)(Wp + (size_t)(n0 + n) * 256 + k0 + kc);
    };
    auto STORE = [&](float4 (&ra)[2], uint2& rw) {
#pragma unroll
        for (int i = 0; i < 2; ++i) {
            int e = t + 256 * i;
            int m = e >> 3, kc = (e & 7) << 2;
            uint2 pk; pk.x = pk2(ra[i].x, ra[i].y); pk.y = pk2(ra[i].z, ra[i].w);
            *(uint2*)&sA[m * LDT + kc] = pk;
        }
        int n = t >> 3, kc = (t & 7) << 2;
        *(uint2*)&sW[n * LDT + kc] = rw;
    };

    f32x4 acc[2];
    acc[0] = (f32x4){0.f, 0.f, 0.f, 0.f};
    acc[1] = (f32x4){0.f, 0.f, 0.f, 0.f};
    auto MFMAstep = [&]() {
        bf16x8 bfr = *(const bf16x8*)&sW[(wn * 16 + lo) * LDT + kg * 8];
#pragma unroll
        for (int mi = 0; mi < 2; ++mi) {
            bf16x8 af = *(const bf16x8*)&sA[(wm * 32 + mi * 16 + lo) * LDT + kg * 8];
            acc[mi] = __builtin_amdgcn_mfma_f32_16x16x32_bf16(af, bfr, acc[mi], 0, 0, 0);
        }
    };

    LOAD(0, ra0, rw0); LOAD(32, ra1, rw1);
    for (int k0 = 0; k0 < 256; k0 += 64) {
        STORE(ra0, rw0);
        __syncthreads();
        if (k0 + 64 < 256) LOAD(k0 + 64, ra0, rw0);
        MFMAstep();
        __syncthreads();
        STORE(ra1, rw1);
        __syncthreads();
        if (k0 + 96 < 256) LOAD(k0 + 96, ra1, rw1);
        MFMAstep();
        __syncthreads();
    }

#pragma unroll
    for (int mi = 0; mi < 2; ++mi) {
#pragma unroll
        for (int r = 0; r < 4; ++r) {
            const int gm = m0 + wm * 32 + mi * 16 + kg * 4 + r;
            const int gn = n0 + wn * 16 + lo;
            float v = (acc[mi][r] + Bp[gn]) * qs;
            int head = gn >> 5, d = gn & 31;
            int b = gm / Lh, l = gm - b * Lh;
            Cp[(((size_t)b * H_ + head) * Lh + l) * HD_ + d] = f2b(v);
        }
    }
}

// ---------------- GEMM + residual + LayerNorm fused (BM=16, BN=256=N, bf16 A+W) ----------------
template<int KK>
__global__ __launch_bounds__(256) void mgemm_ln(
    const ushort* __restrict__ A, const ushort* __restrict__ W,
    const float* __restrict__ bias, const float* __restrict__ res,
    const float* __restrict__ gw, const float* __restrict__ gb, float* __restrict__ O)
{
    constexpr int LDT = 40;
    __shared__ ushort sA[16 * LDT];
    __shared__ ushort sW[256 * LDT];
    __shared__ float red[4][16][2];
    const int t = threadIdx.x, lane = t & 63, wv = t >> 6;
    const int lo = lane & 15, kg = lane >> 4;
    const int m0 = blockIdx.x * 16;
    const bool aact = (t < 128);

    uint2 a0, a1;
    uint2 w0[8], w1[8];
    auto LOADA = [&](int k0, uint2& aa) {
        if (aact) aa = *(const uint2*)(A + (size_t)(m0 + (t >> 3)) * KK + k0 + ((t & 7) << 2));
    };
    auto LOADW = [&](int k0, uint2 (&ww)[8]) {
#pragma unroll
        for (int i = 0; i < 8; ++i) {
            int e = t + 256 * i;
            int n = e >> 3, kc = (e & 7) << 2;
            ww[i] = *(const uint2*)(W + (size_t)n * KK + k0 + kc);
        }
    };
    auto STOREA = [&](uint2& aa) {
        if (aact) *(uint2*)&sA[(t >> 3) * LDT + ((t & 7) << 2)] = aa;
    };
    auto STOREW = [&](uint2 (&ww)[8]) {
#pragma unroll
        for (int i = 0; i < 8; ++i) {
            int e = t + 256 * i;
            int n = e >> 3, kc = (e & 7) << 2;
            *(uint2*)&sW[n * LDT + kc] = ww[i];
        }
    };

    f32x4 acc[4];
#pragma unroll
    for (int i = 0; i < 4; ++i) acc[i] = (f32x4){0.f, 0.f, 0.f, 0.f};

    auto MFMAstep = [&]() {
        bf16x8 af = *(const bf16x8*)&sA[lo * LDT + kg * 8];
#pragma unroll
        for (int ni = 0; ni < 4; ++ni) {
            bf16x8 bfr = *(const bf16x8*)&sW[(wv * 64 + ni * 16 + lo) * LDT + kg * 8];
            acc[ni] = __builtin_amdgcn_mfma_f32_16x16x32_bf16(af, bfr, acc[ni], 0, 0, 0);
        }
    };

    LOADA(0, a0); LOADW(0, w0);
    LOADA(32, a1); LOADW(32, w1);
    for (int k0 = 0; k0 < KK; k0 += 64) {
        STOREA(a0); STOREW(w0);
        __syncthreads();
        if (k0 + 64 < KK) { LOADA(k0 + 64, a0); LOADW(k0 + 64, w0); }
        MFMAstep();
        __syncthreads();
        STOREA(a1); STOREW(w1);
        __syncthreads();
        if (k0 + 96 < KK) { LOADA(k0 + 96, a1); LOADW(k0 + 96, w1); }
        MFMAstep();
        __syncthreads();
    }

    const int gmb = m0 + kg * 4;
    float vvv[4][4];
    float ps[4] = {0.f, 0.f, 0.f, 0.f}, qs[4] = {0.f, 0.f, 0.f, 0.f};
#pragma unroll
    for (int ni = 0; ni < 4; ++ni) {
        const int gn = wv * 64 + ni * 16 + lo;
        const float bs = bias[gn];
#pragma unroll
        for (int r = 0; r < 4; ++r) {
            float x = acc[ni][r] + bs + res[(size_t)(gmb + r) * 256 + gn];
            vvv[ni][r] = x;
            ps[r] += x;
            qs[r] += x * x;
        }
    }
#pragma unroll
    for (int off = 1; off < 16; off <<= 1) {
#pragma unroll
        for (int r = 0; r < 4; ++r) {
            ps[r] += __shfl_xor(ps[r], off);
            qs[r] += __shfl_xor(qs[r], off);
        }
    }
    if (lo == 0) {
#pragma unroll
        for (int r = 0; r < 4; ++r) {
            red[wv][kg * 4 + r][0] = ps[r];
            red[wv][kg * 4 + r][1] = qs[r];
        }
    }
    __syncthreads();
    float mean[4], rs[4];
#pragma unroll
    for (int r = 0; r < 4; ++r) {
        const int row = kg * 4 + r;
        float s = red[0][row][0] + red[1][row][0] + red[2][row][0] + red[3][row][0];
        float q = red[0][row][1] + red[1][row][1] + red[2][row][1] + red[3][row][1];
        mean[r] = s * (1.f / 256.f);
        float var = q * (1.f / 256.f) - mean[r] * mean[r];
        rs[r] = rsqrtf(var + EPS_);
    }
#pragma unroll
    for (int ni = 0; ni < 4; ++ni) {
        const int gn = wv * 64 + ni * 16 + lo;
        const float g = gw[gn], b2 = gb[gn];
#pragma unroll
        for (int r = 0; r < 4; ++r)
            O[(size_t)(gmb + r) * 256 + gn] = (vvv[ni][r] - mean[r]) * rs[r] * g + b2;
    }
}

// ---------------- Fused SA attention; LDS-aliased; XCD-grouped ----------------
__global__ __launch_bounds__(256) void sa_fused(const ushort* __restrict__ q,
    const ushort* __restrict__ k, const ushort* __restrict__ v, ushort* __restrict__ ctx)
{
    __shared__ __align__(16) char sm[62976];
    ushort* Vt = (ushort*)sm;             // [d][key] 32 x 328
    ushort* Kt = (ushort*)(sm + 20992);   // [key][d] 304 x 40
    ushort* Pt = (ushort*)(sm + 20992);   // [wv][l][key] 4 x 16 x 328 (aliases Kt)
    const int t = threadIdx.x, lane = t & 63, wv = t >> 6;
    const int lo = lane & 15, kg = lane >> 4;
    const int linear = blockIdx.x + 5 * blockIdx.y;
    const int xcd = linear & 7, slot = linear >> 3;
    const int l0 = (slot % 5) * 64;
    const int bh = xcd + 8 * (slot / 5);
    const ushort* qp = q + (size_t)bh * 9600;
    const ushort* kp = k + (size_t)bh * 9600;
    const ushort* vp = v + (size_t)bh * 9600;

    for (int e = t; e < 1216; e += 256) {
        int row = e >> 2, dq = (e & 3) << 3;
        uint4 kv = (row < 300) ? *(const uint4*)(kp + row * 32 + dq)
                               : make_uint4(0, 0, 0, 0);
        *(uint4*)&Kt[row * 40 + dq] = kv;
    }
    for (int e = t; e < 1200; e += 256) {
        int row = e >> 2, dq = (e & 3) << 3;
        uint4 vv4 = *(const uint4*)(vp + row * 32 + dq);
        const ushort* sv = (const ushort*)&vv4;
#pragma unroll
        for (int j = 0; j < 8; ++j) Vt[(dq + j) * 328 + row] = sv[j];
    }
    for (int e = t; e < 32 * 28; e += 256) {
        int d = e / 28, kk = 300 + e % 28;
        Vt[d * 328 + kk] = 0;
    }
    const int ql = l0 + wv * 16 + lo;
    bf16x8 qf = {0, 0, 0, 0, 0, 0, 0, 0};
    if (ql < 300) qf = *(const bf16x8*)(qp + ql * 32 + kg * 8);
    __syncthreads();

    f32x4 s[19];
#pragma unroll
    for (int f = 0; f < 19; ++f) {
        bf16x8 af = *(const bf16x8*)&Kt[(f * 16 + lo) * 40 + kg * 8];
        f32x4 z = {0.f, 0.f, 0.f, 0.f};
        s[f] = __builtin_amdgcn_mfma_f32_16x16x32_bf16(af, qf, z, 0, 0, 0);
    }
    if (kg == 3) { s[18][0] = -3.4e38f; s[18][1] = -3.4e38f; s[18][2] = -3.4e38f; s[18][3] = -3.4e38f; }

    float mx = -3.4e38f;
#pragma unroll
    for (int f = 0; f < 19; ++f)
#pragma unroll
        for (int r = 0; r < 4; ++r) mx = fmaxf(mx, s[f][r]);
    mx = fmaxf(mx, __shfl_xor(mx, 16));
    mx = fmaxf(mx, __shfl_xor(mx, 32));
    float sum = 0.f;
#pragma unroll
    for (int f = 0; f < 19; ++f)
#pragma unroll
        for (int r = 0; r < 4; ++r) { s[f][r] = __expf(s[f][r] - mx); sum += s[f][r]; }
    sum += __shfl_xor(sum, 16);
    sum += __shfl_xor(sum, 32);
    const float inv = 1.f / sum;

    __syncthreads();   // all waves done reading Kt; Pt may overwrite

    ushort* Ptw = Pt + wv * (16 * 328);
#pragma unroll
    for (int f = 0; f < 19; ++f) {
        *(unsigned*)&Ptw[lo * 328 + f * 16 + kg * 4]     = pk2(s[f][0] * inv, s[f][1] * inv);
        *(unsigned*)&Ptw[lo * 328 + f * 16 + kg * 4 + 2] = pk2(s[f][2] * inv, s[f][3] * inv);
    }
    {
        uint2 z2 = make_uint2(0, 0);
        *(uint2*)&Ptw[(lane & 15) * 328 + 304 + ((lane >> 4) << 2)] = z2;
    }

    f32x4 o0 = {0.f, 0.f, 0.f, 0.f}, o1 = {0.f, 0.f, 0.f, 0.f};
#pragma unroll
    for (int f = 0; f < 10; ++f) {
        bf16x8 pa = *(const bf16x8*)&Ptw[lo * 328 + f * 32 + kg * 8];
        bf16x8 b0 = *(const bf16x8*)&Vt[lo * 328 + f * 32 + kg * 8];
        bf16x8 b1 = *(const bf16x8*)&Vt[(16 + lo) * 328 + f * 32 + kg * 8];
        o0 = __builtin_amdgcn_mfma_f32_16x16x32_bf16(pa, b0, o0, 0, 0, 0);
        o1 = __builtin_amdgcn_mfma_f32_16x16x32_bf16(pa, b1, o1, 0, 0, 0);
    }

    const int lb = l0 + wv * 16 + kg * 4;
    const int b = bh >> 3, h = bh & 7;
#pragma unroll
    for (int r = 0; r < 4; ++r) {
        int l = lb + r;
        if (l < 300) {
            ushort* op = ctx + ((size_t)b * 300 + l) * 256 + h * 32;
            op[lo] = f2b(o0[r]);
            op[lo + 16] = f2b(o1[r]);
        }
    }
}

// ---------------- Fused CA; LDS-aliased; XCD-grouped (depth-1 vv prefetch) ----------------
__global__ __launch_bounds__(256) void ca_fused(const ushort* __restrict__ qr,
    const ushort* __restrict__ qc, const ushort* __restrict__ kr, const ushort* __restrict__ kc,
    const ushort* __restrict__ vv, ushort* __restrict__ out)
{
    __shared__ __align__(16) char sm[45056];
    ushort* s_ar = (ushort*)sm;             // [l][w] 64 x 72 bf16
    float*  s_ac = (float*)(sm + 9216);     // [h][l] 64 x 68 f32
    ushort* Kr   = (ushort*)(sm + 26624);   // 64 x 40
    ushort* Kc   = (ushort*)(sm + 31744);   // 64 x 40
    ushort* vvT  = (ushort*)(sm + 26624);   // [buf][h'][d][w] 2 x 2 x 32 x 72

    const int t = threadIdx.x, lane = t & 63, wv = t >> 6;
    const int lo = lane & 15, kg = lane >> 4;
    const int linear = blockIdx.x + 5 * (blockIdx.y + 8 * blockIdx.z);
    const int xcd = linear & 7, slot = linear >> 3;
    const int l0 = (slot % 5) * 64;
    const int bh = xcd + 8 * (slot / 5);
    const int nh = bh & 7, b = bh >> 3;

    {
        const ushort* krp = kr + (size_t)bh * 2048;
        const ushort* kcp = kc + (size_t)bh * 2048;
        int row = t >> 2, dq = (t & 3) << 3;
        *(uint4*)&Kr[row * 40 + dq] = *(const uint4*)(krp + row * 32 + dq);
        *(uint4*)&Kc[row * 40 + dq] = *(const uint4*)(kcp + row * 32 + dq);
    }
    const int ql = l0 + wv * 16 + lo;
    bf16x8 qrf = {0,0,0,0,0,0,0,0}, qcf = {0,0,0,0,0,0,0,0};
    if (ql < 300) {
        qrf = *(const bf16x8*)(qr + (size_t)bh * 9600 + ql * 32 + kg * 8);
        qcf = *(const bf16x8*)(qc + (size_t)bh * 9600 + ql * 32 + kg * 8);
    }
    const ushort* vvp = vv + (size_t)bh * 131072;
    __syncthreads();   // Kr/Kc staged

#pragma unroll
    for (int m = 0; m < 2; ++m) {
        const ushort* Kp = m ? Kc : Kr;
        const bf16x8 qf = m ? qcf : qrf;
        f32x4 s[4];
#pragma unroll
        for (int f = 0; f < 4; ++f) {
            bf16x8 af = *(const bf16x8*)&Kp[(f * 16 + lo) * 40 + kg * 8];
            f32x4 z = {0.f, 0.f, 0.f, 0.f};
            s[f] = __builtin_amdgcn_mfma_f32_16x16x32_bf16(af, qf, z, 0, 0, 0);
        }
        float mx = -3.4e38f;
#pragma unroll
        for (int f = 0; f < 4; ++f)
#pragma unroll
            for (int r = 0; r < 4; ++r) mx = fmaxf(mx, s[f][r]);
        mx = fmaxf(mx, __shfl_xor(mx, 16));
        mx = fmaxf(mx, __shfl_xor(mx, 32));
        float sum = 0.f;
#pragma unroll
        for (int f = 0; f < 4; ++f)
#pragma unroll
            for (int r = 0; r < 4; ++r) { s[f][r] = __expf(s[f][r] - mx); sum += s[f][r]; }
        sum += __shfl_xor(sum, 16);
        sum += __shfl_xor(sum, 32);
        const float inv = 1.f / sum;
        if (m == 0) {
#pragma unroll
            for (int f = 0; f < 4; ++f) {
                *(unsigned*)&s_ar[(wv * 16 + lo) * 72 + f * 16 + kg * 4]     = pk2(s[f][0] * inv, s[f][1] * inv);
                *(unsigned*)&s_ar[(wv * 16 + lo) * 72 + f * 16 + kg * 4 + 2] = pk2(s[f][2] * inv, s[f][3] * inv);
            }
        } else {
#pragma unroll
            for (int f = 0; f < 4; ++f)
#pragma unroll
                for (int r = 0; r < 4; ++r)
                    s_ac[(f * 16 + kg * 4 + r) * 68 + wv * 16 + lo] = s[f][r] * inv;
        }
    }

    __syncthreads();   // done reading Kr/Kc; vvT may overwrite

#pragma unroll
    for (int i = 0; i < 2; ++i) {
        int c = t + 256 * i;
        int h1 = c >> 8, d = (c >> 3) & 31, w8 = (c & 7) << 3;
        uint4 v4 = *(const uint4*)(vvp + h1 * 2048 + d * 64 + w8);
        *(uint4*)&vvT[(h1 * 32 + d) * 72 + w8] = v4;
    }
    __syncthreads();

    const bf16x8 af0 = *(const bf16x8*)&s_ar[(wv * 16 + lo) * 72 + kg * 8];
    const bf16x8 af1 = *(const bf16x8*)&s_ar[(wv * 16 + lo) * 72 + 32 + kg * 8];

    f32x4 acc0 = {0.f, 0.f, 0.f, 0.f};
    f32x4 acc1 = {0.f, 0.f, 0.f, 0.f};

    for (int it = 0; it < 32; ++it) {
        const int cur = it & 1;
        uint4 pre[2];
        if (it < 31) {
            const ushort* nxt = vvp + (size_t)(2 * (it + 1)) * 2048;
#pragma unroll
            for (int i = 0; i < 2; ++i) {
                int c = t + 256 * i;
                int h1 = c >> 8, d = (c >> 3) & 31, w8 = (c & 7) << 3;
                pre[i] = *(const uint4*)(nxt + h1 * 2048 + d * 64 + w8);
            }
        }
#pragma unroll
        for (int hh = 0; hh < 2; ++hh) {
            const int h = 2 * it + hh;
            const ushort* vt = &vvT[(cur * 2 + hh) * 32 * 72];
            bf16x8 b00 = *(const bf16x8*)&vt[lo * 72 + kg * 8];
            bf16x8 b01 = *(const bf16x8*)&vt[lo * 72 + 32 + kg * 8];
            bf16x8 b10 = *(const bf16x8*)&vt[(16 + lo) * 72 + kg * 8];
            bf16x8 b11 = *(const bf16x8*)&vt[(16 + lo) * 72 + 32 + kg * 8];
            f32x4 z = {0.f, 0.f, 0.f, 0.f};
            f32x4 t0 = __builtin_amdgcn_mfma_f32_16x16x32_bf16(af0, b00, z, 0, 0, 0);
            t0 = __builtin_amdgcn_mfma_f32_16x16x32_bf16(af1, b01, t0, 0, 0, 0);
            f32x4 t1 = __builtin_amdgcn_mfma_f32_16x16x32_bf16(af0, b10, z, 0, 0, 0);
            t1 = __builtin_amdgcn_mfma_f32_16x16x32_bf16(af1, b11, t1, 0, 0, 0);
            const float* sp = &s_ac[h * 68 + wv * 16 + kg * 4];
#pragma unroll
            for (int r = 0; r < 4; ++r) {
                float sc = sp[r];
                acc0[r] += sc * t0[r];
                acc1[r] += sc * t1[r];
            }
        }
        if (it < 31) {
#pragma unroll
            for (int i = 0; i < 2; ++i) {
                int c = t + 256 * i;
                int h1 = c >> 8, d = (c >> 3) & 31, w8 = (c & 7) << 3;
                *(uint4*)&vvT[((cur ^ 1) * 2 + h1) * 32 * 72 + d * 72 + w8] = pre[i];
            }
        }
        __syncthreads();
    }

    const int lbase = l0 + wv * 16 + kg * 4;
#pragma unroll
    for (int r = 0; r < 4; ++r) {
        if (lbase + r < 300) {
            ushort* op = out + ((size_t)b * 300 + lbase + r) * 256 + nh * 32;
            op[lo] = f2b(acc0[r]);
            op[16 + lo] = f2b(acc1[r]);
        }
    }
}

// ---------------- src means ----------------
__global__ __launch_bounds__(256) void means_kernel(const float* __restrict__ srcs,
    float* __restrict__ rowm, float* __restrict__ colm)
{
    const int bc = blockIdx.x;
    const int b = bc >> 8, c = bc & 255;
    const float* sp = srcs + (size_t)bc * 4096;
    __shared__ float tile[64][65];
    for (int e = threadIdx.x; e < 4096; e += 256) tile[e >> 6][e & 63] = sp[e];
    __syncthreads();
    const int t = threadIdx.x;
    if (t < 64) {
        float s = 0.f;
        for (int y = 0; y < 64; ++y) s += tile[y][t];
        rowm[((size_t)b * 64 + t) * 256 + c] = s * (1.f / 64.f);
    } else if (t < 128) {
        int y = t - 64;
        float s = 0.f;
        for (int x = 0; x < 64; ++x) s += tile[y][x];
        colm[((size_t)b * 64 + y) * 256 + c] = s * (1.f / 64.f);
    }
}

extern "C" void kernel_launch(void* const* d_in, const int* in_sizes, int n_in,
                              void* d_out, int out_size, void* d_ws, size_t ws_size,
                              hipStream_t stream)
{
    (void)in_sizes; (void)n_in; (void)out_size; (void)ws_size;
    const float* tgt   = (const float*)d_in[0];
    const float* qpos  = (const float*)d_in[1];
    const float* qpx   = (const float*)d_in[2];
    const float* qpy   = (const float*)d_in[3];
    const float* srcs  = (const float*)d_in[4];
    const float* prow  = (const float*)d_in[6];
    const float* pcol  = (const float*)d_in[7];
    const float* sa_w  = (const float*)d_in[8];
    const float* sa_b  = (const float*)d_in[9];
    const float* sa_ow = (const float*)d_in[10];
    const float* sa_ob = (const float*)d_in[11];
    const float* ca_w  = (const float*)d_in[12];
    const float* ca_b  = (const float*)d_in[13];
    const float* ca_ow = (const float*)d_in[14];
    const float* ca_ob = (const float*)d_in[15];
    const float* n1w   = (const float*)d_in[16];
    const float* n1b   = (const float*)d_in[17];
    const float* n2w   = (const float*)d_in[18];
    const float* n2b   = (const float*)d_in[19];
    const float* l1w   = (const float*)d_in[20];
    const float* l1b   = (const float*)d_in[21];
    const float* l2w   = (const float*)d_in[22];
    const float* l2b   = (const float*)d_in[23];
    const float* nfw   = (const float*)d_in[24];
    const float* nfb   = (const float*)d_in[25];
    float* out = (float*)d_out;
    float* ws  = (float*)d_ws;

    float* tgt2  = ws + 1228800;
    float* tgt3  = ws + 2457600;
    float* rowm  = ws + 3686400;       // (B,64,E) f32
    float* colm  = ws + 3948544;
    ushort* u    = (ushort*)(ws + 4210688);
    ushort* q16    = u;                // (B,H,L,HD)
    ushort* k16    = u + 1228800;
    ushort* v16    = u + 2457600;
    ushort* ctx16  = u + 3686400;      // (B,L,E)
    ushort* qrow16 = u + 4915200;
    ushort* qcol16 = u + 6144000;
    ushort* krow16 = u + 7372800;      // (B,H,64,HD)
    ushort* kcol16 = u + 7634944;
    ushort* ffm16  = u + 7897088;      // (B,L,FF)
    ushort* vvb    = u + 12812288;     // vvT: (B*H)[h][d][w] bf16
    ushort* wbf    = u + 29589504;     // bf16 weight pool (1,179,648 elems)
    // pool offsets
    ushort* w_sa   = wbf;              // 768x256
    ushort* w_sao  = wbf + 196608;     // 256x256
    ushort* w_ca   = wbf + 262144;     // 5 x 256x256 (qpx, qpy, krow, kcol, vv)
    ushort* w_cao  = wbf + 589824;     // 256x256
    ushort* w_l1   = wbf + 655360;     // 1024x256
    ushort* w_l2   = wbf + 917504;     // 256x1024

    // ---- Weight conversion (once per launch) ----
    convert_w<<<1152,256,0,stream>>>(sa_w, sa_ow, ca_w, ca_ow, l1w, l2w, wbf);

    // ---- Self-attention ----
    mgemm<64,32,0,true,false,1,false,false><<<dim3(75,24),256,0,stream>>>(
        tgt, qpos, w_sa, sa_b, q16, k16, v16, 4800, 768, 256, 300, SCALE_, 512,
        nullptr, nullptr, nullptr, nullptr, nullptr);
    sa_fused<<<dim3(5,128),256,0,stream>>>(q16, k16, v16, ctx16);
    mgemm_ln<256><<<300,256,0,stream>>>(ctx16, w_sao, sa_ob, tgt, n2w, n2b, tgt2);

    // ---- Cross-attention prep ----
    means_kernel<<<4096,256,0,stream>>>(srcs, rowm, colm);
    mgemm_maps<<<dim3(75,8,4),256,0,stream>>>(
        tgt2, tgt2, rowm, colm,
        qpx, qpy, prow, pcol,
        w_ca, w_ca + 65536, w_ca + 2*65536, w_ca + 3*65536,
        ca_b, ca_b + 256, ca_b + 512, ca_b + 768,
        qrow16, qcol16, krow16, kcol16);
    mgemm<128,128,3,false,false,2,false,true><<<dim3(512,2),256,0,stream>>>(
        srcs, nullptr, w_ca + 4*65536, ca_b + 1024, vvb, nullptr, nullptr,
        65536, 256, 256, 0, 1.f, 0,
        nullptr, nullptr, nullptr, nullptr, nullptr);

    // ---- CA fused core + out proj + LN ----
    ca_fused<<<dim3(5,8,16),256,0,stream>>>(qrow16, qcol16, krow16, kcol16, vvb, ctx16);
    mgemm_ln<256><<<300,256,0,stream>>>(ctx16, w_cao, ca_ob, tgt2, n1w, n1b, tgt3);

    // ---- FFN ----
    mgemm<64,128,0,false,true,3,false,false><<<dim3(75,8),256,0,stream>>>(
        tgt3, nullptr, w_l1, l1b, ffm16, nullptr, nullptr, 4800, 1024, 256, 0, 1.f, 0,
        nullptr, nullptr, nullptr, nullptr, nullptr);
    mgemm_ln<1024><<<300,256,0,stream>>>(ffm16, w_l2, l2b, tgt3, nfw, nfb, out);
}

// Round 16
// 188.868 us; speedup vs baseline: 1.1199x; 1.0098x over previous
//
#include <hip/hip_runtime.h>

#define B_ 16
#define L_ 300
#define E_ 256
#define H_ 8
#define HD_ 32
#define FF_ 1024
#define SCALE_ 0.17677669529663687f
#define EPS_ 1e-5f

typedef __attribute__((ext_vector_type(8))) short bf16x8;
typedef __attribute__((ext_vector_type(4))) float f32x4;

__device__ __forceinline__ ushort f2b(float f) {
    unsigned u = __float_as_uint(f);
    u += 0x7fff + ((u >> 16) & 1);
    return (ushort)(u >> 16);
}
// packed f32x2 -> bf16x2 via HW cvt (RNE), 1 VALU op
__device__ __forceinline__ unsigned pk2(float a, float b) {
    unsigned r;
    asm("v_cvt_pk_bf16_f32 %0, %1, %2" : "=v"(r) : "v"(a), "v"(b));
    return r;
}

// ---------------- prep: weight f32->bf16 conversion + src means, one launch ----------------
// blocks [0,1152): convert (294912 float4); [1152,5248): means (b,c) tiles.
// Resource-compatible merge: both paths low-VGPR streaming, LDS 16.6 KB.
__global__ __launch_bounds__(256) void prep(
    const float* __restrict__ w0, const float* __restrict__ w1,
    const float* __restrict__ w2, const float* __restrict__ w3,
    const float* __restrict__ w4, const float* __restrict__ w5,
    ushort* __restrict__ dst,
    const float* __restrict__ srcs, float* __restrict__ rowm, float* __restrict__ colm)
{
    __shared__ float tile[64 * 65];
    if (blockIdx.x < 1152) {
        int i4 = blockIdx.x * 256 + threadIdx.x;
        const float* src; int base4;
        if (i4 < 49152)       { src = w0; base4 = 0; }
        else if (i4 < 65536)  { src = w1; base4 = 49152; }
        else if (i4 < 147456) { src = w2; base4 = 65536; }
        else if (i4 < 163840) { src = w3; base4 = 147456; }
        else if (i4 < 229376) { src = w4; base4 = 163840; }
        else                  { src = w5; base4 = 229376; }
        float4 v = *(const float4*)(src + (size_t)(i4 - base4) * 4);
        uint2 pk; pk.x = pk2(v.x, v.y); pk.y = pk2(v.z, v.w);
        *(uint2*)(dst + (size_t)i4 * 4) = pk;
    } else {
        const int bc = blockIdx.x - 1152;
        const int b = bc >> 8, c = bc & 255;
        const float* sp = srcs + (size_t)bc * 4096;
        for (int e = threadIdx.x; e < 4096; e += 256) tile[(e >> 6) * 65 + (e & 63)] = sp[e];
        __syncthreads();
        const int t = threadIdx.x;
        if (t < 64) {
            float s = 0.f;
            for (int y = 0; y < 64; ++y) s += tile[y * 65 + t];
            rowm[((size_t)b * 64 + t) * 256 + c] = s * (1.f / 64.f);
        } else if (t < 128) {
            int y = t - 64;
            float s = 0.f;
            for (int x = 0; x < 64; ++x) s += tile[y * 65 + x];
            colm[((size_t)b * 64 + y) * 256 + c] = s * (1.f / 64.f);
        }
    }
}

// ---------------- Pipelined bf16 MFMA GEMM, depth-2 register prefetch; bf16 W ----------------
// AMODE: 0 = f32 A (+ADD2 if n0<a2lim); 2 = bf16 A row-major; 3 = srcs layout (BM=128).
// CL: 1 = bf16 BHLD 3-way dest (qscale on gn<256); 2 = bf16 vvT [b*8+nh][h][d][w];
//     3 = bf16 row-major.
template<int BM, int BN, int AMODE, bool ADD2, bool RELU, int CL, bool DUAL, bool SWZ>
__global__ __launch_bounds__(256) void mgemm(
    const void* __restrict__ A_, const float* __restrict__ A2_,
    const ushort* __restrict__ W_, const float* __restrict__ bias_,
    void* __restrict__ C0_, void* __restrict__ C1_,
    void* __restrict__ C2_, int M, int N, int K, int Lh, float qscale, int a2lim,
    const void* __restrict__ Ab_, const float* __restrict__ A2b_,
    const ushort* __restrict__ Wb_, const float* __restrict__ biasb_, void* __restrict__ C0b_)
{
    constexpr int TM = BM / 2, TN = BN / 2;
    constexpr int FM = TM / 16, FN = TN / 16;
    constexpr int LDT = 40;
    constexpr int NAR = (AMODE == 2) ? (BM / 64) : (BM / 32);
    constexpr int NWR = BN / 32;
    __shared__ ushort sA[BM * LDT];
    __shared__ ushort sW[BN * LDT];
    const int t = threadIdx.x;
    const int lane = t & 63, wv = t >> 6;
    const int lo = lane & 15, kg = lane >> 4;
    const int wm = wv >> 1, wn = wv & 1;
    int bx = blockIdx.x, by = blockIdx.y;
    if constexpr (SWZ) {
        int linear = blockIdx.x + gridDim.x * blockIdx.y;
        int xcd = linear & 7, s = linear >> 3;
        by = s & 1; bx = (s >> 1) * 8 + xcd;
    }
    const int m0 = bx * BM, n0 = by * BN;

    const void* Ap = A_; const float* A2p = A2_; const ushort* Wp = W_;
    const float* biasp = bias_; void* C0v = C0_;
    if constexpr (DUAL) {
        if (blockIdx.z) { Ap = Ab_; A2p = A2b_; Wp = Wb_; biasp = biasb_; C0v = C0b_; }
    }

    struct RS {
        float4 ra[(AMODE == 0) ? NAR : 1];
        uint4  ra16[(AMODE == 2) ? NAR : 1];
        float  ra3[(AMODE == 3) ? 16 : 1];
        uint2  rw[NWR];
    };
    RS s0, s1;

    auto LOAD = [&](int k0, RS& S) {
        if constexpr (AMODE == 0) {
            const float* A = (const float*)Ap;
#pragma unroll
            for (int i = 0; i < NAR; ++i) {
                int e = t + 256 * i;
                int m = e >> 3, kc = (e & 7) << 2;
                float4 va = *(const float4*)(A + (size_t)(m0 + m) * K + k0 + kc);
                if constexpr (ADD2) {
                    if (n0 < a2lim) {
                        float4 v2 = *(const float4*)(A2p + (size_t)(m0 + m) * K + k0 + kc);
                        va.x += v2.x; va.y += v2.y; va.z += v2.z; va.w += v2.w;
                    }
                }
                S.ra[i] = va;
            }
        } else if constexpr (AMODE == 2) {
            const ushort* A = (const ushort*)Ap;
#pragma unroll
            for (int i = 0; i < NAR; ++i) {
                int e = t + 256 * i;
                int m = e >> 2, c = (e & 3) << 3;
                S.ra16[i] = *(const uint4*)(A + (size_t)(m0 + m) * K + k0 + c);
            }
        } else {
            const float* A = (const float*)Ap;
            const int bb = m0 >> 12, p0 = m0 & 4095;
#pragma unroll
            for (int i = 0; i < 2; ++i) {
                int e = t + 256 * i;
                int m = e & 127, kslot = e >> 7;
                const float* base = A + ((size_t)(bb * 256 + k0 + kslot * 8)) * 4096 + p0 + m;
#pragma unroll
                for (int j = 0; j < 8; ++j) S.ra3[i * 8 + j] = base[(size_t)j * 4096];
            }
        }
#pragma unroll
        for (int i = 0; i < NWR; ++i) {
            int e = t + 256 * i;
            int n = e >> 3, kc = (e & 7) << 2;
            S.rw[i] = *(const uint2*)(Wp + (size_t)(n0 + n) * K + k0 + kc);
        }
    };
    auto STORE = [&](RS& S) {
        if constexpr (AMODE == 0) {
#pragma unroll
            for (int i = 0; i < NAR; ++i) {
                int e = t + 256 * i;
                int m = e >> 3, kc = (e & 7) << 2;
                uint2 pk; pk.x = pk2(S.ra[i].x, S.ra[i].y); pk.y = pk2(S.ra[i].z, S.ra[i].w);
                *(uint2*)&sA[m * LDT + kc] = pk;
            }
        } else if constexpr (AMODE == 2) {
#pragma unroll
            for (int i = 0; i < NAR; ++i) {
                int e = t + 256 * i;
                int m = e >> 2, c = (e & 3) << 3;
                *(uint4*)&sA[m * LDT + c] = S.ra16[i];
            }
        } else {
#pragma unroll
            for (int i = 0; i < 2; ++i) {
                int e = t + 256 * i;
                int m = e & 127, kslot = e >> 7;
                uint4 pk;
                pk.x = pk2(S.ra3[i * 8 + 0], S.ra3[i * 8 + 1]);
                pk.y = pk2(S.ra3[i * 8 + 2], S.ra3[i * 8 + 3]);
                pk.z = pk2(S.ra3[i * 8 + 4], S.ra3[i * 8 + 5]);
                pk.w = pk2(S.ra3[i * 8 + 6], S.ra3[i * 8 + 7]);
                *(uint4*)&sA[m * LDT + kslot * 8] = pk;
            }
        }
#pragma unroll
        for (int i = 0; i < NWR; ++i) {
            int e = t + 256 * i;
            int n = e >> 3, kc = (e & 7) << 2;
            *(uint2*)&sW[n * LDT + kc] = S.rw[i];
        }
    };

    f32x4 acc[FM][FN];
#pragma unroll
    for (int i = 0; i < FM; ++i)
#pragma unroll
        for (int j = 0; j < FN; ++j) acc[i][j] = (f32x4){0.f, 0.f, 0.f, 0.f};

    auto MFMAstep = [&]() {
        bf16x8 af[FM], bfr[FN];
#pragma unroll
        for (int mi = 0; mi < FM; ++mi)
            af[mi] = *(const bf16x8*)&sA[(wm * TM + mi * 16 + lo) * LDT + kg * 8];
#pragma unroll
        for (int ni = 0; ni < FN; ++ni)
            bfr[ni] = *(const bf16x8*)&sW[(wn * TN + ni * 16 + lo) * LDT + kg * 8];
#pragma unroll
        for (int mi = 0; mi < FM; ++mi)
#pragma unroll
            for (int ni = 0; ni < FN; ++ni)
                acc[mi][ni] = __builtin_amdgcn_mfma_f32_16x16x32_bf16(af[mi], bfr[ni], acc[mi][ni], 0, 0, 0);
    };

    LOAD(0, s0); LOAD(32, s1);
    for (int k0 = 0; k0 < K; k0 += 64) {
        STORE(s0);
        __syncthreads();
        if (k0 + 64 < K) LOAD(k0 + 64, s0);
        MFMAstep();
        __syncthreads();
        STORE(s1);
        __syncthreads();
        if (k0 + 96 < K) LOAD(k0 + 96, s1);
        MFMAstep();
        __syncthreads();
    }

    if constexpr (CL == 2) {
#pragma unroll
        for (int mi = 0; mi < FM; ++mi) {
            const int gmb = m0 + wm * TM + mi * 16 + kg * 4;
            const int b = gmb >> 12, p = gmb & 4095;
            const int h = p >> 6, w = p & 63;
#pragma unroll
            for (int ni = 0; ni < FN; ++ni) {
                const int gn = n0 + wn * TN + ni * 16 + lo;
                const int nh = gn >> 5, dd = gn & 31;
                const float bs = biasp[gn];
                uint2 pk;
                pk.x = pk2(acc[mi][ni][0] + bs, acc[mi][ni][1] + bs);
                pk.y = pk2(acc[mi][ni][2] + bs, acc[mi][ni][3] + bs);
                *(uint2*)((ushort*)C0v + ((size_t)(b * 8 + nh)) * 131072 + h * 2048 + dd * 64 + w) = pk;
            }
        }
    } else {
#pragma unroll
        for (int mi = 0; mi < FM; ++mi) {
#pragma unroll
            for (int r = 0; r < 4; ++r) {
                const int gm = m0 + wm * TM + mi * 16 + kg * 4 + r;
#pragma unroll
                for (int ni = 0; ni < FN; ++ni) {
                    const int gn = n0 + wn * TN + ni * 16 + lo;
                    float v = acc[mi][ni][r] + biasp[gn];
                    if constexpr (RELU) v = fmaxf(v, 0.f);
                    if constexpr (CL == 1) {
                        if (gn < 256) v *= qscale;
                        int head = (gn & 255) >> 5, d = gn & 31;
                        ushort* dst = (gn < 256) ? (ushort*)C0v
                                     : (gn < 512 ? (ushort*)C1_ : (ushort*)C2_);
                        int b = gm / Lh, l = gm - b * Lh;
                        dst[(((size_t)b * H_ + head) * Lh + l) * HD_ + d] = f2b(v);
                    } else {
                        ushort* C0 = (ushort*)C0v;
                        C0[(size_t)gm * N + gn] = f2b(v);
                    }
                }
            }
        }
    }
}

// ---------------- Merged CA map projections: z = {qrow, qcol, krow, kcol}; bf16 W ----------------
__global__ __launch_bounds__(256) void mgemm_maps(
    const float* __restrict__ A0, const float* __restrict__ A1,
    const float* __restrict__ A2x, const float* __restrict__ A3,
    const float* __restrict__ P0, const float* __restrict__ P1,
    const float* __restrict__ P2, const float* __restrict__ P3,
    const ushort* __restrict__ W0, const ushort* __restrict__ W1,
    const ushort* __restrict__ W2, const ushort* __restrict__ W3,
    const float* __restrict__ B0, const float* __restrict__ B1,
    const float* __restrict__ B2, const float* __restrict__ B3,
    ushort* __restrict__ C0, ushort* __restrict__ C1,
    ushort* __restrict__ C2, ushort* __restrict__ C3)
{
    constexpr int LDT = 40;
    __shared__ ushort sA[64 * LDT];
    __shared__ ushort sW[32 * LDT];
    const int z = blockIdx.z;
    const int M = (z < 2) ? 4800 : 1024;
    const int m0 = blockIdx.x * 64;
    if (m0 >= M) return;
    const int Lh = (z < 2) ? 300 : 64;
    const float qs = (z < 2) ? SCALE_ : 1.f;
    const float* Ap = (z == 0) ? A0 : (z == 1) ? A1 : (z == 2) ? A2x : A3;
    const float* Pp = (z == 0) ? P0 : (z == 1) ? P1 : (z == 2) ? P2 : P3;
    const ushort* Wp = (z == 0) ? W0 : (z == 1) ? W1 : (z == 2) ? W2 : W3;
    const float* Bp = (z == 0) ? B0 : (z == 1) ? B1 : (z == 2) ? B2 : B3;
    ushort* Cp = (z == 0) ? C0 : (z == 1) ? C1 : (z == 2) ? C2 : C3;
    const int t = threadIdx.x, lane = t & 63, wv = t >> 6;
    const int lo = lane & 15, kg = lane >> 4;
    const int wm = wv >> 1, wn = wv & 1;
    const int n0 = blockIdx.y * 32;

    float4 ra0[2], ra1[2];
    uint2 rw0, rw1;
    auto LOAD = [&](int k0, float4 (&ra)[2], uint2& rw) {
#pragma unroll
        for (int i = 0; i < 2; ++i) {
            int e = t + 256 * i;
            int m = e >> 3, kc = (e & 7) << 2;
            float4 va = *(const float4*)(Ap + (size_t)(m0 + m) * 256 + k0 + kc);
            float4 v2 = *(const float4*)(Pp + (size_t)(m0 + m) * 256 + k0 + kc);
            va.x += v2.x; va.y += v2.y; va.z += v2.z; va.w += v2.w;
            ra[i] = va;
        }
        int n = t >> 3, kc = (t & 7) << 2;
        rw = *(const uint2*)(Wp + (size_t)(n0 + n) * 256 + k0 + kc);
    };
    auto STORE = [&](float4 (&ra)[2], uint2& rw) {
#pragma unroll
        for (int i = 0; i < 2; ++i) {
            int e = t + 256 * i;
            int m = e >> 3, kc = (e & 7) << 2;
            uint2 pk; pk.x = pk2(ra[i].x, ra[i].y); pk.y = pk2(ra[i].z, ra[i].w);
            *(uint2*)&sA[m * LDT + kc] = pk;
        }
        int n = t >> 3, kc = (t & 7) << 2;
        *(uint2*)&sW[n * LDT + kc] = rw;
    };

    f32x4 acc[2];
    acc[0] = (f32x4){0.f, 0.f, 0.f, 0.f};
    acc[1] = (f32x4){0.f, 0.f, 0.f, 0.f};
    auto MFMAstep = [&]() {
        bf16x8 bfr = *(const bf16x8*)&sW[(wn * 16 + lo) * LDT + kg * 8];
#pragma unroll
        for (int mi = 0; mi < 2; ++mi) {
            bf16x8 af = *(const bf16x8*)&sA[(wm * 32 + mi * 16 + lo) * LDT + kg * 8];
            acc[mi] = __builtin_amdgcn_mfma_f32_16x16x32_bf16(af, bfr, acc[mi], 0, 0, 0);
        }
    };

    LOAD(0, ra0, rw0); LOAD(32, ra1, rw1);
    for (int k0 = 0; k0 < 256; k0 += 64) {
        STORE(ra0, rw0);
        __syncthreads();
        if (k0 + 64 < 256) LOAD(k0 + 64, ra0, rw0);
        MFMAstep();
        __syncthreads();
        STORE(ra1, rw1);
        __syncthreads();
        if (k0 + 96 < 256) LOAD(k0 + 96, ra1, rw1);
        MFMAstep();
        __syncthreads();
    }

#pragma unroll
    for (int mi = 0; mi < 2; ++mi) {
#pragma unroll
        for (int r = 0; r < 4; ++r) {
            const int gm = m0 + wm * 32 + mi * 16 + kg * 4 + r;
            const int gn = n0 + wn * 16 + lo;
            float v = (acc[mi][r] + Bp[gn]) * qs;
            int head = gn >> 5, d = gn & 31;
            int b = gm / Lh, l = gm - b * Lh;
            Cp[(((size_t)b * H_ + head) * Lh + l) * HD_ + d] = f2b(v);
        }
    }
}

// ---------------- GEMM + residual + LayerNorm fused (BM=16, BN=256=N, bf16 A+W) ----------------
template<int KK>
__global__ __launch_bounds__(256) void mgemm_ln(
    const ushort* __restrict__ A, const ushort* __restrict__ W,
    const float* __restrict__ bias, const float* __restrict__ res,
    const float* __restrict__ gw, const float* __restrict__ gb, float* __restrict__ O)
{
    constexpr int LDT = 40;
    __shared__ ushort sA[16 * LDT];
    __shared__ ushort sW[256 * LDT];
    __shared__ float red[4][16][2];
    const int t = threadIdx.x, lane = t & 63, wv = t >> 6;
    const int lo = lane & 15, kg = lane >> 4;
    const int m0 = blockIdx.x * 16;
    const bool aact = (t < 128);

    uint2 a0, a1;
    uint2 w0[8], w1[8];
    auto LOADA = [&](int k0, uint2& aa) {
        if (aact) aa = *(const uint2*)(A + (size_t)(m0 + (t >> 3)) * KK + k0 + ((t & 7) << 2));
    };
    auto LOADW = [&](int k0, uint2 (&ww)[8]) {
#pragma unroll
        for (int i = 0; i < 8; ++i) {
            int e = t + 256 * i;
            int n = e >> 3, kc = (e & 7) << 2;
            ww[i] = *(const uint2*)(W + (size_t)n * KK + k0 + kc);
        }
    };
    auto STOREA = [&](uint2& aa) {
        if (aact) *(uint2*)&sA[(t >> 3) * LDT + ((t & 7) << 2)] = aa;
    };
    auto STOREW = [&](uint2 (&ww)[8]) {
#pragma unroll
        for (int i = 0; i < 8; ++i) {
            int e = t + 256 * i;
            int n = e >> 3, kc = (e & 7) << 2;
            *(uint2*)&sW[n * LDT + kc] = ww[i];
        }
    };

    f32x4 acc[4];
#pragma unroll
    for (int i = 0; i < 4; ++i) acc[i] = (f32x4){0.f, 0.f, 0.f, 0.f};

    auto MFMAstep = [&]() {
        bf16x8 af = *(const bf16x8*)&sA[lo * LDT + kg * 8];
#pragma unroll
        for (int ni = 0; ni < 4; ++ni) {
            bf16x8 bfr = *(const bf16x8*)&sW[(wv * 64 + ni * 16 + lo) * LDT + kg * 8];
            acc[ni] = __builtin_amdgcn_mfma_f32_16x16x32_bf16(af, bfr, acc[ni], 0, 0, 0);
        }
    };

    LOADA(0, a0); LOADW(0, w0);
    LOADA(32, a1); LOADW(32, w1);
    for (int k0 = 0; k0 < KK; k0 += 64) {
        STOREA(a0); STOREW(w0);
        __syncthreads();
        if (k0 + 64 < KK) { LOADA(k0 + 64, a0); LOADW(k0 + 64, w0); }
        MFMAstep();
        __syncthreads();
        STOREA(a1); STOREW(w1);
        __syncthreads();
        if (k0 + 96 < KK) { LOADA(k0 + 96, a1); LOADW(k0 + 96, w1); }
        MFMAstep();
        __syncthreads();
    }

    const int gmb = m0 + kg * 4;
    float vvv[4][4];
    float ps[4] = {0.f, 0.f, 0.f, 0.f}, qs[4] = {0.f, 0.f, 0.f, 0.f};
#pragma unroll
    for (int ni = 0; ni < 4; ++ni) {
        const int gn = wv * 64 + ni * 16 + lo;
        const float bs = bias[gn];
#pragma unroll
        for (int r = 0; r < 4; ++r) {
            float x = acc[ni][r] + bs + res[(size_t)(gmb + r) * 256 + gn];
            vvv[ni][r] = x;
            ps[r] += x;
            qs[r] += x * x;
        }
    }
#pragma unroll
    for (int off = 1; off < 16; off <<= 1) {
#pragma unroll
        for (int r = 0; r < 4; ++r) {
            ps[r] += __shfl_xor(ps[r], off);
            qs[r] += __shfl_xor(qs[r], off);
        }
    }
    if (lo == 0) {
#pragma unroll
        for (int r = 0; r < 4; ++r) {
            red[wv][kg * 4 + r][0] = ps[r];
            red[wv][kg * 4 + r][1] = qs[r];
        }
    }
    __syncthreads();
    float mean[4], rs[4];
#pragma unroll
    for (int r = 0; r < 4; ++r) {
        const int row = kg * 4 + r;
        float s = red[0][row][0] + red[1][row][0] + red[2][row][0] + red[3][row][0];
        float q = red[0][row][1] + red[1][row][1] + red[2][row][1] + red[3][row][1];
        mean[r] = s * (1.f / 256.f);
        float var = q * (1.f / 256.f) - mean[r] * mean[r];
        rs[r] = rsqrtf(var + EPS_);
    }
#pragma unroll
    for (int ni = 0; ni < 4; ++ni) {
        const int gn = wv * 64 + ni * 16 + lo;
        const float g = gw[gn], b2 = gb[gn];
#pragma unroll
        for (int r = 0; r < 4; ++r)
            O[(size_t)(gmb + r) * 256 + gn] = (vvv[ni][r] - mean[r]) * rs[r] * g + b2;
    }
}

// ---------------- Fused SA attention; LDS-aliased; XCD-grouped; setprio on MFMA ----------------
__global__ __launch_bounds__(256) void sa_fused(const ushort* __restrict__ q,
    const ushort* __restrict__ k, const ushort* __restrict__ v, ushort* __restrict__ ctx)
{
    __shared__ __align__(16) char sm[62976];
    ushort* Vt = (ushort*)sm;             // [d][key] 32 x 328
    ushort* Kt = (ushort*)(sm + 20992);   // [key][d] 304 x 40
    ushort* Pt = (ushort*)(sm + 20992);   // [wv][l][key] 4 x 16 x 328 (aliases Kt)
    const int t = threadIdx.x, lane = t & 63, wv = t >> 6;
    const int lo = lane & 15, kg = lane >> 4;
    const int linear = blockIdx.x + 5 * blockIdx.y;
    const int xcd = linear & 7, slot = linear >> 3;
    const int l0 = (slot % 5) * 64;
    const int bh = xcd + 8 * (slot / 5);
    const ushort* qp = q + (size_t)bh * 9600;
    const ushort* kp = k + (size_t)bh * 9600;
    const ushort* vp = v + (size_t)bh * 9600;

    for (int e = t; e < 1216; e += 256) {
        int row = e >> 2, dq = (e & 3) << 3;
        uint4 kv = (row < 300) ? *(const uint4*)(kp + row * 32 + dq)
                               : make_uint4(0, 0, 0, 0);
        *(uint4*)&Kt[row * 40 + dq] = kv;
    }
    for (int e = t; e < 1200; e += 256) {
        int row = e >> 2, dq = (e & 3) << 3;
        uint4 vv4 = *(const uint4*)(vp + row * 32 + dq);
        const ushort* sv = (const ushort*)&vv4;
#pragma unroll
        for (int j = 0; j < 8; ++j) Vt[(dq + j) * 328 + row] = sv[j];
    }
    for (int e = t; e < 32 * 28; e += 256) {
        int d = e / 28, kk = 300 + e % 28;
        Vt[d * 328 + kk] = 0;
    }
    const int ql = l0 + wv * 16 + lo;
    bf16x8 qf = {0, 0, 0, 0, 0, 0, 0, 0};
    if (ql < 300) qf = *(const bf16x8*)(qp + ql * 32 + kg * 8);
    __syncthreads();

    f32x4 s[19];
    __builtin_amdgcn_s_setprio(1);
#pragma unroll
    for (int f = 0; f < 19; ++f) {
        bf16x8 af = *(const bf16x8*)&Kt[(f * 16 + lo) * 40 + kg * 8];
        f32x4 z = {0.f, 0.f, 0.f, 0.f};
        s[f] = __builtin_amdgcn_mfma_f32_16x16x32_bf16(af, qf, z, 0, 0, 0);
    }
    __builtin_amdgcn_s_setprio(0);
    if (kg == 3) { s[18][0] = -3.4e38f; s[18][1] = -3.4e38f; s[18][2] = -3.4e38f; s[18][3] = -3.4e38f; }

    float mx = -3.4e38f;
#pragma unroll
    for (int f = 0; f < 19; ++f)
#pragma unroll
        for (int r = 0; r < 4; ++r) mx = fmaxf(mx, s[f][r]);
    mx = fmaxf(mx, __shfl_xor(mx, 16));
    mx = fmaxf(mx, __shfl_xor(mx, 32));
    float sum = 0.f;
#pragma unroll
    for (int f = 0; f < 19; ++f)
#pragma unroll
        for (int r = 0; r < 4; ++r) { s[f][r] = __expf(s[f][r] - mx); sum += s[f][r]; }
    sum += __shfl_xor(sum, 16);
    sum += __shfl_xor(sum, 32);
    const float inv = 1.f / sum;

    __syncthreads();   // all waves done reading Kt; Pt may overwrite

    ushort* Ptw = Pt + wv * (16 * 328);
#pragma unroll
    for (int f = 0; f < 19; ++f) {
        *(unsigned*)&Ptw[lo * 328 + f * 16 + kg * 4]     = pk2(s[f][0] * inv, s[f][1] * inv);
        *(unsigned*)&Ptw[lo * 328 + f * 16 + kg * 4 + 2] = pk2(s[f][2] * inv, s[f][3] * inv);
    }
    {
        uint2 z2 = make_uint2(0, 0);
        *(uint2*)&Ptw[(lane & 15) * 328 + 304 + ((lane >> 4) << 2)] = z2;
    }

    f32x4 o0 = {0.f, 0.f, 0.f, 0.f}, o1 = {0.f, 0.f, 0.f, 0.f};
    __builtin_amdgcn_s_setprio(1);
#pragma unroll
    for (int f = 0; f < 10; ++f) {
        bf16x8 pa = *(const bf16x8*)&Ptw[lo * 328 + f * 32 + kg * 8];
        bf16x8 b0 = *(const bf16x8*)&Vt[lo * 328 + f * 32 + kg * 8];
        bf16x8 b1 = *(const bf16x8*)&Vt[(16 + lo) * 328 + f * 32 + kg * 8];
        o0 = __builtin_amdgcn_mfma_f32_16x16x32_bf16(pa, b0, o0, 0, 0, 0);
        o1 = __builtin_amdgcn_mfma_f32_16x16x32_bf16(pa, b1, o1, 0, 0, 0);
    }
    __builtin_amdgcn_s_setprio(0);

    const int lb = l0 + wv * 16 + kg * 4;
    const int b = bh >> 3, h = bh & 7;
#pragma unroll
    for (int r = 0; r < 4; ++r) {
        int l = lb + r;
        if (l < 300) {
            ushort* op = ctx + ((size_t)b * 300 + l) * 256 + h * 32;
            op[lo] = f2b(o0[r]);
            op[lo + 16] = f2b(o1[r]);
        }
    }
}

// ---------------- Fused CA; LDS-aliased; XCD-grouped; depth-1 vv prefetch; setprio ----------------
__global__ __launch_bounds__(256) void ca_fused(const ushort* __restrict__ qr,
    const ushort* __restrict__ qc, const ushort* __restrict__ kr, const ushort* __restrict__ kc,
    const ushort* __restrict__ vv, ushort* __restrict__ out)
{
    __shared__ __align__(16) char sm[45056];
    ushort* s_ar = (ushort*)sm;             // [l][w] 64 x 72 bf16
    float*  s_ac = (float*)(sm + 9216);     // [h][l] 64 x 68 f32
    ushort* Kr   = (ushort*)(sm + 26624);   // 64 x 40
    ushort* Kc   = (ushort*)(sm + 31744);   // 64 x 40
    ushort* vvT  = (ushort*)(sm + 26624);   // [buf][h'][d][w] 2 x 2 x 32 x 72

    const int t = threadIdx.x, lane = t & 63, wv = t >> 6;
    const int lo = lane & 15, kg = lane >> 4;
    const int linear = blockIdx.x + 5 * (blockIdx.y + 8 * blockIdx.z);
    const int xcd = linear & 7, slot = linear >> 3;
    const int l0 = (slot % 5) * 64;
    const int bh = xcd + 8 * (slot / 5);
    const int nh = bh & 7, b = bh >> 3;

    {
        const ushort* krp = kr + (size_t)bh * 2048;
        const ushort* kcp = kc + (size_t)bh * 2048;
        int row = t >> 2, dq = (t & 3) << 3;
        *(uint4*)&Kr[row * 40 + dq] = *(const uint4*)(krp + row * 32 + dq);
        *(uint4*)&Kc[row * 40 + dq] = *(const uint4*)(kcp + row * 32 + dq);
    }
    const int ql = l0 + wv * 16 + lo;
    bf16x8 qrf = {0,0,0,0,0,0,0,0}, qcf = {0,0,0,0,0,0,0,0};
    if (ql < 300) {
        qrf = *(const bf16x8*)(qr + (size_t)bh * 9600 + ql * 32 + kg * 8);
        qcf = *(const bf16x8*)(qc + (size_t)bh * 9600 + ql * 32 + kg * 8);
    }
    const ushort* vvp = vv + (size_t)bh * 131072;
    __syncthreads();   // Kr/Kc staged

#pragma unroll
    for (int m = 0; m < 2; ++m) {
        const ushort* Kp = m ? Kc : Kr;
        const bf16x8 qf = m ? qcf : qrf;
        f32x4 s[4];
#pragma unroll
        for (int f = 0; f < 4; ++f) {
            bf16x8 af = *(const bf16x8*)&Kp[(f * 16 + lo) * 40 + kg * 8];
            f32x4 z = {0.f, 0.f, 0.f, 0.f};
            s[f] = __builtin_amdgcn_mfma_f32_16x16x32_bf16(af, qf, z, 0, 0, 0);
        }
        float mx = -3.4e38f;
#pragma unroll
        for (int f = 0; f < 4; ++f)
#pragma unroll
            for (int r = 0; r < 4; ++r) mx = fmaxf(mx, s[f][r]);
        mx = fmaxf(mx, __shfl_xor(mx, 16));
        mx = fmaxf(mx, __shfl_xor(mx, 32));
        float sum = 0.f;
#pragma unroll
        for (int f = 0; f < 4; ++f)
#pragma unroll
            for (int r = 0; r < 4; ++r) { s[f][r] = __expf(s[f][r] - mx); sum += s[f][r]; }
        sum += __shfl_xor(sum, 16);
        sum += __shfl_xor(sum, 32);
        const float inv = 1.f / sum;
        if (m == 0) {
#pragma unroll
            for (int f = 0; f < 4; ++f) {
                *(unsigned*)&s_ar[(wv * 16 + lo) * 72 + f * 16 + kg * 4]     = pk2(s[f][0] * inv, s[f][1] * inv);
                *(unsigned*)&s_ar[(wv * 16 + lo) * 72 + f * 16 + kg * 4 + 2] = pk2(s[f][2] * inv, s[f][3] * inv);
            }
        } else {
#pragma unroll
            for (int f = 0; f < 4; ++f)
#pragma unroll
                for (int r = 0; r < 4; ++r)
                    s_ac[(f * 16 + kg * 4 + r) * 68 + wv * 16 + lo] = s[f][r] * inv;
        }
    }

    __syncthreads();   // done reading Kr/Kc; vvT may overwrite

#pragma unroll
    for (int i = 0; i < 2; ++i) {
        int c = t + 256 * i;
        int h1 = c >> 8, d = (c >> 3) & 31, w8 = (c & 7) << 3;
        uint4 v4 = *(const uint4*)(vvp + h1 * 2048 + d * 64 + w8);
        *(uint4*)&vvT[(h1 * 32 + d) * 72 + w8] = v4;
    }
    __syncthreads();

    const bf16x8 af0 = *(const bf16x8*)&s_ar[(wv * 16 + lo) * 72 + kg * 8];
    const bf16x8 af1 = *(const bf16x8*)&s_ar[(wv * 16 + lo) * 72 + 32 + kg * 8];

    f32x4 acc0 = {0.f, 0.f, 0.f, 0.f};
    f32x4 acc1 = {0.f, 0.f, 0.f, 0.f};

    for (int it = 0; it < 32; ++it) {
        const int cur = it & 1;
        uint4 pre[2];
        if (it < 31) {
            const ushort* nxt = vvp + (size_t)(2 * (it + 1)) * 2048;
#pragma unroll
            for (int i = 0; i < 2; ++i) {
                int c = t + 256 * i;
                int h1 = c >> 8, d = (c >> 3) & 31, w8 = (c & 7) << 3;
                pre[i] = *(const uint4*)(nxt + h1 * 2048 + d * 64 + w8);
            }
        }
        __builtin_amdgcn_s_setprio(1);
#pragma unroll
        for (int hh = 0; hh < 2; ++hh) {
            const int h = 2 * it + hh;
            const ushort* vt = &vvT[(cur * 2 + hh) * 32 * 72];
            bf16x8 b00 = *(const bf16x8*)&vt[lo * 72 + kg * 8];
            bf16x8 b01 = *(const bf16x8*)&vt[lo * 72 + 32 + kg * 8];
            bf16x8 b10 = *(const bf16x8*)&vt[(16 + lo) * 72 + kg * 8];
            bf16x8 b11 = *(const bf16x8*)&vt[(16 + lo) * 72 + 32 + kg * 8];
            f32x4 z = {0.f, 0.f, 0.f, 0.f};
            f32x4 t0 = __builtin_amdgcn_mfma_f32_16x16x32_bf16(af0, b00, z, 0, 0, 0);
            t0 = __builtin_amdgcn_mfma_f32_16x16x32_bf16(af1, b01, t0, 0, 0, 0);
            f32x4 t1 = __builtin_amdgcn_mfma_f32_16x16x32_bf16(af0, b10, z, 0, 0, 0);
            t1 = __builtin_amdgcn_mfma_f32_16x16x32_bf16(af1, b11, t1, 0, 0, 0);
            const float* sp = &s_ac[h * 68 + wv * 16 + kg * 4];
#pragma unroll
            for (int r = 0; r < 4; ++r) {
                float sc = sp[r];
                acc0[r] += sc * t0[r];
                acc1[r] += sc * t1[r];
            }
        }
        __builtin_amdgcn_s_setprio(0);
        if (it < 31) {
#pragma unroll
            for (int i = 0; i < 2; ++i) {
                int c = t + 256 * i;
                int h1 = c >> 8, d = (c >> 3) & 31, w8 = (c & 7) << 3;
                *(uint4*)&vvT[((cur ^ 1) * 2 + h1) * 32 * 72 + d * 72 + w8] = pre[i];
            }
        }
        __syncthreads();
    }

    const int lbase = l0 + wv * 16 + kg * 4;
#pragma unroll
    for (int r = 0; r < 4; ++r) {
        if (lbase + r < 300) {
            ushort* op = out + ((size_t)b * 300 + lbase + r) * 256 + nh * 32;
            op[lo] = f2b(acc0[r]);
            op[16 + lo] = f2b(acc1[r]);
        }
    }
}

extern "C" void kernel_launch(void* const* d_in, const int* in_sizes, int n_in,
                              void* d_out, int out_size, void* d_ws, size_t ws_size,
                              hipStream_t stream)
{
    (void)in_sizes; (void)n_in; (void)out_size; (void)ws_size;
    const float* tgt   = (const float*)d_in[0];
    const float* qpos  = (const float*)d_in[1];
    const float* qpx   = (const float*)d_in[2];
    const float* qpy   = (const float*)d_in[3];
    const float* srcs  = (const float*)d_in[4];
    const float* prow  = (const float*)d_in[6];
    const float* pcol  = (const float*)d_in[7];
    const float* sa_w  = (const float*)d_in[8];
    const float* sa_b  = (const float*)d_in[9];
    const float* sa_ow = (const float*)d_in[10];
    const float* sa_ob = (const float*)d_in[11];
    const float* ca_w  = (const float*)d_in[12];
    const float* ca_b  = (const float*)d_in[13];
    const float* ca_ow = (const float*)d_in[14];
    const float* ca_ob = (const float*)d_in[15];
    const float* n1w   = (const float*)d_in[16];
    const float* n1b   = (const float*)d_in[17];
    const float* n2w   = (const float*)d_in[18];
    const float* n2b   = (const float*)d_in[19];
    const float* l1w   = (const float*)d_in[20];
    const float* l1b   = (const float*)d_in[21];
    const float* l2w   = (const float*)d_in[22];
    const float* l2b   = (const float*)d_in[23];
    const float* nfw   = (const float*)d_in[24];
    const float* nfb   = (const float*)d_in[25];
    float* out = (float*)d_out;
    float* ws  = (float*)d_ws;

    float* tgt2  = ws + 1228800;
    float* tgt3  = ws + 2457600;
    float* rowm  = ws + 3686400;       // (B,64,E) f32
    float* colm  = ws + 3948544;
    ushort* u    = (ushort*)(ws + 4210688);
    ushort* q16    = u;                // (B,H,L,HD)
    ushort* k16    = u + 1228800;
    ushort* v16    = u + 2457600;
    ushort* ctx16  = u + 3686400;      // (B,L,E)
    ushort* qrow16 = u + 4915200;
    ushort* qcol16 = u + 6144000;
    ushort* krow16 = u + 7372800;      // (B,H,64,HD)
    ushort* kcol16 = u + 7634944;
    ushort* ffm16  = u + 7897088;      // (B,L,FF)
    ushort* vvb    = u + 12812288;     // vvT: (B*H)[h][d][w] bf16
    ushort* wbf    = u + 29589504;     // bf16 weight pool
    ushort* w_sa   = wbf;              // 768x256
    ushort* w_sao  = wbf + 196608;     // 256x256
    ushort* w_ca   = wbf + 262144;     // 5 x 256x256
    ushort* w_cao  = wbf + 589824;     // 256x256
    ushort* w_l1   = wbf + 655360;     // 1024x256
    ushort* w_l2   = wbf + 917504;     // 256x1024

    // ---- prep: weight conversion + src means (one launch) ----
    prep<<<5248,256,0,stream>>>(sa_w, sa_ow, ca_w, ca_ow, l1w, l2w, wbf,
                                srcs, rowm, colm);

    // ---- Self-attention ----
    mgemm<64,32,0,true,false,1,false,false><<<dim3(75,24),256,0,stream>>>(
        tgt, qpos, w_sa, sa_b, q16, k16, v16, 4800, 768, 256, 300, SCALE_, 512,
        nullptr, nullptr, nullptr, nullptr, nullptr);
    sa_fused<<<dim3(5,128),256,0,stream>>>(q16, k16, v16, ctx16);
    mgemm_ln<256><<<300,256,0,stream>>>(ctx16, w_sao, sa_ob, tgt, n2w, n2b, tgt2);

    // ---- Cross-attention prep ----
    mgemm_maps<<<dim3(75,8,4),256,0,stream>>>(
        tgt2, tgt2, rowm, colm,
        qpx, qpy, prow, pcol,
        w_ca, w_ca + 65536, w_ca + 2*65536, w_ca + 3*65536,
        ca_b, ca_b + 256, ca_b + 512, ca_b + 768,
        qrow16, qcol16, krow16, kcol16);
    mgemm<128,128,3,false,false,2,false,true><<<dim3(512,2),256,0,stream>>>(
        srcs, nullptr, w_ca + 4*65536, ca_b + 1024, vvb, nullptr, nullptr,
        65536, 256, 256, 0, 1.f, 0,
        nullptr, nullptr, nullptr, nullptr, nullptr);

    // ---- CA fused core + out proj + LN ----
    ca_fused<<<dim3(5,8,16),256,0,stream>>>(qrow16, qcol16, krow16, kcol16, vvb, ctx16);
    mgemm_ln<256><<<300,256,0,stream>>>(ctx16, w_cao, ca_ob, tgt2, n1w, n1b, tgt3);

    // ---- FFN ----
    mgemm<64,128,0,false,true,3,false,false><<<dim3(75,8),256,0,stream>>>(
        tgt3, nullptr, w_l1, l1b, ffm16, nullptr, nullptr, 4800, 1024, 256, 0, 1.f, 0,
        nullptr, nullptr, nullptr, nullptr, nullptr);
    mgemm_ln<1024><<<300,256,0,stream>>>(ffm16, w_l2, l2b, tgt3, nfw, nfb, out);
}

// Round 17
// 177.238 us; speedup vs baseline: 1.1934x; 1.0656x over previous
//
#include <hip/hip_runtime.h>

#define B_ 16
#define L_ 300
#define E_ 256
#define H_ 8
#define HD_ 32
#define FF_ 1024
#define SCALE_ 0.17677669529663687f
#define EPS_ 1e-5f

typedef __attribute__((ext_vector_type(8))) short bf16x8;
typedef __attribute__((ext_vector_type(4))) float f32x4;

__device__ __forceinline__ ushort f2b(float f) {
    unsigned u = __float_as_uint(f);
    u += 0x7fff + ((u >> 16) & 1);
    return (ushort)(u >> 16);
}
// packed f32x2 -> bf16x2 via HW cvt (RNE), 1 VALU op
__device__ __forceinline__ unsigned pk2(float a, float b) {
    unsigned r;
    asm("v_cvt_pk_bf16_f32 %0, %1, %2" : "=v"(r) : "v"(a), "v"(b));
    return r;
}

// ---------------- prep: weight f32->bf16 conversion + src means, one launch ----------------
__global__ __launch_bounds__(256) void prep(
    const float* __restrict__ w0, const float* __restrict__ w1,
    const float* __restrict__ w2, const float* __restrict__ w3,
    const float* __restrict__ w4, const float* __restrict__ w5,
    ushort* __restrict__ dst,
    const float* __restrict__ srcs, float* __restrict__ rowm, float* __restrict__ colm)
{
    __shared__ float tile[64 * 65];
    if (blockIdx.x < 1152) {
        int i4 = blockIdx.x * 256 + threadIdx.x;
        const float* src; int base4;
        if (i4 < 49152)       { src = w0; base4 = 0; }
        else if (i4 < 65536)  { src = w1; base4 = 49152; }
        else if (i4 < 147456) { src = w2; base4 = 65536; }
        else if (i4 < 163840) { src = w3; base4 = 147456; }
        else if (i4 < 229376) { src = w4; base4 = 163840; }
        else                  { src = w5; base4 = 229376; }
        float4 v = *(const float4*)(src + (size_t)(i4 - base4) * 4);
        uint2 pk; pk.x = pk2(v.x, v.y); pk.y = pk2(v.z, v.w);
        *(uint2*)(dst + (size_t)i4 * 4) = pk;
    } else {
        const int bc = blockIdx.x - 1152;
        const int b = bc >> 8, c = bc & 255;
        const float* sp = srcs + (size_t)bc * 4096;
        for (int e = threadIdx.x; e < 4096; e += 256) tile[(e >> 6) * 65 + (e & 63)] = sp[e];
        __syncthreads();
        const int t = threadIdx.x;
        if (t < 64) {
            float s = 0.f;
            for (int y = 0; y < 64; ++y) s += tile[y * 65 + t];
            rowm[((size_t)b * 64 + t) * 256 + c] = s * (1.f / 64.f);
        } else if (t < 128) {
            int y = t - 64;
            float s = 0.f;
            for (int x = 0; x < 64; ++x) s += tile[y * 65 + x];
            colm[((size_t)b * 64 + y) * 256 + c] = s * (1.f / 64.f);
        }
    }
}

// ---------------- Pipelined bf16 MFMA GEMM, depth-2 register prefetch; bf16 W ----------------
// AMODE: 0 = f32 A (+ADD2 if n0<a2lim); 2 = bf16 A row-major; 3 = srcs layout (BM=128).
// CL: 1 = bf16 BHLD 3-way dest (qscale on gn<256); 2 = bf16 vvT [b*8+nh][h][d][w];
//     3 = bf16 row-major.
template<int BM, int BN, int AMODE, bool ADD2, bool RELU, int CL, bool DUAL, bool SWZ>
__global__ __launch_bounds__(256) void mgemm(
    const void* __restrict__ A_, const float* __restrict__ A2_,
    const ushort* __restrict__ W_, const float* __restrict__ bias_,
    void* __restrict__ C0_, void* __restrict__ C1_,
    void* __restrict__ C2_, int M, int N, int K, int Lh, float qscale, int a2lim,
    const void* __restrict__ Ab_, const float* __restrict__ A2b_,
    const ushort* __restrict__ Wb_, const float* __restrict__ biasb_, void* __restrict__ C0b_)
{
    constexpr int TM = BM / 2, TN = BN / 2;
    constexpr int FM = TM / 16, FN = TN / 16;
    constexpr int LDT = 40;
    constexpr int NAR = (AMODE == 2) ? (BM / 64) : (BM / 32);
    constexpr int NWR = BN / 32;
    __shared__ ushort sA[BM * LDT];
    __shared__ ushort sW[BN * LDT];
    const int t = threadIdx.x;
    const int lane = t & 63, wv = t >> 6;
    const int lo = lane & 15, kg = lane >> 4;
    const int wm = wv >> 1, wn = wv & 1;
    int bx = blockIdx.x, by = blockIdx.y;
    if constexpr (SWZ) {
        int linear = blockIdx.x + gridDim.x * blockIdx.y;
        int xcd = linear & 7, s = linear >> 3;
        by = s & 1; bx = (s >> 1) * 8 + xcd;
    }
    const int m0 = bx * BM, n0 = by * BN;

    const void* Ap = A_; const float* A2p = A2_; const ushort* Wp = W_;
    const float* biasp = bias_; void* C0v = C0_;
    if constexpr (DUAL) {
        if (blockIdx.z) { Ap = Ab_; A2p = A2b_; Wp = Wb_; biasp = biasb_; C0v = C0b_; }
    }

    struct RS {
        float4 ra[(AMODE == 0) ? NAR : 1];
        uint4  ra16[(AMODE == 2) ? NAR : 1];
        float  ra3[(AMODE == 3) ? 16 : 1];
        uint2  rw[NWR];
    };
    RS s0, s1;

    auto LOAD = [&](int k0, RS& S) {
        if constexpr (AMODE == 0) {
            const float* A = (const float*)Ap;
#pragma unroll
            for (int i = 0; i < NAR; ++i) {
                int e = t + 256 * i;
                int m = e >> 3, kc = (e & 7) << 2;
                float4 va = *(const float4*)(A + (size_t)(m0 + m) * K + k0 + kc);
                if constexpr (ADD2) {
                    if (n0 < a2lim) {
                        float4 v2 = *(const float4*)(A2p + (size_t)(m0 + m) * K + k0 + kc);
                        va.x += v2.x; va.y += v2.y; va.z += v2.z; va.w += v2.w;
                    }
                }
                S.ra[i] = va;
            }
        } else if constexpr (AMODE == 2) {
            const ushort* A = (const ushort*)Ap;
#pragma unroll
            for (int i = 0; i < NAR; ++i) {
                int e = t + 256 * i;
                int m = e >> 2, c = (e & 3) << 3;
                S.ra16[i] = *(const uint4*)(A + (size_t)(m0 + m) * K + k0 + c);
            }
        } else {
            const float* A = (const float*)Ap;
            const int bb = m0 >> 12, p0 = m0 & 4095;
#pragma unroll
            for (int i = 0; i < 2; ++i) {
                int e = t + 256 * i;
                int m = e & 127, kslot = e >> 7;
                const float* base = A + ((size_t)(bb * 256 + k0 + kslot * 8)) * 4096 + p0 + m;
#pragma unroll
                for (int j = 0; j < 8; ++j) S.ra3[i * 8 + j] = base[(size_t)j * 4096];
            }
        }
#pragma unroll
        for (int i = 0; i < NWR; ++i) {
            int e = t + 256 * i;
            int n = e >> 3, kc = (e & 7) << 2;
            S.rw[i] = *(const uint2*)(Wp + (size_t)(n0 + n) * K + k0 + kc);
        }
    };
    auto STORE = [&](RS& S) {
        if constexpr (AMODE == 0) {
#pragma unroll
            for (int i = 0; i < NAR; ++i) {
                int e = t + 256 * i;
                int m = e >> 3, kc = (e & 7) << 2;
                uint2 pk; pk.x = pk2(S.ra[i].x, S.ra[i].y); pk.y = pk2(S.ra[i].z, S.ra[i].w);
                *(uint2*)&sA[m * LDT + kc] = pk;
            }
        } else if constexpr (AMODE == 2) {
#pragma unroll
            for (int i = 0; i < NAR; ++i) {
                int e = t + 256 * i;
                int m = e >> 2, c = (e & 3) << 3;
                *(uint4*)&sA[m * LDT + c] = S.ra16[i];
            }
        } else {
#pragma unroll
            for (int i = 0; i < 2; ++i) {
                int e = t + 256 * i;
                int m = e & 127, kslot = e >> 7;
                uint4 pk;
                pk.x = pk2(S.ra3[i * 8 + 0], S.ra3[i * 8 + 1]);
                pk.y = pk2(S.ra3[i * 8 + 2], S.ra3[i * 8 + 3]);
                pk.z = pk2(S.ra3[i * 8 + 4], S.ra3[i * 8 + 5]);
                pk.w = pk2(S.ra3[i * 8 + 6], S.ra3[i * 8 + 7]);
                *(uint4*)&sA[m * LDT + kslot * 8] = pk;
            }
        }
#pragma unroll
        for (int i = 0; i < NWR; ++i) {
            int e = t + 256 * i;
            int n = e >> 3, kc = (e & 7) << 2;
            *(uint2*)&sW[n * LDT + kc] = S.rw[i];
        }
    };

    f32x4 acc[FM][FN];
#pragma unroll
    for (int i = 0; i < FM; ++i)
#pragma unroll
        for (int j = 0; j < FN; ++j) acc[i][j] = (f32x4){0.f, 0.f, 0.f, 0.f};

    auto MFMAstep = [&]() {
        bf16x8 af[FM], bfr[FN];
#pragma unroll
        for (int mi = 0; mi < FM; ++mi)
            af[mi] = *(const bf16x8*)&sA[(wm * TM + mi * 16 + lo) * LDT + kg * 8];
#pragma unroll
        for (int ni = 0; ni < FN; ++ni)
            bfr[ni] = *(const bf16x8*)&sW[(wn * TN + ni * 16 + lo) * LDT + kg * 8];
#pragma unroll
        for (int mi = 0; mi < FM; ++mi)
#pragma unroll
            for (int ni = 0; ni < FN; ++ni)
                acc[mi][ni] = __builtin_amdgcn_mfma_f32_16x16x32_bf16(af[mi], bfr[ni], acc[mi][ni], 0, 0, 0);
    };

    LOAD(0, s0); LOAD(32, s1);
    for (int k0 = 0; k0 < K; k0 += 64) {
        STORE(s0);
        __syncthreads();
        if (k0 + 64 < K) LOAD(k0 + 64, s0);
        MFMAstep();
        __syncthreads();
        STORE(s1);
        __syncthreads();
        if (k0 + 96 < K) LOAD(k0 + 96, s1);
        MFMAstep();
        __syncthreads();
    }

    if constexpr (CL == 2) {
#pragma unroll
        for (int mi = 0; mi < FM; ++mi) {
            const int gmb = m0 + wm * TM + mi * 16 + kg * 4;
            const int b = gmb >> 12, p = gmb & 4095;
            const int h = p >> 6, w = p & 63;
#pragma unroll
            for (int ni = 0; ni < FN; ++ni) {
                const int gn = n0 + wn * TN + ni * 16 + lo;
                const int nh = gn >> 5, dd = gn & 31;
                const float bs = biasp[gn];
                uint2 pk;
                pk.x = pk2(acc[mi][ni][0] + bs, acc[mi][ni][1] + bs);
                pk.y = pk2(acc[mi][ni][2] + bs, acc[mi][ni][3] + bs);
                *(uint2*)((ushort*)C0v + ((size_t)(b * 8 + nh)) * 131072 + h * 2048 + dd * 64 + w) = pk;
            }
        }
    } else {
#pragma unroll
        for (int mi = 0; mi < FM; ++mi) {
#pragma unroll
            for (int r = 0; r < 4; ++r) {
                const int gm = m0 + wm * TM + mi * 16 + kg * 4 + r;
#pragma unroll
                for (int ni = 0; ni < FN; ++ni) {
                    const int gn = n0 + wn * TN + ni * 16 + lo;
                    float v = acc[mi][ni][r] + biasp[gn];
                    if constexpr (RELU) v = fmaxf(v, 0.f);
                    if constexpr (CL == 1) {
                        if (gn < 256) v *= qscale;
                        int head = (gn & 255) >> 5, d = gn & 31;
                        ushort* dst = (gn < 256) ? (ushort*)C0v
                                     : (gn < 512 ? (ushort*)C1_ : (ushort*)C2_);
                        int b = gm / Lh, l = gm - b * Lh;
                        dst[(((size_t)b * H_ + head) * Lh + l) * HD_ + d] = f2b(v);
                    } else {
                        ushort* C0 = (ushort*)C0v;
                        C0[(size_t)gm * N + gn] = f2b(v);
                    }
                }
            }
        }
    }
}

// ---------------- Merged CA map projections (BN=64): z = {qrow, qcol, krow, kcol} ----------------
__global__ __launch_bounds__(256) void mgemm_maps(
    const float* __restrict__ A0, const float* __restrict__ A1,
    const float* __restrict__ A2x, const float* __restrict__ A3,
    const float* __restrict__ P0, const float* __restrict__ P1,
    const float* __restrict__ P2, const float* __restrict__ P3,
    const ushort* __restrict__ W0, const ushort* __restrict__ W1,
    const ushort* __restrict__ W2, const ushort* __restrict__ W3,
    const float* __restrict__ B0, const float* __restrict__ B1,
    const float* __restrict__ B2, const float* __restrict__ B3,
    ushort* __restrict__ C0, ushort* __restrict__ C1,
    ushort* __restrict__ C2, ushort* __restrict__ C3)
{
    constexpr int LDT = 40;
    __shared__ ushort sA[64 * LDT];
    __shared__ ushort sW[64 * LDT];
    const int z = blockIdx.z;
    const int M = (z < 2) ? 4800 : 1024;
    const int m0 = blockIdx.x * 64;
    if (m0 >= M) return;
    const int Lh = (z < 2) ? 300 : 64;
    const float qs = (z < 2) ? SCALE_ : 1.f;
    const float* Ap = (z == 0) ? A0 : (z == 1) ? A1 : (z == 2) ? A2x : A3;
    const float* Pp = (z == 0) ? P0 : (z == 1) ? P1 : (z == 2) ? P2 : P3;
    const ushort* Wp = (z == 0) ? W0 : (z == 1) ? W1 : (z == 2) ? W2 : W3;
    const float* Bp = (z == 0) ? B0 : (z == 1) ? B1 : (z == 2) ? B2 : B3;
    ushort* Cp = (z == 0) ? C0 : (z == 1) ? C1 : (z == 2) ? C2 : C3;
    const int t = threadIdx.x, lane = t & 63, wv = t >> 6;
    const int lo = lane & 15, kg = lane >> 4;
    const int wm = wv >> 1, wn = wv & 1;
    const int n0 = blockIdx.y * 64;

    float4 ra0[2], ra1[2];
    uint2 rw0[2], rw1[2];
    auto LOAD = [&](int k0, float4 (&ra)[2], uint2 (&rw)[2]) {
#pragma unroll
        for (int i = 0; i < 2; ++i) {
            int e = t + 256 * i;
            int m = e >> 3, kc = (e & 7) << 2;
            float4 va = *(const float4*)(Ap + (size_t)(m0 + m) * 256 + k0 + kc);
            float4 v2 = *(const float4*)(Pp + (size_t)(m0 + m) * 256 + k0 + kc);
            va.x += v2.x; va.y += v2.y; va.z += v2.z; va.w += v2.w;
            ra[i] = va;
        }
#pragma unroll
        for (int i = 0; i < 2; ++i) {
            int e = t + 256 * i;
            int n = e >> 3, kc = (e & 7) << 2;
            rw[i] = *(const uint2*)(Wp + (size_t)(n0 + n) * 256 + k0 + kc);
        }
    };
    auto STORE = [&](float4 (&ra)[2], uint2 (&rw)[2]) {
#pragma unroll
        for (int i = 0; i < 2; ++i) {
            int e = t + 256 * i;
            int m = e >> 3, kc = (e & 7) << 2;
            uint2 pk; pk.x = pk2(ra[i].x, ra[i].y); pk.y = pk2(ra[i].z, ra[i].w);
            *(uint2*)&sA[m * LDT + kc] = pk;
        }
#pragma unroll
        for (int i = 0; i < 2; ++i) {
            int e = t + 256 * i;
            int n = e >> 3, kc = (e & 7) << 2;
            *(uint2*)&sW[n * LDT + kc] = rw[i];
        }
    };

    f32x4 acc[2][2];
#pragma unroll
    for (int i = 0; i < 2; ++i)
#pragma unroll
        for (int j = 0; j < 2; ++j) acc[i][j] = (f32x4){0.f, 0.f, 0.f, 0.f};
    auto MFMAstep = [&]() {
        bf16x8 af[2], bfr[2];
#pragma unroll
        for (int mi = 0; mi < 2; ++mi)
            af[mi] = *(const bf16x8*)&sA[(wm * 32 + mi * 16 + lo) * LDT + kg * 8];
#pragma unroll
        for (int ni = 0; ni < 2; ++ni)
            bfr[ni] = *(const bf16x8*)&sW[(wn * 32 + ni * 16 + lo) * LDT + kg * 8];
#pragma unroll
        for (int mi = 0; mi < 2; ++mi)
#pragma unroll
            for (int ni = 0; ni < 2; ++ni)
                acc[mi][ni] = __builtin_amdgcn_mfma_f32_16x16x32_bf16(af[mi], bfr[ni], acc[mi][ni], 0, 0, 0);
    };

    LOAD(0, ra0, rw0); LOAD(32, ra1, rw1);
    for (int k0 = 0; k0 < 256; k0 += 64) {
        STORE(ra0, rw0);
        __syncthreads();
        if (k0 + 64 < 256) LOAD(k0 + 64, ra0, rw0);
        MFMAstep();
        __syncthreads();
        STORE(ra1, rw1);
        __syncthreads();
        if (k0 + 96 < 256) LOAD(k0 + 96, ra1, rw1);
        MFMAstep();
        __syncthreads();
    }

#pragma unroll
    for (int mi = 0; mi < 2; ++mi) {
#pragma unroll
        for (int r = 0; r < 4; ++r) {
            const int gm = m0 + wm * 32 + mi * 16 + kg * 4 + r;
            const int b = gm / Lh, l = gm - b * Lh;
#pragma unroll
            for (int ni = 0; ni < 2; ++ni) {
                const int gn = n0 + wn * 32 + ni * 16 + lo;
                float v = (acc[mi][ni][r] + Bp[gn]) * qs;
                int head = gn >> 5, d = gn & 31;
                Cp[(((size_t)b * H_ + head) * Lh + l) * HD_ + d] = f2b(v);
            }
        }
    }
}

// ---------------- GEMM + residual + LayerNorm fused (BM=16, BN=256=N, bf16 A+W) ----------------
template<int KK>
__global__ __launch_bounds__(256) void mgemm_ln(
    const ushort* __restrict__ A, const ushort* __restrict__ W,
    const float* __restrict__ bias, const float* __restrict__ res,
    const float* __restrict__ gw, const float* __restrict__ gb, float* __restrict__ O)
{
    constexpr int LDT = 40;
    __shared__ ushort sA[16 * LDT];
    __shared__ ushort sW[256 * LDT];
    __shared__ float red[4][16][2];
    const int t = threadIdx.x, lane = t & 63, wv = t >> 6;
    const int lo = lane & 15, kg = lane >> 4;
    const int m0 = blockIdx.x * 16;
    const bool aact = (t < 128);

    uint2 a0, a1;
    uint2 w0[8], w1[8];
    auto LOADA = [&](int k0, uint2& aa) {
        if (aact) aa = *(const uint2*)(A + (size_t)(m0 + (t >> 3)) * KK + k0 + ((t & 7) << 2));
    };
    auto LOADW = [&](int k0, uint2 (&ww)[8]) {
#pragma unroll
        for (int i = 0; i < 8; ++i) {
            int e = t + 256 * i;
            int n = e >> 3, kc = (e & 7) << 2;
            ww[i] = *(const uint2*)(W + (size_t)n * KK + k0 + kc);
        }
    };
    auto STOREA = [&](uint2& aa) {
        if (aact) *(uint2*)&sA[(t >> 3) * LDT + ((t & 7) << 2)] = aa;
    };
    auto STOREW = [&](uint2 (&ww)[8]) {
#pragma unroll
        for (int i = 0; i < 8; ++i) {
            int e = t + 256 * i;
            int n = e >> 3, kc = (e & 7) << 2;
            *(uint2*)&sW[n * LDT + kc] = ww[i];
        }
    };

    f32x4 acc[4];
#pragma unroll
    for (int i = 0; i < 4; ++i) acc[i] = (f32x4){0.f, 0.f, 0.f, 0.f};

    auto MFMAstep = [&]() {
        bf16x8 af = *(const bf16x8*)&sA[lo * LDT + kg * 8];
#pragma unroll
        for (int ni = 0; ni < 4; ++ni) {
            bf16x8 bfr = *(const bf16x8*)&sW[(wv * 64 + ni * 16 + lo) * LDT + kg * 8];
            acc[ni] = __builtin_amdgcn_mfma_f32_16x16x32_bf16(af, bfr, acc[ni], 0, 0, 0);
        }
    };

    LOADA(0, a0); LOADW(0, w0);
    LOADA(32, a1); LOADW(32, w1);
    for (int k0 = 0; k0 < KK; k0 += 64) {
        STOREA(a0); STOREW(w0);
        __syncthreads();
        if (k0 + 64 < KK) { LOADA(k0 + 64, a0); LOADW(k0 + 64, w0); }
        MFMAstep();
        __syncthreads();
        STOREA(a1); STOREW(w1);
        __syncthreads();
        if (k0 + 96 < KK) { LOADA(k0 + 96, a1); LOADW(k0 + 96, w1); }
        MFMAstep();
        __syncthreads();
    }

    const int gmb = m0 + kg * 4;
    float vvv[4][4];
    float ps[4] = {0.f, 0.f, 0.f, 0.f}, qs[4] = {0.f, 0.f, 0.f, 0.f};
#pragma unroll
    for (int ni = 0; ni < 4; ++ni) {
        const int gn = wv * 64 + ni * 16 + lo;
        const float bs = bias[gn];
#pragma unroll
        for (int r = 0; r < 4; ++r) {
            float x = acc[ni][r] + bs + res[(size_t)(gmb + r) * 256 + gn];
            vvv[ni][r] = x;
            ps[r] += x;
            qs[r] += x * x;
        }
    }
#pragma unroll
    for (int off = 1; off < 16; off <<= 1) {
#pragma unroll
        for (int r = 0; r < 4; ++r) {
            ps[r] += __shfl_xor(ps[r], off);
            qs[r] += __shfl_xor(qs[r], off);
        }
    }
    if (lo == 0) {
#pragma unroll
        for (int r = 0; r < 4; ++r) {
            red[wv][kg * 4 + r][0] = ps[r];
            red[wv][kg * 4 + r][1] = qs[r];
        }
    }
    __syncthreads();
    float mean[4], rs[4];
#pragma unroll
    for (int r = 0; r < 4; ++r) {
        const int row = kg * 4 + r;
        float s = red[0][row][0] + red[1][row][0] + red[2][row][0] + red[3][row][0];
        float q = red[0][row][1] + red[1][row][1] + red[2][row][1] + red[3][row][1];
        mean[r] = s * (1.f / 256.f);
        float var = q * (1.f / 256.f) - mean[r] * mean[r];
        rs[r] = rsqrtf(var + EPS_);
    }
#pragma unroll
    for (int ni = 0; ni < 4; ++ni) {
        const int gn = wv * 64 + ni * 16 + lo;
        const float g = gw[gn], b2 = gb[gn];
#pragma unroll
        for (int r = 0; r < 4; ++r)
            O[(size_t)(gmb + r) * 256 + gn] = (vvv[ni][r] - mean[r]) * rs[r] * g + b2;
    }
}

// ---------------- Fused SA attention; LDS-aliased; XCD-grouped; setprio on MFMA ----------------
__global__ __launch_bounds__(256) void sa_fused(const ushort* __restrict__ q,
    const ushort* __restrict__ k, const ushort* __restrict__ v, ushort* __restrict__ ctx)
{
    __shared__ __align__(16) char sm[62976];
    ushort* Vt = (ushort*)sm;             // [d][key] 32 x 328
    ushort* Kt = (ushort*)(sm + 20992);   // [key][d] 304 x 40
    ushort* Pt = (ushort*)(sm + 20992);   // [wv][l][key] 4 x 16 x 328 (aliases Kt)
    const int t = threadIdx.x, lane = t & 63, wv = t >> 6;
    const int lo = lane & 15, kg = lane >> 4;
    const int linear = blockIdx.x + 5 * blockIdx.y;
    const int xcd = linear & 7, slot = linear >> 3;
    const int l0 = (slot % 5) * 64;
    const int bh = xcd + 8 * (slot / 5);
    const ushort* qp = q + (size_t)bh * 9600;
    const ushort* kp = k + (size_t)bh * 9600;
    const ushort* vp = v + (size_t)bh * 9600;

    for (int e = t; e < 1216; e += 256) {
        int row = e >> 2, dq = (e & 3) << 3;
        uint4 kv = (row < 300) ? *(const uint4*)(kp + row * 32 + dq)
                               : make_uint4(0, 0, 0, 0);
        *(uint4*)&Kt[row * 40 + dq] = kv;
    }
    for (int e = t; e < 1200; e += 256) {
        int row = e >> 2, dq = (e & 3) << 3;
        uint4 vv4 = *(const uint4*)(vp + row * 32 + dq);
        const ushort* sv = (const ushort*)&vv4;
#pragma unroll
        for (int j = 0; j < 8; ++j) Vt[(dq + j) * 328 + row] = sv[j];
    }
    for (int e = t; e < 32 * 28; e += 256) {
        int d = e / 28, kk = 300 + e % 28;
        Vt[d * 328 + kk] = 0;
    }
    const int ql = l0 + wv * 16 + lo;
    bf16x8 qf = {0, 0, 0, 0, 0, 0, 0, 0};
    if (ql < 300) qf = *(const bf16x8*)(qp + ql * 32 + kg * 8);
    __syncthreads();

    f32x4 s[19];
    __builtin_amdgcn_s_setprio(1);
#pragma unroll
    for (int f = 0; f < 19; ++f) {
        bf16x8 af = *(const bf16x8*)&Kt[(f * 16 + lo) * 40 + kg * 8];
        f32x4 z = {0.f, 0.f, 0.f, 0.f};
        s[f] = __builtin_amdgcn_mfma_f32_16x16x32_bf16(af, qf, z, 0, 0, 0);
    }
    __builtin_amdgcn_s_setprio(0);
    if (kg == 3) { s[18][0] = -3.4e38f; s[18][1] = -3.4e38f; s[18][2] = -3.4e38f; s[18][3] = -3.4e38f; }

    float mx = -3.4e38f;
#pragma unroll
    for (int f = 0; f < 19; ++f)
#pragma unroll
        for (int r = 0; r < 4; ++r) mx = fmaxf(mx, s[f][r]);
    mx = fmaxf(mx, __shfl_xor(mx, 16));
    mx = fmaxf(mx, __shfl_xor(mx, 32));
    float sum = 0.f;
#pragma unroll
    for (int f = 0; f < 19; ++f)
#pragma unroll
        for (int r = 0; r < 4; ++r) { s[f][r] = __expf(s[f][r] - mx); sum += s[f][r]; }
    sum += __shfl_xor(sum, 16);
    sum += __shfl_xor(sum, 32);
    const float inv = 1.f / sum;

    __syncthreads();   // all waves done reading Kt; Pt may overwrite

    ushort* Ptw = Pt + wv * (16 * 328);
#pragma unroll
    for (int f = 0; f < 19; ++f) {
        *(unsigned*)&Ptw[lo * 328 + f * 16 + kg * 4]     = pk2(s[f][0] * inv, s[f][1] * inv);
        *(unsigned*)&Ptw[lo * 328 + f * 16 + kg * 4 + 2] = pk2(s[f][2] * inv, s[f][3] * inv);
    }
    {
        uint2 z2 = make_uint2(0, 0);
        *(uint2*)&Ptw[(lane & 15) * 328 + 304 + ((lane >> 4) << 2)] = z2;
    }

    f32x4 o0 = {0.f, 0.f, 0.f, 0.f}, o1 = {0.f, 0.f, 0.f, 0.f};
    __builtin_amdgcn_s_setprio(1);
#pragma unroll
    for (int f = 0; f < 10; ++f) {
        bf16x8 pa = *(const bf16x8*)&Ptw[lo * 328 + f * 32 + kg * 8];
        bf16x8 b0 = *(const bf16x8*)&Vt[lo * 328 + f * 32 + kg * 8];
        bf16x8 b1 = *(const bf16x8*)&Vt[(16 + lo) * 328 + f * 32 + kg * 8];
        o0 = __builtin_amdgcn_mfma_f32_16x16x32_bf16(pa, b0, o0, 0, 0, 0);
        o1 = __builtin_amdgcn_mfma_f32_16x16x32_bf16(pa, b1, o1, 0, 0, 0);
    }
    __builtin_amdgcn_s_setprio(0);

    const int lb = l0 + wv * 16 + kg * 4;
    const int b = bh >> 3, h = bh & 7;
#pragma unroll
    for (int r = 0; r < 4; ++r) {
        int l = lb + r;
        if (l < 300) {
            ushort* op = ctx + ((size_t)b * 300 + l) * 256 + h * 32;
            op[lo] = f2b(o0[r]);
            op[lo + 16] = f2b(o1[r]);
        }
    }
}

// ---------------- Fused CA; LDS-aliased; XCD-grouped; depth-1 vv prefetch; setprio ----------------
__global__ __launch_bounds__(256) void ca_fused(const ushort* __restrict__ qr,
    const ushort* __restrict__ qc, const ushort* __restrict__ kr, const ushort* __restrict__ kc,
    const ushort* __restrict__ vv, ushort* __restrict__ out)
{
    __shared__ __align__(16) char sm[45056];
    ushort* s_ar = (ushort*)sm;             // [l][w] 64 x 72 bf16
    float*  s_ac = (float*)(sm + 9216);     // [h][l] 64 x 68 f32
    ushort* Kr   = (ushort*)(sm + 26624);   // 64 x 40
    ushort* Kc   = (ushort*)(sm + 31744);   // 64 x 40
    ushort* vvT  = (ushort*)(sm + 26624);   // [buf][h'][d][w] 2 x 2 x 32 x 72

    const int t = threadIdx.x, lane = t & 63, wv = t >> 6;
    const int lo = lane & 15, kg = lane >> 4;
    const int linear = blockIdx.x + 5 * (blockIdx.y + 8 * blockIdx.z);
    const int xcd = linear & 7, slot = linear >> 3;
    const int l0 = (slot % 5) * 64;
    const int bh = xcd + 8 * (slot / 5);
    const int nh = bh & 7, b = bh >> 3;

    {
        const ushort* krp = kr + (size_t)bh * 2048;
        const ushort* kcp = kc + (size_t)bh * 2048;
        int row = t >> 2, dq = (t & 3) << 3;
        *(uint4*)&Kr[row * 40 + dq] = *(const uint4*)(krp + row * 32 + dq);
        *(uint4*)&Kc[row * 40 + dq] = *(const uint4*)(kcp + row * 32 + dq);
    }
    const int ql = l0 + wv * 16 + lo;
    bf16x8 qrf = {0,0,0,0,0,0,0,0}, qcf = {0,0,0,0,0,0,0,0};
    if (ql < 300) {
        qrf = *(const bf16x8*)(qr + (size_t)bh * 9600 + ql * 32 + kg * 8);
        qcf = *(const bf16x8*)(qc + (size_t)bh * 9600 + ql * 32 + kg * 8);
    }
    const ushort* vvp = vv + (size_t)bh * 131072;
    __syncthreads();   // Kr/Kc staged

#pragma unroll
    for (int m = 0; m < 2; ++m) {
        const ushort* Kp = m ? Kc : Kr;
        const bf16x8 qf = m ? qcf : qrf;
        f32x4 s[4];
#pragma unroll
        for (int f = 0; f < 4; ++f) {
            bf16x8 af = *(const bf16x8*)&Kp[(f * 16 + lo) * 40 + kg * 8];
            f32x4 z = {0.f, 0.f, 0.f, 0.f};
            s[f] = __builtin_amdgcn_mfma_f32_16x16x32_bf16(af, qf, z, 0, 0, 0);
        }
        float mx = -3.4e38f;
#pragma unroll
        for (int f = 0; f < 4; ++f)
#pragma unroll
            for (int r = 0; r < 4; ++r) mx = fmaxf(mx, s[f][r]);
        mx = fmaxf(mx, __shfl_xor(mx, 16));
        mx = fmaxf(mx, __shfl_xor(mx, 32));
        float sum = 0.f;
#pragma unroll
        for (int f = 0; f < 4; ++f)
#pragma unroll
            for (int r = 0; r < 4; ++r) { s[f][r] = __expf(s[f][r] - mx); sum += s[f][r]; }
        sum += __shfl_xor(sum, 16);
        sum += __shfl_xor(sum, 32);
        const float inv = 1.f / sum;
        if (m == 0) {
#pragma unroll
            for (int f = 0; f < 4; ++f) {
                *(unsigned*)&s_ar[(wv * 16 + lo) * 72 + f * 16 + kg * 4]     = pk2(s[f][0] * inv, s[f][1] * inv);
                *(unsigned*)&s_ar[(wv * 16 + lo) * 72 + f * 16 + kg * 4 + 2] = pk2(s[f][2] * inv, s[f][3] * inv);
            }
        } else {
#pragma unroll
            for (int f = 0; f < 4; ++f)
#pragma unroll
                for (int r = 0; r < 4; ++r)
                    s_ac[(f * 16 + kg * 4 + r) * 68 + wv * 16 + lo] = s[f][r] * inv;
        }
    }

    __syncthreads();   // done reading Kr/Kc; vvT may overwrite

#pragma unroll
    for (int i = 0; i < 2; ++i) {
        int c = t + 256 * i;
        int h1 = c >> 8, d = (c >> 3) & 31, w8 = (c & 7) << 3;
        uint4 v4 = *(const uint4*)(vvp + h1 * 2048 + d * 64 + w8);
        *(uint4*)&vvT[(h1 * 32 + d) * 72 + w8] = v4;
    }
    __syncthreads();

    const bf16x8 af0 = *(const bf16x8*)&s_ar[(wv * 16 + lo) * 72 + kg * 8];
    const bf16x8 af1 = *(const bf16x8*)&s_ar[(wv * 16 + lo) * 72 + 32 + kg * 8];

    f32x4 acc0 = {0.f, 0.f, 0.f, 0.f};
    f32x4 acc1 = {0.f, 0.f, 0.f, 0.f};

    for (int it = 0; it < 32; ++it) {
        const int cur = it & 1;
        uint4 pre[2];
        if (it < 31) {
            const ushort* nxt = vvp + (size_t)(2 * (it + 1)) * 2048;
#pragma unroll
            for (int i = 0; i < 2; ++i) {
                int c = t + 256 * i;
                int h1 = c >> 8, d = (c >> 3) & 31, w8 = (c & 7) << 3;
                pre[i] = *(const uint4*)(nxt + h1 * 2048 + d * 64 + w8);
            }
        }
        __builtin_amdgcn_s_setprio(1);
#pragma unroll
        for (int hh = 0; hh < 2; ++hh) {
            const int h = 2 * it + hh;
            const ushort* vt = &vvT[(cur * 2 + hh) * 32 * 72];
            bf16x8 b00 = *(const bf16x8*)&vt[lo * 72 + kg * 8];
            bf16x8 b01 = *(const bf16x8*)&vt[lo * 72 + 32 + kg * 8];
            bf16x8 b10 = *(const bf16x8*)&vt[(16 + lo) * 72 + kg * 8];
            bf16x8 b11 = *(const bf16x8*)&vt[(16 + lo) * 72 + 32 + kg * 8];
            f32x4 z = {0.f, 0.f, 0.f, 0.f};
            f32x4 t0 = __builtin_amdgcn_mfma_f32_16x16x32_bf16(af0, b00, z, 0, 0, 0);
            t0 = __builtin_amdgcn_mfma_f32_16x16x32_bf16(af1, b01, t0, 0, 0, 0);
            f32x4 t1 = __builtin_amdgcn_mfma_f32_16x16x32_bf16(af0, b10, z, 0, 0, 0);
            t1 = __builtin_amdgcn_mfma_f32_16x16x32_bf16(af1, b11, t1, 0, 0, 0);
            const float* sp = &s_ac[h * 68 + wv * 16 + kg * 4];
#pragma unroll
            for (int r = 0; r < 4; ++r) {
                float sc = sp[r];
                acc0[r] += sc * t0[r];
                acc1[r] += sc * t1[r];
            }
        }
        __builtin_amdgcn_s_setprio(0);
        if (it < 31) {
#pragma unroll
            for (int i = 0; i < 2; ++i) {
                int c = t + 256 * i;
                int h1 = c >> 8, d = (c >> 3) & 31, w8 = (c & 7) << 3;
                *(uint4*)&vvT[((cur ^ 1) * 2 + h1) * 32 * 72 + d * 72 + w8] = pre[i];
            }
        }
        __syncthreads();
    }

    const int lbase = l0 + wv * 16 + kg * 4;
#pragma unroll
    for (int r = 0; r < 4; ++r) {
        if (lbase + r < 300) {
            ushort* op = out + ((size_t)b * 300 + lbase + r) * 256 + nh * 32;
            op[lo] = f2b(acc0[r]);
            op[16 + lo] = f2b(acc1[r]);
        }
    }
}

extern "C" void kernel_launch(void* const* d_in, const int* in_sizes, int n_in,
                              void* d_out, int out_size, void* d_ws, size_t ws_size,
                              hipStream_t stream)
{
    (void)in_sizes; (void)n_in; (void)out_size; (void)ws_size;
    const float* tgt   = (const float*)d_in[0];
    const float* qpos  = (const float*)d_in[1];
    const float* qpx   = (const float*)d_in[2];
    const float* qpy   = (const float*)d_in[3];
    const float* srcs  = (const float*)d_in[4];
    const float* prow  = (const float*)d_in[6];
    const float* pcol  = (const float*)d_in[7];
    const float* sa_w  = (const float*)d_in[8];
    const float* sa_b  = (const float*)d_in[9];
    const float* sa_ow = (const float*)d_in[10];
    const float* sa_ob = (const float*)d_in[11];
    const float* ca_w  = (const float*)d_in[12];
    const float* ca_b  = (const float*)d_in[13];
    const float* ca_ow = (const float*)d_in[14];
    const float* ca_ob = (const float*)d_in[15];
    const float* n1w   = (const float*)d_in[16];
    const float* n1b   = (const float*)d_in[17];
    const float* n2w   = (const float*)d_in[18];
    const float* n2b   = (const float*)d_in[19];
    const float* l1w   = (const float*)d_in[20];
    const float* l1b   = (const float*)d_in[21];
    const float* l2w   = (const float*)d_in[22];
    const float* l2b   = (const float*)d_in[23];
    const float* nfw   = (const float*)d_in[24];
    const float* nfb   = (const float*)d_in[25];
    float* out = (float*)d_out;
    float* ws  = (float*)d_ws;

    float* tgt2  = ws + 1228800;
    float* tgt3  = ws + 2457600;
    float* rowm  = ws + 3686400;       // (B,64,E) f32
    float* colm  = ws + 3948544;
    ushort* u    = (ushort*)(ws + 4210688);
    ushort* q16    = u;                // (B,H,L,HD)
    ushort* k16    = u + 1228800;
    ushort* v16    = u + 2457600;
    ushort* ctx16  = u + 3686400;      // (B,L,E)
    ushort* qrow16 = u + 4915200;
    ushort* qcol16 = u + 6144000;
    ushort* krow16 = u + 7372800;      // (B,H,64,HD)
    ushort* kcol16 = u + 7634944;
    ushort* ffm16  = u + 7897088;      // (B,L,FF)
    ushort* vvb    = u + 12812288;     // vvT: (B*H)[h][d][w] bf16
    ushort* wbf    = u + 29589504;     // bf16 weight pool
    ushort* w_sa   = wbf;              // 768x256
    ushort* w_sao  = wbf + 196608;     // 256x256
    ushort* w_ca   = wbf + 262144;     // 5 x 256x256
    ushort* w_cao  = wbf + 589824;     // 256x256
    ushort* w_l1   = wbf + 655360;     // 1024x256
    ushort* w_l2   = wbf + 917504;     // 256x1024

    // ---- prep: weight conversion + src means (one launch) ----
    prep<<<5248,256,0,stream>>>(sa_w, sa_ow, ca_w, ca_ow, l1w, l2w, wbf,
                                srcs, rowm, colm);

    // ---- Self-attention ----
    mgemm<64,64,0,true,false,1,false,false><<<dim3(75,12),256,0,stream>>>(
        tgt, qpos, w_sa, sa_b, q16, k16, v16, 4800, 768, 256, 300, SCALE_, 512,
        nullptr, nullptr, nullptr, nullptr, nullptr);
    sa_fused<<<dim3(5,128),256,0,stream>>>(q16, k16, v16, ctx16);
    mgemm_ln<256><<<300,256,0,stream>>>(ctx16, w_sao, sa_ob, tgt, n2w, n2b, tgt2);

    // ---- Cross-attention prep ----
    mgemm_maps<<<dim3(75,4,4),256,0,stream>>>(
        tgt2, tgt2, rowm, colm,
        qpx, qpy, prow, pcol,
        w_ca, w_ca + 65536, w_ca + 2*65536, w_ca + 3*65536,
        ca_b, ca_b + 256, ca_b + 512, ca_b + 768,
        qrow16, qcol16, krow16, kcol16);
    mgemm<128,128,3,false,false,2,false,true><<<dim3(512,2),256,0,stream>>>(
        srcs, nullptr, w_ca + 4*65536, ca_b + 1024, vvb, nullptr, nullptr,
        65536, 256, 256, 0, 1.f, 0,
        nullptr, nullptr, nullptr, nullptr, nullptr);

    // ---- CA fused core + out proj + LN ----
    ca_fused<<<dim3(5,8,16),256,0,stream>>>(qrow16, qcol16, krow16, kcol16, vvb, ctx16);
    mgemm_ln<256><<<300,256,0,stream>>>(ctx16, w_cao, ca_ob, tgt2, n1w, n1b, tgt3);

    // ---- FFN ----
    mgemm<64,128,0,false,true,3,false,false><<<dim3(75,8),256,0,stream>>>(
        tgt3, nullptr, w_l1, l1b, ffm16, nullptr, nullptr, 4800, 1024, 256, 0, 1.f, 0,
        nullptr, nullptr, nullptr, nullptr, nullptr);
    mgemm_ln<1024><<<300,256,0,stream>>>(ffm16, w_l2, l2b, tgt3, nfw, nfb, out);
}

// Round 18
// 169.980 us; speedup vs baseline: 1.2444x; 1.0427x over previous
//
#include <hip/hip_runtime.h>

#define B_ 16
#define L_ 300
#define E_ 256
#define H_ 8
#define HD_ 32
#define FF_ 1024
#define SCALE_ 0.17677669529663687f
#define EPS_ 1e-5f

typedef __attribute__((ext_vector_type(8))) short bf16x8;
typedef __attribute__((ext_vector_type(4))) float f32x4;

__device__ __forceinline__ ushort f2b(float f) {
    unsigned u = __float_as_uint(f);
    u += 0x7fff + ((u >> 16) & 1);
    return (ushort)(u >> 16);
}
// packed f32x2 -> bf16x2 via HW cvt (RNE), 1 VALU op
__device__ __forceinline__ unsigned pk2(float a, float b) {
    unsigned r;
    asm("v_cvt_pk_bf16_f32 %0, %1, %2" : "=v"(r) : "v"(a), "v"(b));
    return r;
}

// ---------------- prep: weight f32->bf16 conversion + src means, one launch ----------------
__global__ __launch_bounds__(256) void prep(
    const float* __restrict__ w0, const float* __restrict__ w1,
    const float* __restrict__ w2, const float* __restrict__ w3,
    const float* __restrict__ w4, const float* __restrict__ w5,
    ushort* __restrict__ dst,
    const float* __restrict__ srcs, float* __restrict__ rowm, float* __restrict__ colm)
{
    __shared__ float tile[64 * 65];
    if (blockIdx.x < 1152) {
        int i4 = blockIdx.x * 256 + threadIdx.x;
        const float* src; int base4;
        if (i4 < 49152)       { src = w0; base4 = 0; }
        else if (i4 < 65536)  { src = w1; base4 = 49152; }
        else if (i4 < 147456) { src = w2; base4 = 65536; }
        else if (i4 < 163840) { src = w3; base4 = 147456; }
        else if (i4 < 229376) { src = w4; base4 = 163840; }
        else                  { src = w5; base4 = 229376; }
        float4 v = *(const float4*)(src + (size_t)(i4 - base4) * 4);
        uint2 pk; pk.x = pk2(v.x, v.y); pk.y = pk2(v.z, v.w);
        *(uint2*)(dst + (size_t)i4 * 4) = pk;
    } else {
        const int bc = blockIdx.x - 1152;
        const int b = bc >> 8, c = bc & 255;
        const float* sp = srcs + (size_t)bc * 4096;
        for (int e = threadIdx.x; e < 4096; e += 256) tile[(e >> 6) * 65 + (e & 63)] = sp[e];
        __syncthreads();
        const int t = threadIdx.x;
        if (t < 64) {
            float s = 0.f;
            for (int y = 0; y < 64; ++y) s += tile[y * 65 + t];
            rowm[((size_t)b * 64 + t) * 256 + c] = s * (1.f / 64.f);
        } else if (t < 128) {
            int y = t - 64;
            float s = 0.f;
            for (int x = 0; x < 64; ++x) s += tile[y * 65 + x];
            colm[((size_t)b * 64 + y) * 256 + c] = s * (1.f / 64.f);
        }
    }
}

// ---------------- Pipelined bf16 MFMA GEMM, depth-2 register prefetch; bf16 W ----------------
// AMODE: 0 = f32 A (+ADD2 if n0<a2lim); 2 = bf16 A row-major; 3 = srcs layout (BM=128).
// CL: 1 = bf16 BHLD 3-way dest (qscale on gn<256); 2 = bf16 vvT [b*8+nh][h][d][w];
//     3 = bf16 row-major.
template<int BM, int BN, int AMODE, bool ADD2, bool RELU, int CL, bool DUAL, bool SWZ>
__global__ __launch_bounds__(256) void mgemm(
    const void* __restrict__ A_, const float* __restrict__ A2_,
    const ushort* __restrict__ W_, const float* __restrict__ bias_,
    void* __restrict__ C0_, void* __restrict__ C1_,
    void* __restrict__ C2_, int M, int N, int K, int Lh, float qscale, int a2lim,
    const void* __restrict__ Ab_, const float* __restrict__ A2b_,
    const ushort* __restrict__ Wb_, const float* __restrict__ biasb_, void* __restrict__ C0b_)
{
    constexpr int TM = BM / 2, TN = BN / 2;
    constexpr int FM = TM / 16, FN = TN / 16;
    constexpr int LDT = 40;
    constexpr int NAR = (AMODE == 2) ? (BM / 64) : (BM / 32);
    constexpr int NWR = BN / 32;
    __shared__ ushort sA[BM * LDT];
    __shared__ ushort sW[BN * LDT];
    const int t = threadIdx.x;
    const int lane = t & 63, wv = t >> 6;
    const int lo = lane & 15, kg = lane >> 4;
    const int wm = wv >> 1, wn = wv & 1;
    int bx = blockIdx.x, by = blockIdx.y;
    if constexpr (SWZ) {
        int linear = blockIdx.x + gridDim.x * blockIdx.y;
        int xcd = linear & 7, s = linear >> 3;
        by = s & 1; bx = (s >> 1) * 8 + xcd;
    }
    const int m0 = bx * BM, n0 = by * BN;

    const void* Ap = A_; const float* A2p = A2_; const ushort* Wp = W_;
    const float* biasp = bias_; void* C0v = C0_;
    if constexpr (DUAL) {
        if (blockIdx.z) { Ap = Ab_; A2p = A2b_; Wp = Wb_; biasp = biasb_; C0v = C0b_; }
    }

    struct RS {
        float4 ra[(AMODE == 0) ? NAR : 1];
        uint4  ra16[(AMODE == 2) ? NAR : 1];
        float  ra3[(AMODE == 3) ? 16 : 1];
        uint2  rw[NWR];
    };
    RS s0, s1;

    auto LOAD = [&](int k0, RS& S) {
        if constexpr (AMODE == 0) {
            const float* A = (const float*)Ap;
#pragma unroll
            for (int i = 0; i < NAR; ++i) {
                int e = t + 256 * i;
                int m = e >> 3, kc = (e & 7) << 2;
                float4 va = *(const float4*)(A + (size_t)(m0 + m) * K + k0 + kc);
                if constexpr (ADD2) {
                    if (n0 < a2lim) {
                        float4 v2 = *(const float4*)(A2p + (size_t)(m0 + m) * K + k0 + kc);
                        va.x += v2.x; va.y += v2.y; va.z += v2.z; va.w += v2.w;
                    }
                }
                S.ra[i] = va;
            }
        } else if constexpr (AMODE == 2) {
            const ushort* A = (const ushort*)Ap;
#pragma unroll
            for (int i = 0; i < NAR; ++i) {
                int e = t + 256 * i;
                int m = e >> 2, c = (e & 3) << 3;
                S.ra16[i] = *(const uint4*)(A + (size_t)(m0 + m) * K + k0 + c);
            }
        } else {
            const float* A = (const float*)Ap;
            const int bb = m0 >> 12, p0 = m0 & 4095;
#pragma unroll
            for (int i = 0; i < 2; ++i) {
                int e = t + 256 * i;
                int m = e & 127, kslot = e >> 7;
                const float* base = A + ((size_t)(bb * 256 + k0 + kslot * 8)) * 4096 + p0 + m;
#pragma unroll
                for (int j = 0; j < 8; ++j) S.ra3[i * 8 + j] = base[(size_t)j * 4096];
            }
        }
#pragma unroll
        for (int i = 0; i < NWR; ++i) {
            int e = t + 256 * i;
            int n = e >> 3, kc = (e & 7) << 2;
            S.rw[i] = *(const uint2*)(Wp + (size_t)(n0 + n) * K + k0 + kc);
        }
    };
    auto STORE = [&](RS& S) {
        if constexpr (AMODE == 0) {
#pragma unroll
            for (int i = 0; i < NAR; ++i) {
                int e = t + 256 * i;
                int m = e >> 3, kc = (e & 7) << 2;
                uint2 pk; pk.x = pk2(S.ra[i].x, S.ra[i].y); pk.y = pk2(S.ra[i].z, S.ra[i].w);
                *(uint2*)&sA[m * LDT + kc] = pk;
            }
        } else if constexpr (AMODE == 2) {
#pragma unroll
            for (int i = 0; i < NAR; ++i) {
                int e = t + 256 * i;
                int m = e >> 2, c = (e & 3) << 3;
                *(uint4*)&sA[m * LDT + c] = S.ra16[i];
            }
        } else {
#pragma unroll
            for (int i = 0; i < 2; ++i) {
                int e = t + 256 * i;
                int m = e & 127, kslot = e >> 7;
                uint4 pk;
                pk.x = pk2(S.ra3[i * 8 + 0], S.ra3[i * 8 + 1]);
                pk.y = pk2(S.ra3[i * 8 + 2], S.ra3[i * 8 + 3]);
                pk.z = pk2(S.ra3[i * 8 + 4], S.ra3[i * 8 + 5]);
                pk.w = pk2(S.ra3[i * 8 + 6], S.ra3[i * 8 + 7]);
                *(uint4*)&sA[m * LDT + kslot * 8] = pk;
            }
        }
#pragma unroll
        for (int i = 0; i < NWR; ++i) {
            int e = t + 256 * i;
            int n = e >> 3, kc = (e & 7) << 2;
            *(uint2*)&sW[n * LDT + kc] = S.rw[i];
        }
    };

    f32x4 acc[FM][FN];
#pragma unroll
    for (int i = 0; i < FM; ++i)
#pragma unroll
        for (int j = 0; j < FN; ++j) acc[i][j] = (f32x4){0.f, 0.f, 0.f, 0.f};

    auto MFMAstep = [&]() {
        bf16x8 af[FM], bfr[FN];
#pragma unroll
        for (int mi = 0; mi < FM; ++mi)
            af[mi] = *(const bf16x8*)&sA[(wm * TM + mi * 16 + lo) * LDT + kg * 8];
#pragma unroll
        for (int ni = 0; ni < FN; ++ni)
            bfr[ni] = *(const bf16x8*)&sW[(wn * TN + ni * 16 + lo) * LDT + kg * 8];
#pragma unroll
        for (int mi = 0; mi < FM; ++mi)
#pragma unroll
            for (int ni = 0; ni < FN; ++ni)
                acc[mi][ni] = __builtin_amdgcn_mfma_f32_16x16x32_bf16(af[mi], bfr[ni], acc[mi][ni], 0, 0, 0);
    };

    LOAD(0, s0); LOAD(32, s1);
    for (int k0 = 0; k0 < K; k0 += 64) {
        STORE(s0);
        __syncthreads();
        if (k0 + 64 < K) LOAD(k0 + 64, s0);
        MFMAstep();
        __syncthreads();
        STORE(s1);
        __syncthreads();
        if (k0 + 96 < K) LOAD(k0 + 96, s1);
        MFMAstep();
        __syncthreads();
    }

    if constexpr (CL == 2) {
#pragma unroll
        for (int mi = 0; mi < FM; ++mi) {
            const int gmb = m0 + wm * TM + mi * 16 + kg * 4;
            const int b = gmb >> 12, p = gmb & 4095;
            const int h = p >> 6, w = p & 63;
#pragma unroll
            for (int ni = 0; ni < FN; ++ni) {
                const int gn = n0 + wn * TN + ni * 16 + lo;
                const int nh = gn >> 5, dd = gn & 31;
                const float bs = biasp[gn];
                uint2 pk;
                pk.x = pk2(acc[mi][ni][0] + bs, acc[mi][ni][1] + bs);
                pk.y = pk2(acc[mi][ni][2] + bs, acc[mi][ni][3] + bs);
                *(uint2*)((ushort*)C0v + ((size_t)(b * 8 + nh)) * 131072 + h * 2048 + dd * 64 + w) = pk;
            }
        }
    } else {
#pragma unroll
        for (int mi = 0; mi < FM; ++mi) {
#pragma unroll
            for (int r = 0; r < 4; ++r) {
                const int gm = m0 + wm * TM + mi * 16 + kg * 4 + r;
#pragma unroll
                for (int ni = 0; ni < FN; ++ni) {
                    const int gn = n0 + wn * TN + ni * 16 + lo;
                    float v = acc[mi][ni][r] + biasp[gn];
                    if constexpr (RELU) v = fmaxf(v, 0.f);
                    if constexpr (CL == 1) {
                        if (gn < 256) v *= qscale;
                        int head = (gn & 255) >> 5, d = gn & 31;
                        ushort* dst = (gn < 256) ? (ushort*)C0v
                                     : (gn < 512 ? (ushort*)C1_ : (ushort*)C2_);
                        int b = gm / Lh, l = gm - b * Lh;
                        dst[(((size_t)b * H_ + head) * Lh + l) * HD_ + d] = f2b(v);
                    } else {
                        ushort* C0 = (ushort*)C0v;
                        C0[(size_t)gm * N + gn] = f2b(v);
                    }
                }
            }
        }
    }
}

// ---------------- Merged CA map projections (BN=128): z = {qrow, qcol, krow, kcol} ----------------
__global__ __launch_bounds__(256) void mgemm_maps(
    const float* __restrict__ A0, const float* __restrict__ A1,
    const float* __restrict__ A2x, const float* __restrict__ A3,
    const float* __restrict__ P0, const float* __restrict__ P1,
    const float* __restrict__ P2, const float* __restrict__ P3,
    const ushort* __restrict__ W0, const ushort* __restrict__ W1,
    const ushort* __restrict__ W2, const ushort* __restrict__ W3,
    const float* __restrict__ B0, const float* __restrict__ B1,
    const float* __restrict__ B2, const float* __restrict__ B3,
    ushort* __restrict__ C0, ushort* __restrict__ C1,
    ushort* __restrict__ C2, ushort* __restrict__ C3)
{
    constexpr int LDT = 40;
    __shared__ ushort sA[64 * LDT];
    __shared__ ushort sW[128 * LDT];
    const int z = blockIdx.z;
    const int M = (z < 2) ? 4800 : 1024;
    const int m0 = blockIdx.x * 64;
    if (m0 >= M) return;
    const int Lh = (z < 2) ? 300 : 64;
    const float qs = (z < 2) ? SCALE_ : 1.f;
    const float* Ap = (z == 0) ? A0 : (z == 1) ? A1 : (z == 2) ? A2x : A3;
    const float* Pp = (z == 0) ? P0 : (z == 1) ? P1 : (z == 2) ? P2 : P3;
    const ushort* Wp = (z == 0) ? W0 : (z == 1) ? W1 : (z == 2) ? W2 : W3;
    const float* Bp = (z == 0) ? B0 : (z == 1) ? B1 : (z == 2) ? B2 : B3;
    ushort* Cp = (z == 0) ? C0 : (z == 1) ? C1 : (z == 2) ? C2 : C3;
    const int t = threadIdx.x, lane = t & 63, wv = t >> 6;
    const int lo = lane & 15, kg = lane >> 4;
    const int wm = wv >> 1, wn = wv & 1;
    const int n0 = blockIdx.y * 128;

    float4 ra0[2], ra1[2];
    uint2 rw0[4], rw1[4];
    auto LOAD = [&](int k0, float4 (&ra)[2], uint2 (&rw)[4]) {
#pragma unroll
        for (int i = 0; i < 2; ++i) {
            int e = t + 256 * i;
            int m = e >> 3, kc = (e & 7) << 2;
            float4 va = *(const float4*)(Ap + (size_t)(m0 + m) * 256 + k0 + kc);
            float4 v2 = *(const float4*)(Pp + (size_t)(m0 + m) * 256 + k0 + kc);
            va.x += v2.x; va.y += v2.y; va.z += v2.z; va.w += v2.w;
            ra[i] = va;
        }
#pragma unroll
        for (int i = 0; i < 4; ++i) {
            int e = t + 256 * i;
            int n = e >> 3, kc = (e & 7) << 2;
            rw[i] = *(const uint2*)(Wp + (size_t)(n0 + n) * 256 + k0 + kc);
        }
    };
    auto STORE = [&](float4 (&ra)[2], uint2 (&rw)[4]) {
#pragma unroll
        for (int i = 0; i < 2; ++i) {
            int e = t + 256 * i;
            int m = e >> 3, kc = (e & 7) << 2;
            uint2 pk; pk.x = pk2(ra[i].x, ra[i].y); pk.y = pk2(ra[i].z, ra[i].w);
            *(uint2*)&sA[m * LDT + kc] = pk;
        }
#pragma unroll
        for (int i = 0; i < 4; ++i) {
            int e = t + 256 * i;
            int n = e >> 3, kc = (e & 7) << 2;
            *(uint2*)&sW[n * LDT + kc] = rw[i];
        }
    };

    f32x4 acc[2][4];
#pragma unroll
    for (int i = 0; i < 2; ++i)
#pragma unroll
        for (int j = 0; j < 4; ++j) acc[i][j] = (f32x4){0.f, 0.f, 0.f, 0.f};
    auto MFMAstep = [&]() {
        bf16x8 af[2], bfr[4];
#pragma unroll
        for (int mi = 0; mi < 2; ++mi)
            af[mi] = *(const bf16x8*)&sA[(wm * 32 + mi * 16 + lo) * LDT + kg * 8];
#pragma unroll
        for (int ni = 0; ni < 4; ++ni)
            bfr[ni] = *(const bf16x8*)&sW[(wn * 64 + ni * 16 + lo) * LDT + kg * 8];
#pragma unroll
        for (int mi = 0; mi < 2; ++mi)
#pragma unroll
            for (int ni = 0; ni < 4; ++ni)
                acc[mi][ni] = __builtin_amdgcn_mfma_f32_16x16x32_bf16(af[mi], bfr[ni], acc[mi][ni], 0, 0, 0);
    };

    LOAD(0, ra0, rw0); LOAD(32, ra1, rw1);
    for (int k0 = 0; k0 < 256; k0 += 64) {
        STORE(ra0, rw0);
        __syncthreads();
        if (k0 + 64 < 256) LOAD(k0 + 64, ra0, rw0);
        MFMAstep();
        __syncthreads();
        STORE(ra1, rw1);
        __syncthreads();
        if (k0 + 96 < 256) LOAD(k0 + 96, ra1, rw1);
        MFMAstep();
        __syncthreads();
    }

#pragma unroll
    for (int mi = 0; mi < 2; ++mi) {
#pragma unroll
        for (int r = 0; r < 4; ++r) {
            const int gm = m0 + wm * 32 + mi * 16 + kg * 4 + r;
            const int b = gm / Lh, l = gm - b * Lh;
#pragma unroll
            for (int ni = 0; ni < 4; ++ni) {
                const int gn = n0 + wn * 64 + ni * 16 + lo;
                float v = (acc[mi][ni][r] + Bp[gn]) * qs;
                int head = gn >> 5, d = gn & 31;
                Cp[(((size_t)b * H_ + head) * Lh + l) * HD_ + d] = f2b(v);
            }
        }
    }
}

// ---------------- GEMM + residual + LayerNorm fused (BM=16, BN=256=N, bf16 A+W) ----------------
template<int KK>
__global__ __launch_bounds__(256) void mgemm_ln(
    const ushort* __restrict__ A, const ushort* __restrict__ W,
    const float* __restrict__ bias, const float* __restrict__ res,
    const float* __restrict__ gw, const float* __restrict__ gb, float* __restrict__ O)
{
    constexpr int LDT = 40;
    __shared__ ushort sA[16 * LDT];
    __shared__ ushort sW[256 * LDT];
    __shared__ float red[4][16][2];
    const int t = threadIdx.x, lane = t & 63, wv = t >> 6;
    const int lo = lane & 15, kg = lane >> 4;
    const int m0 = blockIdx.x * 16;
    const bool aact = (t < 128);

    uint2 a0, a1;
    uint2 w0[8], w1[8];
    auto LOADA = [&](int k0, uint2& aa) {
        if (aact) aa = *(const uint2*)(A + (size_t)(m0 + (t >> 3)) * KK + k0 + ((t & 7) << 2));
    };
    auto LOADW = [&](int k0, uint2 (&ww)[8]) {
#pragma unroll
        for (int i = 0; i < 8; ++i) {
            int e = t + 256 * i;
            int n = e >> 3, kc = (e & 7) << 2;
            ww[i] = *(const uint2*)(W + (size_t)n * KK + k0 + kc);
        }
    };
    auto STOREA = [&](uint2& aa) {
        if (aact) *(uint2*)&sA[(t >> 3) * LDT + ((t & 7) << 2)] = aa;
    };
    auto STOREW = [&](uint2 (&ww)[8]) {
#pragma unroll
        for (int i = 0; i < 8; ++i) {
            int e = t + 256 * i;
            int n = e >> 3, kc = (e & 7) << 2;
            *(uint2*)&sW[n * LDT + kc] = ww[i];
        }
    };

    f32x4 acc[4];
#pragma unroll
    for (int i = 0; i < 4; ++i) acc[i] = (f32x4){0.f, 0.f, 0.f, 0.f};

    auto MFMAstep = [&]() {
        bf16x8 af = *(const bf16x8*)&sA[lo * LDT + kg * 8];
#pragma unroll
        for (int ni = 0; ni < 4; ++ni) {
            bf16x8 bfr = *(const bf16x8*)&sW[(wv * 64 + ni * 16 + lo) * LDT + kg * 8];
            acc[ni] = __builtin_amdgcn_mfma_f32_16x16x32_bf16(af, bfr, acc[ni], 0, 0, 0);
        }
    };

    LOADA(0, a0); LOADW(0, w0);
    LOADA(32, a1); LOADW(32, w1);
    for (int k0 = 0; k0 < KK; k0 += 64) {
        STOREA(a0); STOREW(w0);
        __syncthreads();
        if (k0 + 64 < KK) { LOADA(k0 + 64, a0); LOADW(k0 + 64, w0); }
        MFMAstep();
        __syncthreads();
        STOREA(a1); STOREW(w1);
        __syncthreads();
        if (k0 + 96 < KK) { LOADA(k0 + 96, a1); LOADW(k0 + 96, w1); }
        MFMAstep();
        __syncthreads();
    }

    const int gmb = m0 + kg * 4;
    float vvv[4][4];
    float ps[4] = {0.f, 0.f, 0.f, 0.f}, qs[4] = {0.f, 0.f, 0.f, 0.f};
#pragma unroll
    for (int ni = 0; ni < 4; ++ni) {
        const int gn = wv * 64 + ni * 16 + lo;
        const float bs = bias[gn];
#pragma unroll
        for (int r = 0; r < 4; ++r) {
            float x = acc[ni][r] + bs + res[(size_t)(gmb + r) * 256 + gn];
            vvv[ni][r] = x;
            ps[r] += x;
            qs[r] += x * x;
        }
    }
#pragma unroll
    for (int off = 1; off < 16; off <<= 1) {
#pragma unroll
        for (int r = 0; r < 4; ++r) {
            ps[r] += __shfl_xor(ps[r], off);
            qs[r] += __shfl_xor(qs[r], off);
        }
    }
    if (lo == 0) {
#pragma unroll
        for (int r = 0; r < 4; ++r) {
            red[wv][kg * 4 + r][0] = ps[r];
            red[wv][kg * 4 + r][1] = qs[r];
        }
    }
    __syncthreads();
    float mean[4], rs[4];
#pragma unroll
    for (int r = 0; r < 4; ++r) {
        const int row = kg * 4 + r;
        float s = red[0][row][0] + red[1][row][0] + red[2][row][0] + red[3][row][0];
        float q = red[0][row][1] + red[1][row][1] + red[2][row][1] + red[3][row][1];
        mean[r] = s * (1.f / 256.f);
        float var = q * (1.f / 256.f) - mean[r] * mean[r];
        rs[r] = rsqrtf(var + EPS_);
    }
#pragma unroll
    for (int ni = 0; ni < 4; ++ni) {
        const int gn = wv * 64 + ni * 16 + lo;
        const float g = gw[gn], b2 = gb[gn];
#pragma unroll
        for (int r = 0; r < 4; ++r)
            O[(size_t)(gmb + r) * 256 + gn] = (vvv[ni][r] - mean[r]) * rs[r] * g + b2;
    }
}

// ---------------- Fused SA attention; LDS-aliased; XCD-grouped; setprio on MFMA ----------------
__global__ __launch_bounds__(256) void sa_fused(const ushort* __restrict__ q,
    const ushort* __restrict__ k, const ushort* __restrict__ v, ushort* __restrict__ ctx)
{
    __shared__ __align__(16) char sm[62976];
    ushort* Vt = (ushort*)sm;             // [d][key] 32 x 328
    ushort* Kt = (ushort*)(sm + 20992);   // [key][d] 304 x 40
    ushort* Pt = (ushort*)(sm + 20992);   // [wv][l][key] 4 x 16 x 328 (aliases Kt)
    const int t = threadIdx.x, lane = t & 63, wv = t >> 6;
    const int lo = lane & 15, kg = lane >> 4;
    const int linear = blockIdx.x + 5 * blockIdx.y;
    const int xcd = linear & 7, slot = linear >> 3;
    const int l0 = (slot % 5) * 64;
    const int bh = xcd + 8 * (slot / 5);
    const ushort* qp = q + (size_t)bh * 9600;
    const ushort* kp = k + (size_t)bh * 9600;
    const ushort* vp = v + (size_t)bh * 9600;

    for (int e = t; e < 1216; e += 256) {
        int row = e >> 2, dq = (e & 3) << 3;
        uint4 kv = (row < 300) ? *(const uint4*)(kp + row * 32 + dq)
                               : make_uint4(0, 0, 0, 0);
        *(uint4*)&Kt[row * 40 + dq] = kv;
    }
    for (int e = t; e < 1200; e += 256) {
        int row = e >> 2, dq = (e & 3) << 3;
        uint4 vv4 = *(const uint4*)(vp + row * 32 + dq);
        const ushort* sv = (const ushort*)&vv4;
#pragma unroll
        for (int j = 0; j < 8; ++j) Vt[(dq + j) * 328 + row] = sv[j];
    }
    for (int e = t; e < 32 * 28; e += 256) {
        int d = e / 28, kk = 300 + e % 28;
        Vt[d * 328 + kk] = 0;
    }
    const int ql = l0 + wv * 16 + lo;
    bf16x8 qf = {0, 0, 0, 0, 0, 0, 0, 0};
    if (ql < 300) qf = *(const bf16x8*)(qp + ql * 32 + kg * 8);
    __syncthreads();

    f32x4 s[19];
    __builtin_amdgcn_s_setprio(1);
#pragma unroll
    for (int f = 0; f < 19; ++f) {
        bf16x8 af = *(const bf16x8*)&Kt[(f * 16 + lo) * 40 + kg * 8];
        f32x4 z = {0.f, 0.f, 0.f, 0.f};
        s[f] = __builtin_amdgcn_mfma_f32_16x16x32_bf16(af, qf, z, 0, 0, 0);
    }
    __builtin_amdgcn_s_setprio(0);
    if (kg == 3) { s[18][0] = -3.4e38f; s[18][1] = -3.4e38f; s[18][2] = -3.4e38f; s[18][3] = -3.4e38f; }

    float mx = -3.4e38f;
#pragma unroll
    for (int f = 0; f < 19; ++f)
#pragma unroll
        for (int r = 0; r < 4; ++r) mx = fmaxf(mx, s[f][r]);
    mx = fmaxf(mx, __shfl_xor(mx, 16));
    mx = fmaxf(mx, __shfl_xor(mx, 32));
    float sum = 0.f;
#pragma unroll
    for (int f = 0; f < 19; ++f)
#pragma unroll
        for (int r = 0; r < 4; ++r) { s[f][r] = __expf(s[f][r] - mx); sum += s[f][r]; }
    sum += __shfl_xor(sum, 16);
    sum += __shfl_xor(sum, 32);
    const float inv = 1.f / sum;

    __syncthreads();   // all waves done reading Kt; Pt may overwrite

    ushort* Ptw = Pt + wv * (16 * 328);
#pragma unroll
    for (int f = 0; f < 19; ++f) {
        *(unsigned*)&Ptw[lo * 328 + f * 16 + kg * 4]     = pk2(s[f][0] * inv, s[f][1] * inv);
        *(unsigned*)&Ptw[lo * 328 + f * 16 + kg * 4 + 2] = pk2(s[f][2] * inv, s[f][3] * inv);
    }
    {
        uint2 z2 = make_uint2(0, 0);
        *(uint2*)&Ptw[(lane & 15) * 328 + 304 + ((lane >> 4) << 2)] = z2;
    }

    f32x4 o0 = {0.f, 0.f, 0.f, 0.f}, o1 = {0.f, 0.f, 0.f, 0.f};
    __builtin_amdgcn_s_setprio(1);
#pragma unroll
    for (int f = 0; f < 10; ++f) {
        bf16x8 pa = *(const bf16x8*)&Ptw[lo * 328 + f * 32 + kg * 8];
        bf16x8 b0 = *(const bf16x8*)&Vt[lo * 328 + f * 32 + kg * 8];
        bf16x8 b1 = *(const bf16x8*)&Vt[(16 + lo) * 328 + f * 32 + kg * 8];
        o0 = __builtin_amdgcn_mfma_f32_16x16x32_bf16(pa, b0, o0, 0, 0, 0);
        o1 = __builtin_amdgcn_mfma_f32_16x16x32_bf16(pa, b1, o1, 0, 0, 0);
    }
    __builtin_amdgcn_s_setprio(0);

    const int lb = l0 + wv * 16 + kg * 4;
    const int b = bh >> 3, h = bh & 7;
#pragma unroll
    for (int r = 0; r < 4; ++r) {
        int l = lb + r;
        if (l < 300) {
            ushort* op = ctx + ((size_t)b * 300 + l) * 256 + h * 32;
            op[lo] = f2b(o0[r]);
            op[lo + 16] = f2b(o1[r]);
        }
    }
}

// ---------------- Fused CA; LDS-aliased; XCD-grouped; depth-1 vv prefetch; setprio ----------------
__global__ __launch_bounds__(256) void ca_fused(const ushort* __restrict__ qr,
    const ushort* __restrict__ qc, const ushort* __restrict__ kr, const ushort* __restrict__ kc,
    const ushort* __restrict__ vv, ushort* __restrict__ out)
{
    __shared__ __align__(16) char sm[45056];
    ushort* s_ar = (ushort*)sm;             // [l][w] 64 x 72 bf16
    float*  s_ac = (float*)(sm + 9216);     // [h][l] 64 x 68 f32
    ushort* Kr   = (ushort*)(sm + 26624);   // 64 x 40
    ushort* Kc   = (ushort*)(sm + 31744);   // 64 x 40
    ushort* vvT  = (ushort*)(sm + 26624);   // [buf][h'][d][w] 2 x 2 x 32 x 72

    const int t = threadIdx.x, lane = t & 63, wv = t >> 6;
    const int lo = lane & 15, kg = lane >> 4;
    const int linear = blockIdx.x + 5 * (blockIdx.y + 8 * blockIdx.z);
    const int xcd = linear & 7, slot = linear >> 3;
    const int l0 = (slot % 5) * 64;
    const int bh = xcd + 8 * (slot / 5);
    const int nh = bh & 7, b = bh >> 3;

    {
        const ushort* krp = kr + (size_t)bh * 2048;
        const ushort* kcp = kc + (size_t)bh * 2048;
        int row = t >> 2, dq = (t & 3) << 3;
        *(uint4*)&Kr[row * 40 + dq] = *(const uint4*)(krp + row * 32 + dq);
        *(uint4*)&Kc[row * 40 + dq] = *(const uint4*)(kcp + row * 32 + dq);
    }
    const int ql = l0 + wv * 16 + lo;
    bf16x8 qrf = {0,0,0,0,0,0,0,0}, qcf = {0,0,0,0,0,0,0,0};
    if (ql < 300) {
        qrf = *(const bf16x8*)(qr + (size_t)bh * 9600 + ql * 32 + kg * 8);
        qcf = *(const bf16x8*)(qc + (size_t)bh * 9600 + ql * 32 + kg * 8);
    }
    const ushort* vvp = vv + (size_t)bh * 131072;
    __syncthreads();   // Kr/Kc staged

#pragma unroll
    for (int m = 0; m < 2; ++m) {
        const ushort* Kp = m ? Kc : Kr;
        const bf16x8 qf = m ? qcf : qrf;
        f32x4 s[4];
#pragma unroll
        for (int f = 0; f < 4; ++f) {
            bf16x8 af = *(const bf16x8*)&Kp[(f * 16 + lo) * 40 + kg * 8];
            f32x4 z = {0.f, 0.f, 0.f, 0.f};
            s[f] = __builtin_amdgcn_mfma_f32_16x16x32_bf16(af, qf, z, 0, 0, 0);
        }
        float mx = -3.4e38f;
#pragma unroll
        for (int f = 0; f < 4; ++f)
#pragma unroll
            for (int r = 0; r < 4; ++r) mx = fmaxf(mx, s[f][r]);
        mx = fmaxf(mx, __shfl_xor(mx, 16));
        mx = fmaxf(mx, __shfl_xor(mx, 32));
        float sum = 0.f;
#pragma unroll
        for (int f = 0; f < 4; ++f)
#pragma unroll
            for (int r = 0; r < 4; ++r) { s[f][r] = __expf(s[f][r] - mx); sum += s[f][r]; }
        sum += __shfl_xor(sum, 16);
        sum += __shfl_xor(sum, 32);
        const float inv = 1.f / sum;
        if (m == 0) {
#pragma unroll
            for (int f = 0; f < 4; ++f) {
                *(unsigned*)&s_ar[(wv * 16 + lo) * 72 + f * 16 + kg * 4]     = pk2(s[f][0] * inv, s[f][1] * inv);
                *(unsigned*)&s_ar[(wv * 16 + lo) * 72 + f * 16 + kg * 4 + 2] = pk2(s[f][2] * inv, s[f][3] * inv);
            }
        } else {
#pragma unroll
            for (int f = 0; f < 4; ++f)
#pragma unroll
                for (int r = 0; r < 4; ++r)
                    s_ac[(f * 16 + kg * 4 + r) * 68 + wv * 16 + lo] = s[f][r] * inv;
        }
    }

    __syncthreads();   // done reading Kr/Kc; vvT may overwrite

#pragma unroll
    for (int i = 0; i < 2; ++i) {
        int c = t + 256 * i;
        int h1 = c >> 8, d = (c >> 3) & 31, w8 = (c & 7) << 3;
        uint4 v4 = *(const uint4*)(vvp + h1 * 2048 + d * 64 + w8);
        *(uint4*)&vvT[(h1 * 32 + d) * 72 + w8] = v4;
    }
    __syncthreads();

    const bf16x8 af0 = *(const bf16x8*)&s_ar[(wv * 16 + lo) * 72 + kg * 8];
    const bf16x8 af1 = *(const bf16x8*)&s_ar[(wv * 16 + lo) * 72 + 32 + kg * 8];

    f32x4 acc0 = {0.f, 0.f, 0.f, 0.f};
    f32x4 acc1 = {0.f, 0.f, 0.f, 0.f};

    for (int it = 0; it < 32; ++it) {
        const int cur = it & 1;
        uint4 pre[2];
        if (it < 31) {
            const ushort* nxt = vvp + (size_t)(2 * (it + 1)) * 2048;
#pragma unroll
            for (int i = 0; i < 2; ++i) {
                int c = t + 256 * i;
                int h1 = c >> 8, d = (c >> 3) & 31, w8 = (c & 7) << 3;
                pre[i] = *(const uint4*)(nxt + h1 * 2048 + d * 64 + w8);
            }
        }
        __builtin_amdgcn_s_setprio(1);
#pragma unroll
        for (int hh = 0; hh < 2; ++hh) {
            const int h = 2 * it + hh;
            const ushort* vt = &vvT[(cur * 2 + hh) * 32 * 72];
            bf16x8 b00 = *(const bf16x8*)&vt[lo * 72 + kg * 8];
            bf16x8 b01 = *(const bf16x8*)&vt[lo * 72 + 32 + kg * 8];
            bf16x8 b10 = *(const bf16x8*)&vt[(16 + lo) * 72 + kg * 8];
            bf16x8 b11 = *(const bf16x8*)&vt[(16 + lo) * 72 + 32 + kg * 8];
            f32x4 z = {0.f, 0.f, 0.f, 0.f};
            f32x4 t0 = __builtin_amdgcn_mfma_f32_16x16x32_bf16(af0, b00, z, 0, 0, 0);
            t0 = __builtin_amdgcn_mfma_f32_16x16x32_bf16(af1, b01, t0, 0, 0, 0);
            f32x4 t1 = __builtin_amdgcn_mfma_f32_16x16x32_bf16(af0, b10, z, 0, 0, 0);
            t1 = __builtin_amdgcn_mfma_f32_16x16x32_bf16(af1, b11, t1, 0, 0, 0);
            const float* sp = &s_ac[h * 68 + wv * 16 + kg * 4];
#pragma unroll
            for (int r = 0; r < 4; ++r) {
                float sc = sp[r];
                acc0[r] += sc * t0[r];
                acc1[r] += sc * t1[r];
            }
        }
        __builtin_amdgcn_s_setprio(0);
        if (it < 31) {
#pragma unroll
            for (int i = 0; i < 2; ++i) {
                int c = t + 256 * i;
                int h1 = c >> 8, d = (c >> 3) & 31, w8 = (c & 7) << 3;
                *(uint4*)&vvT[((cur ^ 1) * 2 + h1) * 32 * 72 + d * 72 + w8] = pre[i];
            }
        }
        __syncthreads();
    }

    const int lbase = l0 + wv * 16 + kg * 4;
#pragma unroll
    for (int r = 0; r < 4; ++r) {
        if (lbase + r < 300) {
            ushort* op = out + ((size_t)b * 300 + lbase + r) * 256 + nh * 32;
            op[lo] = f2b(acc0[r]);
            op[16 + lo] = f2b(acc1[r]);
        }
    }
}

extern "C" void kernel_launch(void* const* d_in, const int* in_sizes, int n_in,
                              void* d_out, int out_size, void* d_ws, size_t ws_size,
                              hipStream_t stream)
{
    (void)in_sizes; (void)n_in; (void)out_size; (void)ws_size;
    const float* tgt   = (const float*)d_in[0];
    const float* qpos  = (const float*)d_in[1];
    const float* qpx   = (const float*)d_in[2];
    const float* qpy   = (const float*)d_in[3];
    const float* srcs  = (const float*)d_in[4];
    const float* prow  = (const float*)d_in[6];
    const float* pcol  = (const float*)d_in[7];
    const float* sa_w  = (const float*)d_in[8];
    const float* sa_b  = (const float*)d_in[9];
    const float* sa_ow = (const float*)d_in[10];
    const float* sa_ob = (const float*)d_in[11];
    const float* ca_w  = (const float*)d_in[12];
    const float* ca_b  = (const float*)d_in[13];
    const float* ca_ow = (const float*)d_in[14];
    const float* ca_ob = (const float*)d_in[15];
    const float* n1w   = (const float*)d_in[16];
    const float* n1b   = (const float*)d_in[17];
    const float* n2w   = (const float*)d_in[18];
    const float* n2b   = (const float*)d_in[19];
    const float* l1w   = (const float*)d_in[20];
    const float* l1b   = (const float*)d_in[21];
    const float* l2w   = (const float*)d_in[22];
    const float* l2b   = (const float*)d_in[23];
    const float* nfw   = (const float*)d_in[24];
    const float* nfb   = (const float*)d_in[25];
    float* out = (float*)d_out;
    float* ws  = (float*)d_ws;

    float* tgt2  = ws + 1228800;
    float* tgt3  = ws + 2457600;
    float* rowm  = ws + 3686400;       // (B,64,E) f32
    float* colm  = ws + 3948544;
    ushort* u    = (ushort*)(ws + 4210688);
    ushort* q16    = u;                // (B,H,L,HD)
    ushort* k16    = u + 1228800;
    ushort* v16    = u + 2457600;
    ushort* ctx16  = u + 3686400;      // (B,L,E)
    ushort* qrow16 = u + 4915200;
    ushort* qcol16 = u + 6144000;
    ushort* krow16 = u + 7372800;      // (B,H,64,HD)
    ushort* kcol16 = u + 7634944;
    ushort* ffm16  = u + 7897088;      // (B,L,FF)
    ushort* vvb    = u + 12812288;     // vvT: (B*H)[h][d][w] bf16
    ushort* wbf    = u + 29589504;     // bf16 weight pool
    ushort* w_sa   = wbf;              // 768x256
    ushort* w_sao  = wbf + 196608;     // 256x256
    ushort* w_ca   = wbf + 262144;     // 5 x 256x256
    ushort* w_cao  = wbf + 589824;     // 256x256
    ushort* w_l1   = wbf + 655360;     // 1024x256
    ushort* w_l2   = wbf + 917504;     // 256x1024

    // ---- prep: weight conversion + src means (one launch) ----
    prep<<<5248,256,0,stream>>>(sa_w, sa_ow, ca_w, ca_ow, l1w, l2w, wbf,
                                srcs, rowm, colm);

    // ---- Self-attention ----
    mgemm<64,128,0,true,false,1,false,false><<<dim3(75,6),256,0,stream>>>(
        tgt, qpos, w_sa, sa_b, q16, k16, v16, 4800, 768, 256, 300, SCALE_, 512,
        nullptr, nullptr, nullptr, nullptr, nullptr);
    sa_fused<<<dim3(5,128),256,0,stream>>>(q16, k16, v16, ctx16);
    mgemm_ln<256><<<300,256,0,stream>>>(ctx16, w_sao, sa_ob, tgt, n2w, n2b, tgt2);

    // ---- Cross-attention prep ----
    mgemm_maps<<<dim3(75,2,4),256,0,stream>>>(
        tgt2, tgt2, rowm, colm,
        qpx, qpy, prow, pcol,
        w_ca, w_ca + 65536, w_ca + 2*65536, w_ca + 3*65536,
        ca_b, ca_b + 256, ca_b + 512, ca_b + 768,
        qrow16, qcol16, krow16, kcol16);
    mgemm<128,128,3,false,false,2,false,true><<<dim3(512,2),256,0,stream>>>(
        srcs, nullptr, w_ca + 4*65536, ca_b + 1024, vvb, nullptr, nullptr,
        65536, 256, 256, 0, 1.f, 0,
        nullptr, nullptr, nullptr, nullptr, nullptr);

    // ---- CA fused core + out proj + LN ----
    ca_fused<<<dim3(5,8,16),256,0,stream>>>(qrow16, qcol16, krow16, kcol16, vvb, ctx16);
    mgemm_ln<256><<<300,256,0,stream>>>(ctx16, w_cao, ca_ob, tgt2, n1w, n1b, tgt3);

    // ---- FFN ----
    mgemm<64,128,0,false,true,3,false,false><<<dim3(75,8),256,0,stream>>>(
        tgt3, nullptr, w_l1, l1b, ffm16, nullptr, nullptr, 4800, 1024, 256, 0, 1.f, 0,
        nullptr, nullptr, nullptr, nullptr, nullptr);
    mgemm_ln<1024><<<300,256,0,stream>>>(ffm16, w_l2, l2b, tgt3, nfw, nfb, out);
}

// Round 19
// 168.803 us; speedup vs baseline: 1.2530x; 1.0070x over previous
//
#include <hip/hip_runtime.h>

#define B_ 16
#define L_ 300
#define E_ 256
#define H_ 8
#define HD_ 32
#define FF_ 1024
#define SCALE_ 0.17677669529663687f
#define EPS_ 1e-5f

typedef __attribute__((ext_vector_type(8))) short bf16x8;
typedef __attribute__((ext_vector_type(4))) float f32x4;

__device__ __forceinline__ ushort f2b(float f) {
    unsigned u = __float_as_uint(f);
    u += 0x7fff + ((u >> 16) & 1);
    return (ushort)(u >> 16);
}
// packed f32x2 -> bf16x2 via HW cvt (RNE), 1 VALU op
__device__ __forceinline__ unsigned pk2(float a, float b) {
    unsigned r;
    asm("v_cvt_pk_bf16_f32 %0, %1, %2" : "=v"(r) : "v"(a), "v"(b));
    return r;
}

// ---------------- prep: weight f32->bf16 conversion + src means, one launch ----------------
__global__ __launch_bounds__(256) void prep(
    const float* __restrict__ w0, const float* __restrict__ w1,
    const float* __restrict__ w2, const float* __restrict__ w3,
    const float* __restrict__ w4, const float* __restrict__ w5,
    ushort* __restrict__ dst,
    const float* __restrict__ srcs, float* __restrict__ rowm, float* __restrict__ colm)
{
    __shared__ float tile[64 * 65];
    if (blockIdx.x < 1152) {
        int i4 = blockIdx.x * 256 + threadIdx.x;
        const float* src; int base4;
        if (i4 < 49152)       { src = w0; base4 = 0; }
        else if (i4 < 65536)  { src = w1; base4 = 49152; }
        else if (i4 < 147456) { src = w2; base4 = 65536; }
        else if (i4 < 163840) { src = w3; base4 = 147456; }
        else if (i4 < 229376) { src = w4; base4 = 163840; }
        else                  { src = w5; base4 = 229376; }
        float4 v = *(const float4*)(src + (size_t)(i4 - base4) * 4);
        uint2 pk; pk.x = pk2(v.x, v.y); pk.y = pk2(v.z, v.w);
        *(uint2*)(dst + (size_t)i4 * 4) = pk;
    } else {
        const int bc = blockIdx.x - 1152;
        const int b = bc >> 8, c = bc & 255;
        const float* sp = srcs + (size_t)bc * 4096;
        for (int e = threadIdx.x; e < 4096; e += 256) tile[(e >> 6) * 65 + (e & 63)] = sp[e];
        __syncthreads();
        const int t = threadIdx.x;
        if (t < 64) {
            float s = 0.f;
            for (int y = 0; y < 64; ++y) s += tile[y * 65 + t];
            rowm[((size_t)b * 64 + t) * 256 + c] = s * (1.f / 64.f);
        } else if (t < 128) {
            int y = t - 64;
            float s = 0.f;
            for (int x = 0; x < 64; ++x) s += tile[y * 65 + x];
            colm[((size_t)b * 64 + y) * 256 + c] = s * (1.f / 64.f);
        }
    }
}

// ---------------- Pipelined bf16 MFMA GEMM, depth-2 register prefetch; bf16 W ----------------
// AMODE: 0 = f32 A (+ADD2 if n0<a2lim); 2 = bf16 A row-major; 3 = srcs layout (BM=128).
// CL: 1 = bf16 BHLD 3-way dest (qscale on gn<256); 2 = bf16 vvT [b*8+nh][h][d][w];
//     3 = bf16 row-major.
template<int BM, int BN, int AMODE, bool ADD2, bool RELU, int CL, bool DUAL, bool SWZ>
__global__ __launch_bounds__(256) void mgemm(
    const void* __restrict__ A_, const float* __restrict__ A2_,
    const ushort* __restrict__ W_, const float* __restrict__ bias_,
    void* __restrict__ C0_, void* __restrict__ C1_,
    void* __restrict__ C2_, int M, int N, int K, int Lh, float qscale, int a2lim,
    const void* __restrict__ Ab_, const float* __restrict__ A2b_,
    const ushort* __restrict__ Wb_, const float* __restrict__ biasb_, void* __restrict__ C0b_)
{
    constexpr int TM = BM / 2, TN = BN / 2;
    constexpr int FM = TM / 16, FN = TN / 16;
    constexpr int LDT = 40;
    constexpr int NAR = (AMODE == 2) ? (BM / 64) : (BM / 32);
    constexpr int NWR = BN / 32;
    __shared__ ushort sA[BM * LDT];
    __shared__ ushort sW[BN * LDT];
    const int t = threadIdx.x;
    const int lane = t & 63, wv = t >> 6;
    const int lo = lane & 15, kg = lane >> 4;
    const int wm = wv >> 1, wn = wv & 1;
    int bx = blockIdx.x, by = blockIdx.y;
    if constexpr (SWZ) {
        int linear = blockIdx.x + gridDim.x * blockIdx.y;
        int xcd = linear & 7, s = linear >> 3;
        by = s & 1; bx = (s >> 1) * 8 + xcd;
    }
    const int m0 = bx * BM, n0 = by * BN;

    const void* Ap = A_; const float* A2p = A2_; const ushort* Wp = W_;
    const float* biasp = bias_; void* C0v = C0_;
    if constexpr (DUAL) {
        if (blockIdx.z) { Ap = Ab_; A2p = A2b_; Wp = Wb_; biasp = biasb_; C0v = C0b_; }
    }

    struct RS {
        float4 ra[(AMODE == 0) ? NAR : 1];
        uint4  ra16[(AMODE == 2) ? NAR : 1];
        float  ra3[(AMODE == 3) ? 16 : 1];
        uint2  rw[NWR];
    };
    RS s0, s1;

    auto LOAD = [&](int k0, RS& S) {
        if constexpr (AMODE == 0) {
            const float* A = (const float*)Ap;
#pragma unroll
            for (int i = 0; i < NAR; ++i) {
                int e = t + 256 * i;
                int m = e >> 3, kc = (e & 7) << 2;
                float4 va = *(const float4*)(A + (size_t)(m0 + m) * K + k0 + kc);
                if constexpr (ADD2) {
                    if (n0 < a2lim) {
                        float4 v2 = *(const float4*)(A2p + (size_t)(m0 + m) * K + k0 + kc);
                        va.x += v2.x; va.y += v2.y; va.z += v2.z; va.w += v2.w;
                    }
                }
                S.ra[i] = va;
            }
        } else if constexpr (AMODE == 2) {
            const ushort* A = (const ushort*)Ap;
#pragma unroll
            for (int i = 0; i < NAR; ++i) {
                int e = t + 256 * i;
                int m = e >> 2, c = (e & 3) << 3;
                S.ra16[i] = *(const uint4*)(A + (size_t)(m0 + m) * K + k0 + c);
            }
        } else {
            const float* A = (const float*)Ap;
            const int bb = m0 >> 12, p0 = m0 & 4095;
#pragma unroll
            for (int i = 0; i < 2; ++i) {
                int e = t + 256 * i;
                int m = e & 127, kslot = e >> 7;
                const float* base = A + ((size_t)(bb * 256 + k0 + kslot * 8)) * 4096 + p0 + m;
#pragma unroll
                for (int j = 0; j < 8; ++j) S.ra3[i * 8 + j] = base[(size_t)j * 4096];
            }
        }
#pragma unroll
        for (int i = 0; i < NWR; ++i) {
            int e = t + 256 * i;
            int n = e >> 3, kc = (e & 7) << 2;
            S.rw[i] = *(const uint2*)(Wp + (size_t)(n0 + n) * K + k0 + kc);
        }
    };
    auto STORE = [&](RS& S) {
        if constexpr (AMODE == 0) {
#pragma unroll
            for (int i = 0; i < NAR; ++i) {
                int e = t + 256 * i;
                int m = e >> 3, kc = (e & 7) << 2;
                uint2 pk; pk.x = pk2(S.ra[i].x, S.ra[i].y); pk.y = pk2(S.ra[i].z, S.ra[i].w);
                *(uint2*)&sA[m * LDT + kc] = pk;
            }
        } else if constexpr (AMODE == 2) {
#pragma unroll
            for (int i = 0; i < NAR; ++i) {
                int e = t + 256 * i;
                int m = e >> 2, c = (e & 3) << 3;
                *(uint4*)&sA[m * LDT + c] = S.ra16[i];
            }
        } else {
#pragma unroll
            for (int i = 0; i < 2; ++i) {
                int e = t + 256 * i;
                int m = e & 127, kslot = e >> 7;
                uint4 pk;
                pk.x = pk2(S.ra3[i * 8 + 0], S.ra3[i * 8 + 1]);
                pk.y = pk2(S.ra3[i * 8 + 2], S.ra3[i * 8 + 3]);
                pk.z = pk2(S.ra3[i * 8 + 4], S.ra3[i * 8 + 5]);
                pk.w = pk2(S.ra3[i * 8 + 6], S.ra3[i * 8 + 7]);
                *(uint4*)&sA[m * LDT + kslot * 8] = pk;
            }
        }
#pragma unroll
        for (int i = 0; i < NWR; ++i) {
            int e = t + 256 * i;
            int n = e >> 3, kc = (e & 7) << 2;
            *(uint2*)&sW[n * LDT + kc] = S.rw[i];
        }
    };

    f32x4 acc[FM][FN];
#pragma unroll
    for (int i = 0; i < FM; ++i)
#pragma unroll
        for (int j = 0; j < FN; ++j) acc[i][j] = (f32x4){0.f, 0.f, 0.f, 0.f};

    auto MFMAstep = [&]() {
        bf16x8 af[FM], bfr[FN];
#pragma unroll
        for (int mi = 0; mi < FM; ++mi)
            af[mi] = *(const bf16x8*)&sA[(wm * TM + mi * 16 + lo) * LDT + kg * 8];
#pragma unroll
        for (int ni = 0; ni < FN; ++ni)
            bfr[ni] = *(const bf16x8*)&sW[(wn * TN + ni * 16 + lo) * LDT + kg * 8];
#pragma unroll
        for (int mi = 0; mi < FM; ++mi)
#pragma unroll
            for (int ni = 0; ni < FN; ++ni)
                acc[mi][ni] = __builtin_amdgcn_mfma_f32_16x16x32_bf16(af[mi], bfr[ni], acc[mi][ni], 0, 0, 0);
    };

    LOAD(0, s0); LOAD(32, s1);
    for (int k0 = 0; k0 < K; k0 += 64) {
        STORE(s0);
        __syncthreads();
        if (k0 + 64 < K) LOAD(k0 + 64, s0);
        MFMAstep();
        __syncthreads();
        STORE(s1);
        __syncthreads();
        if (k0 + 96 < K) LOAD(k0 + 96, s1);
        MFMAstep();
        __syncthreads();
    }

    if constexpr (CL == 2) {
#pragma unroll
        for (int mi = 0; mi < FM; ++mi) {
            const int gmb = m0 + wm * TM + mi * 16 + kg * 4;
            const int b = gmb >> 12, p = gmb & 4095;
            const int h = p >> 6, w = p & 63;
#pragma unroll
            for (int ni = 0; ni < FN; ++ni) {
                const int gn = n0 + wn * TN + ni * 16 + lo;
                const int nh = gn >> 5, dd = gn & 31;
                const float bs = biasp[gn];
                uint2 pk;
                pk.x = pk2(acc[mi][ni][0] + bs, acc[mi][ni][1] + bs);
                pk.y = pk2(acc[mi][ni][2] + bs, acc[mi][ni][3] + bs);
                *(uint2*)((ushort*)C0v + ((size_t)(b * 8 + nh)) * 131072 + h * 2048 + dd * 64 + w) = pk;
            }
        }
    } else {
#pragma unroll
        for (int mi = 0; mi < FM; ++mi) {
#pragma unroll
            for (int r = 0; r < 4; ++r) {
                const int gm = m0 + wm * TM + mi * 16 + kg * 4 + r;
#pragma unroll
                for (int ni = 0; ni < FN; ++ni) {
                    const int gn = n0 + wn * TN + ni * 16 + lo;
                    float v = acc[mi][ni][r] + biasp[gn];
                    if constexpr (RELU) v = fmaxf(v, 0.f);
                    if constexpr (CL == 1) {
                        if (gn < 256) v *= qscale;
                        int head = (gn & 255) >> 5, d = gn & 31;
                        ushort* dst = (gn < 256) ? (ushort*)C0v
                                     : (gn < 512 ? (ushort*)C1_ : (ushort*)C2_);
                        int b = gm / Lh, l = gm - b * Lh;
                        dst[(((size_t)b * H_ + head) * Lh + l) * HD_ + d] = f2b(v);
                    } else {
                        ushort* C0 = (ushort*)C0v;
                        C0[(size_t)gm * N + gn] = f2b(v);
                    }
                }
            }
        }
    }
}

// ---------------- Merged CA map projections (BN=256): z = {qrow, qcol, krow, kcol} ----------------
__global__ __launch_bounds__(256) void mgemm_maps(
    const float* __restrict__ A0, const float* __restrict__ A1,
    const float* __restrict__ A2x, const float* __restrict__ A3,
    const float* __restrict__ P0, const float* __restrict__ P1,
    const float* __restrict__ P2, const float* __restrict__ P3,
    const ushort* __restrict__ W0, const ushort* __restrict__ W1,
    const ushort* __restrict__ W2, const ushort* __restrict__ W3,
    const float* __restrict__ B0, const float* __restrict__ B1,
    const float* __restrict__ B2, const float* __restrict__ B3,
    ushort* __restrict__ C0, ushort* __restrict__ C1,
    ushort* __restrict__ C2, ushort* __restrict__ C3)
{
    constexpr int LDT = 40;
    __shared__ ushort sA[64 * LDT];
    __shared__ ushort sW[256 * LDT];
    const int z = blockIdx.z;
    const int M = (z < 2) ? 4800 : 1024;
    const int m0 = blockIdx.x * 64;
    if (m0 >= M) return;
    const int Lh = (z < 2) ? 300 : 64;
    const float qs = (z < 2) ? SCALE_ : 1.f;
    const float* Ap = (z == 0) ? A0 : (z == 1) ? A1 : (z == 2) ? A2x : A3;
    const float* Pp = (z == 0) ? P0 : (z == 1) ? P1 : (z == 2) ? P2 : P3;
    const ushort* Wp = (z == 0) ? W0 : (z == 1) ? W1 : (z == 2) ? W2 : W3;
    const float* Bp = (z == 0) ? B0 : (z == 1) ? B1 : (z == 2) ? B2 : B3;
    ushort* Cp = (z == 0) ? C0 : (z == 1) ? C1 : (z == 2) ? C2 : C3;
    const int t = threadIdx.x, lane = t & 63, wv = t >> 6;
    const int lo = lane & 15, kg = lane >> 4;
    const int wm = wv >> 1, wn = wv & 1;

    float4 ra0[2], ra1[2];
    uint2 rw0[8], rw1[8];
    auto LOAD = [&](int k0, float4 (&ra)[2], uint2 (&rw)[8]) {
#pragma unroll
        for (int i = 0; i < 2; ++i) {
            int e = t + 256 * i;
            int m = e >> 3, kc = (e & 7) << 2;
            float4 va = *(const float4*)(Ap + (size_t)(m0 + m) * 256 + k0 + kc);
            float4 v2 = *(const float4*)(Pp + (size_t)(m0 + m) * 256 + k0 + kc);
            va.x += v2.x; va.y += v2.y; va.z += v2.z; va.w += v2.w;
            ra[i] = va;
        }
#pragma unroll
        for (int i = 0; i < 8; ++i) {
            int e = t + 256 * i;
            int n = e >> 3, kc = (e & 7) << 2;
            rw[i] = *(const uint2*)(Wp + (size_t)n * 256 + k0 + kc);
        }
    };
    auto STORE = [&](float4 (&ra)[2], uint2 (&rw)[8]) {
#pragma unroll
        for (int i = 0; i < 2; ++i) {
            int e = t + 256 * i;
            int m = e >> 3, kc = (e & 7) << 2;
            uint2 pk; pk.x = pk2(ra[i].x, ra[i].y); pk.y = pk2(ra[i].z, ra[i].w);
            *(uint2*)&sA[m * LDT + kc] = pk;
        }
#pragma unroll
        for (int i = 0; i < 8; ++i) {
            int e = t + 256 * i;
            int n = e >> 3, kc = (e & 7) << 2;
            *(uint2*)&sW[n * LDT + kc] = rw[i];
        }
    };

    f32x4 acc[2][8];
#pragma unroll
    for (int i = 0; i < 2; ++i)
#pragma unroll
        for (int j = 0; j < 8; ++j) acc[i][j] = (f32x4){0.f, 0.f, 0.f, 0.f};
    auto MFMAstep = [&]() {
        bf16x8 af[2], bfr[8];
#pragma unroll
        for (int mi = 0; mi < 2; ++mi)
            af[mi] = *(const bf16x8*)&sA[(wm * 32 + mi * 16 + lo) * LDT + kg * 8];
#pragma unroll
        for (int ni = 0; ni < 8; ++ni)
            bfr[ni] = *(const bf16x8*)&sW[(wn * 128 + ni * 16 + lo) * LDT + kg * 8];
#pragma unroll
        for (int mi = 0; mi < 2; ++mi)
#pragma unroll
            for (int ni = 0; ni < 8; ++ni)
                acc[mi][ni] = __builtin_amdgcn_mfma_f32_16x16x32_bf16(af[mi], bfr[ni], acc[mi][ni], 0, 0, 0);
    };

    LOAD(0, ra0, rw0); LOAD(32, ra1, rw1);
    for (int k0 = 0; k0 < 256; k0 += 64) {
        STORE(ra0, rw0);
        __syncthreads();
        if (k0 + 64 < 256) LOAD(k0 + 64, ra0, rw0);
        MFMAstep();
        __syncthreads();
        STORE(ra1, rw1);
        __syncthreads();
        if (k0 + 96 < 256) LOAD(k0 + 96, ra1, rw1);
        MFMAstep();
        __syncthreads();
    }

#pragma unroll
    for (int mi = 0; mi < 2; ++mi) {
#pragma unroll
        for (int r = 0; r < 4; ++r) {
            const int gm = m0 + wm * 32 + mi * 16 + kg * 4 + r;
            const int b = gm / Lh, l = gm - b * Lh;
#pragma unroll
            for (int ni = 0; ni < 8; ++ni) {
                const int gn = wn * 128 + ni * 16 + lo;
                float v = (acc[mi][ni][r] + Bp[gn]) * qs;
                int head = gn >> 5, d = gn & 31;
                Cp[(((size_t)b * H_ + head) * Lh + l) * HD_ + d] = f2b(v);
            }
        }
    }
}

// ---------------- GEMM + residual + LayerNorm fused (BM=16, BN=256=N, bf16 A+W) ----------------
template<int KK>
__global__ __launch_bounds__(256) void mgemm_ln(
    const ushort* __restrict__ A, const ushort* __restrict__ W,
    const float* __restrict__ bias, const float* __restrict__ res,
    const float* __restrict__ gw, const float* __restrict__ gb, float* __restrict__ O)
{
    constexpr int LDT = 40;
    __shared__ ushort sA[16 * LDT];
    __shared__ ushort sW[256 * LDT];
    __shared__ float red[4][16][2];
    const int t = threadIdx.x, lane = t & 63, wv = t >> 6;
    const int lo = lane & 15, kg = lane >> 4;
    const int m0 = blockIdx.x * 16;
    const bool aact = (t < 128);

    uint2 a0, a1;
    uint2 w0[8], w1[8];
    auto LOADA = [&](int k0, uint2& aa) {
        if (aact) aa = *(const uint2*)(A + (size_t)(m0 + (t >> 3)) * KK + k0 + ((t & 7) << 2));
    };
    auto LOADW = [&](int k0, uint2 (&ww)[8]) {
#pragma unroll
        for (int i = 0; i < 8; ++i) {
            int e = t + 256 * i;
            int n = e >> 3, kc = (e & 7) << 2;
            ww[i] = *(const uint2*)(W + (size_t)n * KK + k0 + kc);
        }
    };
    auto STOREA = [&](uint2& aa) {
        if (aact) *(uint2*)&sA[(t >> 3) * LDT + ((t & 7) << 2)] = aa;
    };
    auto STOREW = [&](uint2 (&ww)[8]) {
#pragma unroll
        for (int i = 0; i < 8; ++i) {
            int e = t + 256 * i;
            int n = e >> 3, kc = (e & 7) << 2;
            *(uint2*)&sW[n * LDT + kc] = ww[i];
        }
    };

    f32x4 acc[4];
#pragma unroll
    for (int i = 0; i < 4; ++i) acc[i] = (f32x4){0.f, 0.f, 0.f, 0.f};

    auto MFMAstep = [&]() {
        bf16x8 af = *(const bf16x8*)&sA[lo * LDT + kg * 8];
#pragma unroll
        for (int ni = 0; ni < 4; ++ni) {
            bf16x8 bfr = *(const bf16x8*)&sW[(wv * 64 + ni * 16 + lo) * LDT + kg * 8];
            acc[ni] = __builtin_amdgcn_mfma_f32_16x16x32_bf16(af, bfr, acc[ni], 0, 0, 0);
        }
    };

    LOADA(0, a0); LOADW(0, w0);
    LOADA(32, a1); LOADW(32, w1);
    for (int k0 = 0; k0 < KK; k0 += 64) {
        STOREA(a0); STOREW(w0);
        __syncthreads();
        if (k0 + 64 < KK) { LOADA(k0 + 64, a0); LOADW(k0 + 64, w0); }
        MFMAstep();
        __syncthreads();
        STOREA(a1); STOREW(w1);
        __syncthreads();
        if (k0 + 96 < KK) { LOADA(k0 + 96, a1); LOADW(k0 + 96, w1); }
        MFMAstep();
        __syncthreads();
    }

    const int gmb = m0 + kg * 4;
    float vvv[4][4];
    float ps[4] = {0.f, 0.f, 0.f, 0.f}, qs[4] = {0.f, 0.f, 0.f, 0.f};
#pragma unroll
    for (int ni = 0; ni < 4; ++ni) {
        const int gn = wv * 64 + ni * 16 + lo;
        const float bs = bias[gn];
#pragma unroll
        for (int r = 0; r < 4; ++r) {
            float x = acc[ni][r] + bs + res[(size_t)(gmb + r) * 256 + gn];
            vvv[ni][r] = x;
            ps[r] += x;
            qs[r] += x * x;
        }
    }
#pragma unroll
    for (int off = 1; off < 16; off <<= 1) {
#pragma unroll
        for (int r = 0; r < 4; ++r) {
            ps[r] += __shfl_xor(ps[r], off);
            qs[r] += __shfl_xor(qs[r], off);
        }
    }
    if (lo == 0) {
#pragma unroll
        for (int r = 0; r < 4; ++r) {
            red[wv][kg * 4 + r][0] = ps[r];
            red[wv][kg * 4 + r][1] = qs[r];
        }
    }
    __syncthreads();
    float mean[4], rs[4];
#pragma unroll
    for (int r = 0; r < 4; ++r) {
        const int row = kg * 4 + r;
        float s = red[0][row][0] + red[1][row][0] + red[2][row][0] + red[3][row][0];
        float q = red[0][row][1] + red[1][row][1] + red[2][row][1] + red[3][row][1];
        mean[r] = s * (1.f / 256.f);
        float var = q * (1.f / 256.f) - mean[r] * mean[r];
        rs[r] = rsqrtf(var + EPS_);
    }
#pragma unroll
    for (int ni = 0; ni < 4; ++ni) {
        const int gn = wv * 64 + ni * 16 + lo;
        const float g = gw[gn], b2 = gb[gn];
#pragma unroll
        for (int r = 0; r < 4; ++r)
            O[(size_t)(gmb + r) * 256 + gn] = (vvv[ni][r] - mean[r]) * rs[r] * g + b2;
    }
}

// ---------------- Fused SA attention; LDS-aliased; XCD-grouped; setprio on MFMA ----------------
__global__ __launch_bounds__(256) void sa_fused(const ushort* __restrict__ q,
    const ushort* __restrict__ k, const ushort* __restrict__ v, ushort* __restrict__ ctx)
{
    __shared__ __align__(16) char sm[62976];
    ushort* Vt = (ushort*)sm;             // [d][key] 32 x 328
    ushort* Kt = (ushort*)(sm + 20992);   // [key][d] 304 x 40
    ushort* Pt = (ushort*)(sm + 20992);   // [wv][l][key] 4 x 16 x 328 (aliases Kt)
    const int t = threadIdx.x, lane = t & 63, wv = t >> 6;
    const int lo = lane & 15, kg = lane >> 4;
    const int linear = blockIdx.x + 5 * blockIdx.y;
    const int xcd = linear & 7, slot = linear >> 3;
    const int l0 = (slot % 5) * 64;
    const int bh = xcd + 8 * (slot / 5);
    const ushort* qp = q + (size_t)bh * 9600;
    const ushort* kp = k + (size_t)bh * 9600;
    const ushort* vp = v + (size_t)bh * 9600;

    for (int e = t; e < 1216; e += 256) {
        int row = e >> 2, dq = (e & 3) << 3;
        uint4 kv = (row < 300) ? *(const uint4*)(kp + row * 32 + dq)
                               : make_uint4(0, 0, 0, 0);
        *(uint4*)&Kt[row * 40 + dq] = kv;
    }
    for (int e = t; e < 1200; e += 256) {
        int row = e >> 2, dq = (e & 3) << 3;
        uint4 vv4 = *(const uint4*)(vp + row * 32 + dq);
        const ushort* sv = (const ushort*)&vv4;
#pragma unroll
        for (int j = 0; j < 8; ++j) Vt[(dq + j) * 328 + row] = sv[j];
    }
    for (int e = t; e < 32 * 28; e += 256) {
        int d = e / 28, kk = 300 + e % 28;
        Vt[d * 328 + kk] = 0;
    }
    const int ql = l0 + wv * 16 + lo;
    bf16x8 qf = {0, 0, 0, 0, 0, 0, 0, 0};
    if (ql < 300) qf = *(const bf16x8*)(qp + ql * 32 + kg * 8);
    __syncthreads();

    f32x4 s[19];
    __builtin_amdgcn_s_setprio(1);
#pragma unroll
    for (int f = 0; f < 19; ++f) {
        bf16x8 af = *(const bf16x8*)&Kt[(f * 16 + lo) * 40 + kg * 8];
        f32x4 z = {0.f, 0.f, 0.f, 0.f};
        s[f] = __builtin_amdgcn_mfma_f32_16x16x32_bf16(af, qf, z, 0, 0, 0);
    }
    __builtin_amdgcn_s_setprio(0);
    if (kg == 3) { s[18][0] = -3.4e38f; s[18][1] = -3.4e38f; s[18][2] = -3.4e38f; s[18][3] = -3.4e38f; }

    float mx = -3.4e38f;
#pragma unroll
    for (int f = 0; f < 19; ++f)
#pragma unroll
        for (int r = 0; r < 4; ++r) mx = fmaxf(mx, s[f][r]);
    mx = fmaxf(mx, __shfl_xor(mx, 16));
    mx = fmaxf(mx, __shfl_xor(mx, 32));
    float sum = 0.f;
#pragma unroll
    for (int f = 0; f < 19; ++f)
#pragma unroll
        for (int r = 0; r < 4; ++r) { s[f][r] = __expf(s[f][r] - mx); sum += s[f][r]; }
    sum += __shfl_xor(sum, 16);
    sum += __shfl_xor(sum, 32);
    const float inv = 1.f / sum;

    __syncthreads();   // all waves done reading Kt; Pt may overwrite

    ushort* Ptw = Pt + wv * (16 * 328);
#pragma unroll
    for (int f = 0; f < 19; ++f) {
        *(unsigned*)&Ptw[lo * 328 + f * 16 + kg * 4]     = pk2(s[f][0] * inv, s[f][1] * inv);
        *(unsigned*)&Ptw[lo * 328 + f * 16 + kg * 4 + 2] = pk2(s[f][2] * inv, s[f][3] * inv);
    }
    {
        uint2 z2 = make_uint2(0, 0);
        *(uint2*)&Ptw[(lane & 15) * 328 + 304 + ((lane >> 4) << 2)] = z2;
    }

    f32x4 o0 = {0.f, 0.f, 0.f, 0.f}, o1 = {0.f, 0.f, 0.f, 0.f};
    __builtin_amdgcn_s_setprio(1);
#pragma unroll
    for (int f = 0; f < 10; ++f) {
        bf16x8 pa = *(const bf16x8*)&Ptw[lo * 328 + f * 32 + kg * 8];
        bf16x8 b0 = *(const bf16x8*)&Vt[lo * 328 + f * 32 + kg * 8];
        bf16x8 b1 = *(const bf16x8*)&Vt[(16 + lo) * 328 + f * 32 + kg * 8];
        o0 = __builtin_amdgcn_mfma_f32_16x16x32_bf16(pa, b0, o0, 0, 0, 0);
        o1 = __builtin_amdgcn_mfma_f32_16x16x32_bf16(pa, b1, o1, 0, 0, 0);
    }
    __builtin_amdgcn_s_setprio(0);

    const int lb = l0 + wv * 16 + kg * 4;
    const int b = bh >> 3, h = bh & 7;
#pragma unroll
    for (int r = 0; r < 4; ++r) {
        int l = lb + r;
        if (l < 300) {
            ushort* op = ctx + ((size_t)b * 300 + l) * 256 + h * 32;
            op[lo] = f2b(o0[r]);
            op[lo + 16] = f2b(o1[r]);
        }
    }
}

// ---------------- Fused CA; LDS-aliased; XCD-grouped; depth-1 vv prefetch; setprio ----------------
__global__ __launch_bounds__(256) void ca_fused(const ushort* __restrict__ qr,
    const ushort* __restrict__ qc, const ushort* __restrict__ kr, const ushort* __restrict__ kc,
    const ushort* __restrict__ vv, ushort* __restrict__ out)
{
    __shared__ __align__(16) char sm[45056];
    ushort* s_ar = (ushort*)sm;             // [l][w] 64 x 72 bf16
    float*  s_ac = (float*)(sm + 9216);     // [h][l] 64 x 68 f32
    ushort* Kr   = (ushort*)(sm + 26624);   // 64 x 40
    ushort* Kc   = (ushort*)(sm + 31744);   // 64 x 40
    ushort* vvT  = (ushort*)(sm + 26624);   // [buf][h'][d][w] 2 x 2 x 32 x 72

    const int t = threadIdx.x, lane = t & 63, wv = t >> 6;
    const int lo = lane & 15, kg = lane >> 4;
    const int linear = blockIdx.x + 5 * (blockIdx.y + 8 * blockIdx.z);
    const int xcd = linear & 7, slot = linear >> 3;
    const int l0 = (slot % 5) * 64;
    const int bh = xcd + 8 * (slot / 5);
    const int nh = bh & 7, b = bh >> 3;

    {
        const ushort* krp = kr + (size_t)bh * 2048;
        const ushort* kcp = kc + (size_t)bh * 2048;
        int row = t >> 2, dq = (t & 3) << 3;
        *(uint4*)&Kr[row * 40 + dq] = *(const uint4*)(krp + row * 32 + dq);
        *(uint4*)&Kc[row * 40 + dq] = *(const uint4*)(kcp + row * 32 + dq);
    }
    const int ql = l0 + wv * 16 + lo;
    bf16x8 qrf = {0,0,0,0,0,0,0,0}, qcf = {0,0,0,0,0,0,0,0};
    if (ql < 300) {
        qrf = *(const bf16x8*)(qr + (size_t)bh * 9600 + ql * 32 + kg * 8);
        qcf = *(const bf16x8*)(qc + (size_t)bh * 9600 + ql * 32 + kg * 8);
    }
    const ushort* vvp = vv + (size_t)bh * 131072;
    __syncthreads();   // Kr/Kc staged

#pragma unroll
    for (int m = 0; m < 2; ++m) {
        const ushort* Kp = m ? Kc : Kr;
        const bf16x8 qf = m ? qcf : qrf;
        f32x4 s[4];
#pragma unroll
        for (int f = 0; f < 4; ++f) {
            bf16x8 af = *(const bf16x8*)&Kp[(f * 16 + lo) * 40 + kg * 8];
            f32x4 z = {0.f, 0.f, 0.f, 0.f};
            s[f] = __builtin_amdgcn_mfma_f32_16x16x32_bf16(af, qf, z, 0, 0, 0);
        }
        float mx = -3.4e38f;
#pragma unroll
        for (int f = 0; f < 4; ++f)
#pragma unroll
            for (int r = 0; r < 4; ++r) mx = fmaxf(mx, s[f][r]);
        mx = fmaxf(mx, __shfl_xor(mx, 16));
        mx = fmaxf(mx, __shfl_xor(mx, 32));
        float sum = 0.f;
#pragma unroll
        for (int f = 0; f < 4; ++f)
#pragma unroll
            for (int r = 0; r < 4; ++r) { s[f][r] = __expf(s[f][r] - mx); sum += s[f][r]; }
        sum += __shfl_xor(sum, 16);
        sum += __shfl_xor(sum, 32);
        const float inv = 1.f / sum;
        if (m == 0) {
#pragma unroll
            for (int f = 0; f < 4; ++f) {
                *(unsigned*)&s_ar[(wv * 16 + lo) * 72 + f * 16 + kg * 4]     = pk2(s[f][0] * inv, s[f][1] * inv);
                *(unsigned*)&s_ar[(wv * 16 + lo) * 72 + f * 16 + kg * 4 + 2] = pk2(s[f][2] * inv, s[f][3] * inv);
            }
        } else {
#pragma unroll
            for (int f = 0; f < 4; ++f)
#pragma unroll
                for (int r = 0; r < 4; ++r)
                    s_ac[(f * 16 + kg * 4 + r) * 68 + wv * 16 + lo] = s[f][r] * inv;
        }
    }

    __syncthreads();   // done reading Kr/Kc; vvT may overwrite

#pragma unroll
    for (int i = 0; i < 2; ++i) {
        int c = t + 256 * i;
        int h1 = c >> 8, d = (c >> 3) & 31, w8 = (c & 7) << 3;
        uint4 v4 = *(const uint4*)(vvp + h1 * 2048 + d * 64 + w8);
        *(uint4*)&vvT[(h1 * 32 + d) * 72 + w8] = v4;
    }
    __syncthreads();

    const bf16x8 af0 = *(const bf16x8*)&s_ar[(wv * 16 + lo) * 72 + kg * 8];
    const bf16x8 af1 = *(const bf16x8*)&s_ar[(wv * 16 + lo) * 72 + 32 + kg * 8];

    f32x4 acc0 = {0.f, 0.f, 0.f, 0.f};
    f32x4 acc1 = {0.f, 0.f, 0.f, 0.f};

    for (int it = 0; it < 32; ++it) {
        const int cur = it & 1;
        uint4 pre[2];
        if (it < 31) {
            const ushort* nxt = vvp + (size_t)(2 * (it + 1)) * 2048;
#pragma unroll
            for (int i = 0; i < 2; ++i) {
                int c = t + 256 * i;
                int h1 = c >> 8, d = (c >> 3) & 31, w8 = (c & 7) << 3;
                pre[i] = *(const uint4*)(nxt + h1 * 2048 + d * 64 + w8);
            }
        }
        __builtin_amdgcn_s_setprio(1);
#pragma unroll
        for (int hh = 0; hh < 2; ++hh) {
            const int h = 2 * it + hh;
            const ushort* vt = &vvT[(cur * 2 + hh) * 32 * 72];
            bf16x8 b00 = *(const bf16x8*)&vt[lo * 72 + kg * 8];
            bf16x8 b01 = *(const bf16x8*)&vt[lo * 72 + 32 + kg * 8];
            bf16x8 b10 = *(const bf16x8*)&vt[(16 + lo) * 72 + kg * 8];
            bf16x8 b11 = *(const bf16x8*)&vt[(16 + lo) * 72 + 32 + kg * 8];
            f32x4 z = {0.f, 0.f, 0.f, 0.f};
            f32x4 t0 = __builtin_amdgcn_mfma_f32_16x16x32_bf16(af0, b00, z, 0, 0, 0);
            t0 = __builtin_amdgcn_mfma_f32_16x16x32_bf16(af1, b01, t0, 0, 0, 0);
            f32x4 t1 = __builtin_amdgcn_mfma_f32_16x16x32_bf16(af0, b10, z, 0, 0, 0);
            t1 = __builtin_amdgcn_mfma_f32_16x16x32_bf16(af1, b11, t1, 0, 0, 0);
            const float* sp = &s_ac[h * 68 + wv * 16 + kg * 4];
#pragma unroll
            for (int r = 0; r < 4; ++r) {
                float sc = sp[r];
                acc0[r] += sc * t0[r];
                acc1[r] += sc * t1[r];
            }
        }
        __builtin_amdgcn_s_setprio(0);
        if (it < 31) {
#pragma unroll
            for (int i = 0; i < 2; ++i) {
                int c = t + 256 * i;
                int h1 = c >> 8, d = (c >> 3) & 31, w8 = (c & 7) << 3;
                *(uint4*)&vvT[((cur ^ 1) * 2 + h1) * 32 * 72 + d * 72 + w8] = pre[i];
            }
        }
        __syncthreads();
    }

    const int lbase = l0 + wv * 16 + kg * 4;
#pragma unroll
    for (int r = 0; r < 4; ++r) {
        if (lbase + r < 300) {
            ushort* op = out + ((size_t)b * 300 + lbase + r) * 256 + nh * 32;
            op[lo] = f2b(acc0[r]);
            op[16 + lo] = f2b(acc1[r]);
        }
    }
}

extern "C" void kernel_launch(void* const* d_in, const int* in_sizes, int n_in,
                              void* d_out, int out_size, void* d_ws, size_t ws_size,
                              hipStream_t stream)
{
    (void)in_sizes; (void)n_in; (void)out_size; (void)ws_size;
    const float* tgt   = (const float*)d_in[0];
    const float* qpos  = (const float*)d_in[1];
    const float* qpx   = (const float*)d_in[2];
    const float* qpy   = (const float*)d_in[3];
    const float* srcs  = (const float*)d_in[4];
    const float* prow  = (const float*)d_in[6];
    const float* pcol  = (const float*)d_in[7];
    const float* sa_w  = (const float*)d_in[8];
    const float* sa_b  = (const float*)d_in[9];
    const float* sa_ow = (const float*)d_in[10];
    const float* sa_ob = (const float*)d_in[11];
    const float* ca_w  = (const float*)d_in[12];
    const float* ca_b  = (const float*)d_in[13];
    const float* ca_ow = (const float*)d_in[14];
    const float* ca_ob = (const float*)d_in[15];
    const float* n1w   = (const float*)d_in[16];
    const float* n1b   = (const float*)d_in[17];
    const float* n2w   = (const float*)d_in[18];
    const float* n2b   = (const float*)d_in[19];
    const float* l1w   = (const float*)d_in[20];
    const float* l1b   = (const float*)d_in[21];
    const float* l2w   = (const float*)d_in[22];
    const float* l2b   = (const float*)d_in[23];
    const float* nfw   = (const float*)d_in[24];
    const float* nfb   = (const float*)d_in[25];
    float* out = (float*)d_out;
    float* ws  = (float*)d_ws;

    float* tgt2  = ws + 1228800;
    float* tgt3  = ws + 2457600;
    float* rowm  = ws + 3686400;       // (B,64,E) f32
    float* colm  = ws + 3948544;
    ushort* u    = (ushort*)(ws + 4210688);
    ushort* q16    = u;                // (B,H,L,HD)
    ushort* k16    = u + 1228800;
    ushort* v16    = u + 2457600;
    ushort* ctx16  = u + 3686400;      // (B,L,E)
    ushort* qrow16 = u + 4915200;
    ushort* qcol16 = u + 6144000;
    ushort* krow16 = u + 7372800;      // (B,H,64,HD)
    ushort* kcol16 = u + 7634944;
    ushort* ffm16  = u + 7897088;      // (B,L,FF)
    ushort* vvb    = u + 12812288;     // vvT: (B*H)[h][d][w] bf16
    ushort* wbf    = u + 29589504;     // bf16 weight pool
    ushort* w_sa   = wbf;              // 768x256
    ushort* w_sao  = wbf + 196608;     // 256x256
    ushort* w_ca   = wbf + 262144;     // 5 x 256x256
    ushort* w_cao  = wbf + 589824;     // 256x256
    ushort* w_l1   = wbf + 655360;     // 1024x256
    ushort* w_l2   = wbf + 917504;     // 256x1024

    // ---- prep: weight conversion + src means (one launch) ----
    prep<<<5248,256,0,stream>>>(sa_w, sa_ow, ca_w, ca_ow, l1w, l2w, wbf,
                                srcs, rowm, colm);

    // ---- Self-attention ----
    mgemm<64,128,0,true,false,1,false,false><<<dim3(75,6),256,0,stream>>>(
        tgt, qpos, w_sa, sa_b, q16, k16, v16, 4800, 768, 256, 300, SCALE_, 512,
        nullptr, nullptr, nullptr, nullptr, nullptr);
    sa_fused<<<dim3(5,128),256,0,stream>>>(q16, k16, v16, ctx16);
    mgemm_ln<256><<<300,256,0,stream>>>(ctx16, w_sao, sa_ob, tgt, n2w, n2b, tgt2);

    // ---- Cross-attention prep ----
    mgemm_maps<<<dim3(75,1,4),256,0,stream>>>(
        tgt2, tgt2, rowm, colm,
        qpx, qpy, prow, pcol,
        w_ca, w_ca + 65536, w_ca + 2*65536, w_ca + 3*65536,
        ca_b, ca_b + 256, ca_b + 512, ca_b + 768,
        qrow16, qcol16, krow16, kcol16);
    mgemm<128,128,3,false,false,2,false,true><<<dim3(512,2),256,0,stream>>>(
        srcs, nullptr, w_ca + 4*65536, ca_b + 1024, vvb, nullptr, nullptr,
        65536, 256, 256, 0, 1.f, 0,
        nullptr, nullptr, nullptr, nullptr, nullptr);

    // ---- CA fused core + out proj + LN ----
    ca_fused<<<dim3(5,8,16),256,0,stream>>>(qrow16, qcol16, krow16, kcol16, vvb, ctx16);
    mgemm_ln<256><<<300,256,0,stream>>>(ctx16, w_cao, ca_ob, tgt2, n1w, n1b, tgt3);

    // ---- FFN ----
    mgemm<64,256,0,false,true,3,false,false><<<dim3(75,4),256,0,stream>>>(
        tgt3, nullptr, w_l1, l1b, ffm16, nullptr, nullptr, 4800, 1024, 256, 0, 1.f, 0,
        nullptr, nullptr, nullptr, nullptr, nullptr);
    mgemm_ln<1024><<<300,256,0,stream>>>(ffm16, w_l2, l2b, tgt3, nfw, nfb, out);
}